// Round 1
// baseline (960.476 us; speedup 1.0000x reference)
//
#include <hip/hip_runtime.h>
#include <hip/hip_bf16.h>

// Problem dims
#define BB 32
#define LL 256
#define KC 50
#define SS 16
#define DD 128
#define NH 4
#define CC 128
#define VV 50000
#define NNN 100000
#define NUU 50000
#define NSS 5000

__device__ __forceinline__ float dot4(float4 a, float4 b){
  return a.x*b.x + a.y*b.y + a.z*b.z + a.w*b.w;
}

// ---------------------------------------------------------------------------
// 1) newsK/newsV = news_table @ [wk;wv]^T + [bk;bv]
//    256 threads = 256 output cols (0..127 -> K, 128..255 -> V).
//    weight row cached in 32 float4 regs; 64 input rows staged in LDS.
__global__ __launch_bounds__(256, 2) void k_projkv(
    const float* __restrict__ news, const float* __restrict__ in_w,
    const float* __restrict__ in_b, float* __restrict__ nK, float* __restrict__ nV){
  __shared__ float xs[64][128];
  const int c = threadIdx.x;
  const int wrow = 128 + c;          // K col c -> row 128+c ; V col c-128 -> row 256+(c-128)=128+c
  float4 w[32];
  const float4* wr = (const float4*)(in_w + wrow*DD);
  #pragma unroll
  for (int j=0;j<32;j++) w[j] = wr[j];
  const float bias = in_b[wrow];
  const int r0 = blockIdx.x * 64;
  const float4* src = (const float4*)(news + (size_t)r0*DD);
  float4* dst = (float4*)&xs[0][0];
  for (int i=threadIdx.x; i<64*32; i+=256){
    int row = r0 + (i>>5);
    if (row < NNN) dst[i] = src[i];
  }
  __syncthreads();
  const int rmax = (NNN - r0 < 64) ? (NNN - r0) : 64;
  for (int r=0;r<rmax;r++){
    const float4* x4 = (const float4*)xs[r];
    float acc = bias;
    #pragma unroll
    for (int j=0;j<32;j++) acc += dot4(w[j], x4[j]);
    const size_t row = (size_t)(r0 + r);
    if (c < 128) nK[row*DD + c] = acc;
    else         nV[row*DD + (c-128)] = acc;
  }
}

// ---------------------------------------------------------------------------
// 2) qh[p][c] = word_table[widx[p]] . wq[c] + bq[c]
__global__ __launch_bounds__(128, 2) void k_qh(
    const float* __restrict__ word_table, const int* __restrict__ widx,
    const float* __restrict__ in_w, const float* __restrict__ in_b,
    float* __restrict__ qh){
  __shared__ float xs[32][128];
  __shared__ int idx[32];
  const int c = threadIdx.x;
  float4 w[32];
  const float4* wr = (const float4*)(in_w + c*DD);
  #pragma unroll
  for (int j=0;j<32;j++) w[j] = wr[j];
  const float bias = in_b[c];
  const int p0 = blockIdx.x * 32;
  if (c < 32) idx[c] = widx[p0 + c];
  __syncthreads();
  for (int i=c; i<32*32; i+=128){
    int r = i>>5, j = i&31;
    ((float4*)xs[r])[j] = ((const float4*)(word_table + (size_t)idx[r]*DD))[j];
  }
  __syncthreads();
  for (int r=0;r<32;r++){
    const float4* x4 = (const float4*)xs[r];
    float acc = bias;
    #pragma unroll
    for (int j=0;j<32;j++) acc += dot4(w[j], x4[j]);
    qh[(size_t)(p0+r)*DD + c] = acc;
  }
}

// ---------------------------------------------------------------------------
// 3) per-(b,l) attention over 50 gathered projected K/V rows
__global__ __launch_bounds__(128) void k_attn(
    const float* __restrict__ qh, const float* __restrict__ nK,
    const float* __restrict__ nV, const int* __restrict__ ctx_ids,
    float* __restrict__ o_out){
  const int p = blockIdx.x;
  const int tid = threadIdx.x;
  const int h = tid >> 5;
  __shared__ int ids[KC];
  __shared__ float sc[NH][KC];
  if (tid < KC) ids[tid] = ctx_ids[(size_t)p*KC + tid];
  const float qd = qh[(size_t)p*DD + tid];
  __syncthreads();
  for (int k2=0;k2<KC;k2++){
    float pr = qd * nK[(size_t)ids[k2]*DD + tid];
    pr += __shfl_xor(pr, 16, 32);
    pr += __shfl_xor(pr, 8, 32);
    pr += __shfl_xor(pr, 4, 32);
    pr += __shfl_xor(pr, 2, 32);
    pr += __shfl_xor(pr, 1, 32);
    if ((tid & 31) == 0) sc[h][k2] = pr;
  }
  __syncthreads();
  if (tid < NH){
    const float scale = 0.17677669529663687f;  // 1/sqrt(32)
    float mx = -1e30f;
    for (int k2=0;k2<KC;k2++) mx = fmaxf(mx, sc[tid][k2]);
    float sm = 0.f;
    for (int k2=0;k2<KC;k2++){
      float ee = __expf((sc[tid][k2]-mx)*scale);
      sc[tid][k2] = ee; sm += ee;
    }
    float inv = 1.f/sm;
    for (int k2=0;k2<KC;k2++) sc[tid][k2] *= inv;
  }
  __syncthreads();
  float acc = 0.f;
  for (int k2=0;k2<KC;k2++) acc += sc[h][k2] * nV[(size_t)ids[k2]*DD + tid];
  o_out[(size_t)p*DD + tid] = acc;
}

// ---------------------------------------------------------------------------
// 4) doc = mask(widx==0) ? 0 : o @ wo^T + bo
__global__ __launch_bounds__(128, 2) void k_wo(
    const float* __restrict__ o_attn, const int* __restrict__ widx,
    const float* __restrict__ out_w, const float* __restrict__ out_b,
    float* __restrict__ doc){
  __shared__ float xs[32][128];
  const int c = threadIdx.x;
  float4 w[32];
  const float4* wr = (const float4*)(out_w + c*DD);
  #pragma unroll
  for (int j=0;j<32;j++) w[j] = wr[j];
  const float bias = out_b[c];
  const int p0 = blockIdx.x * 32;
  const float4* src = (const float4*)(o_attn + (size_t)p0*DD);
  float4* dst = (float4*)&xs[0][0];
  for (int i=c; i<32*32; i+=128) dst[i] = src[i];
  __syncthreads();
  for (int r=0;r<32;r++){
    const float4* x4 = (const float4*)xs[r];
    float acc = bias;
    #pragma unroll
    for (int j=0;j<32;j++) acc += dot4(w[j], x4[j]);
    int p = p0 + r;
    doc[(size_t)p*DD + c] = (widx[p] == 0) ? 0.0f : acc;
  }
}

// ---------------------------------------------------------------------------
// 5) transpose conv weights: Wt[(d*kk+jj)*C + c] = W[c][d][jj]
__global__ __launch_bounds__(256) void k_convprep(
    const float* __restrict__ w3, const float* __restrict__ w4,
    const float* __restrict__ w5, float* __restrict__ wt3,
    float* __restrict__ wt4, float* __restrict__ wt5){
  int e = blockIdx.x*256 + threadIdx.x;
  if (e < CC*DD*3){ int c = e/(DD*3), rm = e%(DD*3); wt3[rm*CC + c] = w3[e]; }
  if (e < CC*DD*4){ int c = e/(DD*4), rm = e%(DD*4); wt4[rm*CC + c] = w4[e]; }
  if (e < CC*DD*5){ int c = e/(DD*5), rm = e%(DD*5); wt5[rm*CC + c] = w5[e]; }
}

// ---------------------------------------------------------------------------
// 6) conv + max-pool (raw max per t-chunk; bias+relu applied at reduce)
//    grid: b * 3 convs * 8 t-chunks; 128 threads = out channel c
__global__ __launch_bounds__(128) void k_conv(
    const float* __restrict__ doc, const float* __restrict__ wt3,
    const float* __restrict__ wt4, const float* __restrict__ wt5,
    float* __restrict__ convp){
  const int blk = blockIdx.x;
  const int ci = blk & 7;
  const int j  = (blk >> 3) % 3;
  const int b  = blk / 24;
  const int kk = 3 + j;
  const int T  = LL - kk + 1;
  const int t0 = ci * 32;
  const int len = (T - t0 < 32) ? (T - t0) : 32;
  const float* wt = (j==0) ? wt3 : (j==1) ? wt4 : wt5;
  __shared__ float xs[36][128];
  const int nrows = len + kk - 1;
  const float4* src = (const float4*)(doc + ((size_t)b*LL + t0)*DD);
  float4* dst = (float4*)&xs[0][0];
  for (int i=threadIdx.x; i<nrows*32; i+=128) dst[i] = src[i];
  __syncthreads();
  const int c = threadIdx.x;
  float acc[32];
  #pragma unroll
  for (int u=0;u<32;u++) acc[u] = 0.f;
  for (int d=0; d<DD; d++){
    for (int jj=0; jj<kk; jj++){
      float wv = wt[(d*kk+jj)*CC + c];
      #pragma unroll
      for (int u=0;u<32;u++) acc[u] += xs[u+jj][d] * wv;
    }
  }
  float m = -1e30f;
  for (int u=0;u<len;u++) m = fmaxf(m, acc[u]);
  convp[(((size_t)b*3 + j)*8 + ci)*CC + c] = m;
}

// ---------------------------------------------------------------------------
// 7) GRU over 3 steps; block per (module, b, half-of-16-seqs); 384 threads
__global__ __launch_bounds__(384, 1) void k_gru(
    const float* __restrict__ news_table, const float* __restrict__ user_table,
    const float* __restrict__ source_table,
    const int* __restrict__ news_ids, const int* __restrict__ nsn_src,
    const int* __restrict__ nsn_end, const int* __restrict__ nun_usr,
    const int* __restrict__ nun_end,
    const float* __restrict__ wih0, const float* __restrict__ whh0,
    const float* __restrict__ bih0, const float* __restrict__ bhh0,
    const float* __restrict__ wih1, const float* __restrict__ whh1,
    const float* __restrict__ bih1, const float* __restrict__ bhh1,
    float* __restrict__ enc){
  const int gb = blockIdx.x;
  const int m  = gb >> 6;
  const int b  = (gb >> 1) & 31;
  const int s0 = (gb & 1) * 8;
  const int tid = threadIdx.x;
  __shared__ float xs[8][128], hs[8][128];
  __shared__ float gi[384][8], gh[384][8];
  const float* Wih = m ? wih1 : wih0;
  const float* Whh = m ? whh1 : whh0;
  const float* bih = m ? bih1 : bih0;
  const float* bhh = m ? bhh1 : bhh0;
  for (int i=tid;i<8*128;i+=384) ((float*)hs)[i] = 0.f;
  const float bi = bih[tid], bh = bhh[tid];
  const float4* wi4 = (const float4*)(Wih + tid*DD);
  const float4* wh4 = (const float4*)(Whh + tid*DD);
  for (int t=0;t<3;t++){
    __syncthreads();
    for (int i=tid;i<8*128;i+=384){
      int u = i>>7, d = i&127;
      int s = s0 + u;
      int row; const float* tab;
      if (t==0){ row = news_ids[b]; tab = news_table; }
      else if (t==1){ row = m ? nun_usr[b*SS+s] : nsn_src[b*SS+s];
                      tab = m ? user_table : source_table; }
      else { row = m ? nun_end[b*SS+s] : nsn_end[b*SS+s]; tab = news_table; }
      xs[u][d] = tab[(size_t)row*DD + d];
    }
    __syncthreads();
    float aI[8], aH[8];
    #pragma unroll
    for (int u=0;u<8;u++){ aI[u]=bi; aH[u]=bh; }
    for (int j=0;j<32;j++){
      float4 wiv = wi4[j], whv = wh4[j];
      #pragma unroll
      for (int u=0;u<8;u++){
        aI[u] += dot4(wiv, ((const float4*)xs[u])[j]);
        aH[u] += dot4(whv, ((const float4*)hs[u])[j]);
      }
    }
    #pragma unroll
    for (int u=0;u<8;u++){ gi[tid][u]=aI[u]; gh[tid][u]=aH[u]; }
    __syncthreads();
    if (tid < 128){
      #pragma unroll
      for (int u=0;u<8;u++){
        float r = 1.f/(1.f+__expf(-(gi[tid][u]+gh[tid][u])));
        float z = 1.f/(1.f+__expf(-(gi[128+tid][u]+gh[128+tid][u])));
        float n = tanhf(gi[256+tid][u] + r*gh[256+tid][u]);
        hs[u][tid] = (1.f-z)*n + z*hs[u][tid];
      }
    }
  }
  __syncthreads();
  for (int i=tid;i<8*128;i+=384){
    int u=i>>7, d=i&127;
    enc[(((size_t)m*BB + b)*SS + (s0+u))*DD + d] = hs[u][d];
  }
}

// ---------------------------------------------------------------------------
// 8) meta-path MHA + residual + LN + mean over s; block per (module, b)
__global__ __launch_bounds__(128, 2) void k_metamha(
    const float* __restrict__ enc,
    const float* __restrict__ inw0, const float* __restrict__ inb0,
    const float* __restrict__ outw0, const float* __restrict__ outb0,
    const float* __restrict__ lng0, const float* __restrict__ lnb0,
    const float* __restrict__ inw1, const float* __restrict__ inb1,
    const float* __restrict__ outw1, const float* __restrict__ outb1,
    const float* __restrict__ lng1, const float* __restrict__ lnb1,
    float* __restrict__ meta_e){
  const int m = blockIdx.x >> 5;
  const int b = blockIdx.x & 31;
  const int c = threadIdx.x;
  const float* in_w  = m?inw1:inw0;  const float* in_b  = m?inb1:inb0;
  const float* out_w = m?outw1:outw0; const float* out_b = m?outb1:outb0;
  const float* lng   = m?lng1:lng0;  const float* lnb   = m?lnb1:lnb0;
  __shared__ float e[16][128], q[16][128], k[16][128], v[16][128];
  __shared__ float at[4][16][16];
  __shared__ float mu[16], rs[16];
  const float* esrc = enc + ((size_t)m*BB + b)*SS*DD;
  for (int i=c;i<16*128;i+=128) ((float*)e)[i] = esrc[i];
  __syncthreads();
  { // qkv projections, 16-seq register accumulators
    float aq[16], ak[16], av[16];
    float bq = in_b[c], bk = in_b[128+c], bv = in_b[256+c];
    #pragma unroll
    for (int s=0;s<16;s++){ aq[s]=bq; ak[s]=bk; av[s]=bv; }
    const float4* wq4 = (const float4*)(in_w + c*DD);
    const float4* wk4 = (const float4*)(in_w + (128+c)*DD);
    const float4* wv4 = (const float4*)(in_w + (256+c)*DD);
    for (int j=0;j<32;j++){
      float4 a0=wq4[j], a1=wk4[j], a2=wv4[j];
      #pragma unroll
      for (int s=0;s<16;s++){
        float4 ev = ((const float4*)e[s])[j];
        aq[s]+=dot4(a0,ev); ak[s]+=dot4(a1,ev); av[s]+=dot4(a2,ev);
      }
    }
    #pragma unroll
    for (int s=0;s<16;s++){ q[s][c]=aq[s]; k[s][c]=ak[s]; v[s][c]=av[s]; }
  }
  __syncthreads();
  for (int r=0;r<8;r++){
    int lin = r*128 + c;
    int h = lin >> 8, qi = (lin>>4)&15, ki = lin&15;
    float sum=0.f;
    const float* qp = &q[qi][h*32];
    const float* kp = &k[ki][h*32];
    for (int x=0;x<32;x++) sum += qp[x]*kp[x];
    at[h][qi][ki] = sum * 0.17677669529663687f;
  }
  __syncthreads();
  if (c < 64){
    int h = c>>4, qi = c&15;
    float mx=-1e30f;
    for (int ki=0;ki<16;ki++) mx = fmaxf(mx, at[h][qi][ki]);
    float sm=0.f;
    for (int ki=0;ki<16;ki++){ float ee=__expf(at[h][qi][ki]-mx); at[h][qi][ki]=ee; sm+=ee; }
    float inv=1.f/sm;
    for (int ki=0;ki<16;ki++) at[h][qi][ki]*=inv;
  }
  __syncthreads();
  { // o = attn @ v, store into q (q no longer needed)
    int h = c>>5;
    float o[16];
    #pragma unroll
    for (int s=0;s<16;s++){
      float acc=0.f;
      for (int ki=0;ki<16;ki++) acc += at[h][s][ki]*v[ki][c];
      o[s]=acc;
    }
    __syncthreads();
    #pragma unroll
    for (int s=0;s<16;s++) q[s][c]=o[s];
  }
  __syncthreads();
  { // y = o @ out_w^T + out_b + enc ; overwrite e
    float ay[16];
    float bo = out_b[c];
    #pragma unroll
    for (int s=0;s<16;s++) ay[s] = bo + e[s][c];
    const float4* wo4 = (const float4*)(out_w + c*DD);
    for (int j=0;j<32;j++){
      float4 wv_ = wo4[j];
      #pragma unroll
      for (int s=0;s<16;s++) ay[s] += dot4(wv_, ((const float4*)q[s])[j]);
    }
    __syncthreads();
    #pragma unroll
    for (int s=0;s<16;s++) e[s][c] = ay[s];
  }
  __syncthreads();
  if (c < 16){
    float sm=0.f;
    for (int d=0;d<128;d++) sm += e[c][d];
    float mean = sm*(1.f/128.f);
    float vs=0.f;
    for (int d=0;d<128;d++){ float df = e[c][d]-mean; vs += df*df; }
    mu[c]=mean; rs[c]=rsqrtf(vs*(1.f/128.f) + 1e-5f);
  }
  __syncthreads();
  {
    float g = lng[c], bb2 = lnb[c];
    float acc=0.f;
    #pragma unroll
    for (int s=0;s<16;s++) acc += (e[s][c]-mu[s])*rs[s]*g + bb2;
    meta_e[((size_t)m*BB+b)*DD + c] = acc * (1.f/16.f);
  }
}

// ---------------------------------------------------------------------------
// 9) pool-reduce + fc + meta gate + classifier; block per b
__global__ __launch_bounds__(128) void k_final(
    const float* __restrict__ convp,
    const float* __restrict__ cb3, const float* __restrict__ cb4,
    const float* __restrict__ cb5,
    const float* __restrict__ fc_w, const float* __restrict__ fc_b,
    const float* __restrict__ meta_e,
    const float* __restrict__ mp_w1, const float* __restrict__ mp_b1,
    const float* __restrict__ mp_w2, const float* __restrict__ mp_b2,
    const float* __restrict__ cls_w1, const float* __restrict__ cls_b1,
    const float* __restrict__ cls_w2, const float* __restrict__ cls_b2,
    float* __restrict__ out){
  const int b = blockIdx.x;
  const int c = threadIdx.x;
  __shared__ float pooled[384];
  __shared__ float comb[256];
  __shared__ float hcls[128];
  __shared__ float tt[2][64];
  __shared__ float wsc[2];
  for (int idx=c; idx<384; idx+=128){
    int j = idx >> 7, cc2 = idx & 127;
    const float* base = convp + (((size_t)b*3 + j)*8)*CC + cc2;
    float mx = -1e30f;
    for (int ci=0;ci<8;ci++) mx = fmaxf(mx, base[ci*CC]);
    const float* cb = (j==0)?cb3:(j==1)?cb4:cb5;
    pooled[idx] = fmaxf(mx + cb[cc2], 0.f);
  }
  __syncthreads();
  {
    float acc = fc_b[c];
    const float* wr = fc_w + (size_t)c*384;
    for (int i=0;i<384;i++) acc += pooled[i]*wr[i];
    comb[c] = acc;
  }
  if (c < 64){
    for (int m=0;m<2;m++){
      const float* ev = meta_e + ((size_t)m*BB+b)*DD;
      float acc = mp_b1[c];
      const float* wr = mp_w1 + (size_t)c*DD;
      for (int i=0;i<DD;i++) acc += ev[i]*wr[i];
      tt[m][c] = tanhf(acc);
    }
  }
  __syncthreads();
  if (c == 0){
    float s0 = mp_b2[0], s1 = mp_b2[0];
    for (int j=0;j<64;j++){ s0 += tt[0][j]*mp_w2[j]; s1 += tt[1][j]*mp_w2[j]; }
    float mx = fmaxf(s0,s1);
    float e0 = __expf(s0-mx), e1 = __expf(s1-mx);
    wsc[0] = e0/(e0+e1); wsc[1] = e1/(e0+e1);
  }
  __syncthreads();
  comb[128+c] = wsc[0]*meta_e[((size_t)b)*DD + c]
              + wsc[1]*meta_e[((size_t)(BB+b))*DD + c];
  __syncthreads();
  {
    float acc = cls_b1[c];
    const float* wr = cls_w1 + (size_t)c*256;
    for (int i=0;i<256;i++) acc += comb[i]*wr[i];
    hcls[c] = fmaxf(acc, 0.f);
  }
  __syncthreads();
  if (c < 2){
    float acc = cls_b2[c];
    const float* wr = cls_w2 + (size_t)c*DD;
    for (int i=0;i<DD;i++) acc += hcls[i]*wr[i];
    out[b*2 + c] = acc;
  }
}

// ---------------------------------------------------------------------------
extern "C" void kernel_launch(void* const* d_in, const int* in_sizes, int n_in,
                              void* d_out, int out_size, void* d_ws, size_t ws_size,
                              hipStream_t stream){
  const int* news_ids = (const int*)d_in[0];
  const int* nwi      = (const int*)d_in[1];
  const int* ctx_ids  = (const int*)d_in[2];
  const int* nsn_src  = (const int*)d_in[3];
  const int* nsn_end  = (const int*)d_in[4];
  const int* nun_usr  = (const int*)d_in[5];
  const int* nun_end  = (const int*)d_in[6];
  const float* word_table   = (const float*)d_in[7];
  const float* news_table   = (const float*)d_in[8];
  const float* user_table   = (const float*)d_in[9];
  const float* source_table = (const float*)d_in[10];
  const float* wa_in_w  = (const float*)d_in[11];
  const float* wa_in_b  = (const float*)d_in[12];
  const float* wa_out_w = (const float*)d_in[13];
  const float* wa_out_b = (const float*)d_in[14];
  const float* conv_w3 = (const float*)d_in[15];
  const float* conv_b3 = (const float*)d_in[16];
  const float* conv_w4 = (const float*)d_in[17];
  const float* conv_b4 = (const float*)d_in[18];
  const float* conv_w5 = (const float*)d_in[19];
  const float* conv_b5 = (const float*)d_in[20];
  const float* fc_w = (const float*)d_in[21];
  const float* fc_b = (const float*)d_in[22];
  // nsn block 23..32, nun block 33..42
  const float* wih0 = (const float*)d_in[23];
  const float* whh0 = (const float*)d_in[24];
  const float* bih0 = (const float*)d_in[25];
  const float* bhh0 = (const float*)d_in[26];
  const float* inw0 = (const float*)d_in[27];
  const float* inb0 = (const float*)d_in[28];
  const float* outw0 = (const float*)d_in[29];
  const float* outb0 = (const float*)d_in[30];
  const float* lng0 = (const float*)d_in[31];
  const float* lnb0 = (const float*)d_in[32];
  const float* wih1 = (const float*)d_in[33];
  const float* whh1 = (const float*)d_in[34];
  const float* bih1 = (const float*)d_in[35];
  const float* bhh1 = (const float*)d_in[36];
  const float* inw1 = (const float*)d_in[37];
  const float* inb1 = (const float*)d_in[38];
  const float* outw1 = (const float*)d_in[39];
  const float* outb1 = (const float*)d_in[40];
  const float* lng1 = (const float*)d_in[41];
  const float* lnb1 = (const float*)d_in[42];
  const float* mp_w1 = (const float*)d_in[43];
  const float* mp_b1 = (const float*)d_in[44];
  const float* mp_w2 = (const float*)d_in[45];
  const float* mp_b2 = (const float*)d_in[46];
  const float* cls_w1 = (const float*)d_in[47];
  const float* cls_b1 = (const float*)d_in[48];
  const float* cls_w2 = (const float*)d_in[49];
  const float* cls_b2 = (const float*)d_in[50];

  // workspace layout (floats)
  float* ws = (float*)d_ws;
  float* nK     = ws;
  float* nV     = nK + (size_t)NNN*DD;
  float* qh     = nV + (size_t)NNN*DD;
  float* o_at   = qh + (size_t)BB*LL*DD;
  float* doc    = o_at + (size_t)BB*LL*DD;
  float* wt3    = doc + (size_t)BB*LL*DD;
  float* wt4    = wt3 + CC*DD*3;
  float* wt5    = wt4 + CC*DD*4;
  float* convp  = wt5 + CC*DD*5;
  float* enc    = convp + BB*3*8*CC;
  float* meta_e = enc + (size_t)2*BB*SS*DD;
  const size_t need_floats = (size_t)(meta_e - ws) + 2*BB*DD;
  if (ws_size < need_floats*sizeof(float)) return;  // signals as exact-zero output

  k_projkv<<<dim3((NNN+63)/64), dim3(256), 0, stream>>>(news_table, wa_in_w, wa_in_b, nK, nV);
  k_qh<<<dim3(BB*LL/32), dim3(128), 0, stream>>>(word_table, nwi, wa_in_w, wa_in_b, qh);
  k_attn<<<dim3(BB*LL), dim3(128), 0, stream>>>(qh, nK, nV, ctx_ids, o_at);
  k_wo<<<dim3(BB*LL/32), dim3(128), 0, stream>>>(o_at, nwi, wa_out_w, wa_out_b, doc);
  k_convprep<<<dim3(320), dim3(256), 0, stream>>>(conv_w3, conv_w4, conv_w5, wt3, wt4, wt5);
  k_conv<<<dim3(BB*3*8), dim3(128), 0, stream>>>(doc, wt3, wt4, wt5, convp);
  k_gru<<<dim3(128), dim3(384), 0, stream>>>(news_table, user_table, source_table,
      news_ids, nsn_src, nsn_end, nun_usr, nun_end,
      wih0, whh0, bih0, bhh0, wih1, whh1, bih1, bhh1, enc);
  k_metamha<<<dim3(64), dim3(128), 0, stream>>>(enc,
      inw0, inb0, outw0, outb0, lng0, lnb0,
      inw1, inb1, outw1, outb1, lng1, lnb1, meta_e);
  k_final<<<dim3(BB), dim3(128), 0, stream>>>(convp, conv_b3, conv_b4, conv_b5,
      fc_w, fc_b, meta_e, mp_w1, mp_b1, mp_w2, mp_b2,
      cls_w1, cls_b1, cls_w2, cls_b2, (float*)d_out);
}

// Round 2
// 766.712 us; speedup vs baseline: 1.2527x; 1.2527x over previous
//
#include <hip/hip_runtime.h>
#include <hip/hip_bf16.h>

// Problem dims
#define BB 32
#define LL 256
#define KC 50
#define SS 16
#define DD 128
#define NH 4
#define CC 128
#define VV 50000
#define NNN 100000
#define NUU 50000
#define NSS 5000

typedef __attribute__((ext_vector_type(8))) short bf16x8;
typedef __attribute__((ext_vector_type(4))) float f32x4;

__device__ __forceinline__ float dot4(float4 a, float4 b){
  return a.x*b.x + a.y*b.y + a.z*b.z + a.w*b.w;
}

__device__ __forceinline__ unsigned short f2bf(float f){
  union { float f; unsigned int u; } v; v.f = f;
  unsigned int r = (v.u + 0x7FFFu + ((v.u >> 16) & 1u)) >> 16;
  return (unsigned short)r;
}
__device__ __forceinline__ float bf2f(unsigned short s){
  union { unsigned int u; float f; } v; v.u = ((unsigned int)s) << 16;
  return v.f;
}

// ---------------------------------------------------------------------------
// 1) nK/nV = bf16( news_table @ [wk;wv]^T + [bk;bv] )  via MFMA 16x16x32 bf16
//    block: 256 thr (4 waves), M-tile 64 rows, N = 256 cols (wave w: cols w*64..w*64+63)
__global__ __launch_bounds__(256) void k_projkv(
    const float* __restrict__ news, const float* __restrict__ in_w,
    const float* __restrict__ in_b, unsigned short* __restrict__ nK,
    unsigned short* __restrict__ nV){
  __shared__ __align__(16) char smem[64*260*2];   // 33280 B, aliased A-tile then Out-tile
  unsigned short* As = (unsigned short*)smem;      // [64][128] bf16 (16 KB)
  unsigned short* Os = (unsigned short*)smem;      // [64][260] bf16 (pad 4 -> conflict-free)
  const int tid = threadIdx.x;
  const int r0 = blockIdx.x * 64;
  // stage A tile as bf16 (coalesced float4 reads)
  for (int i = tid; i < 64*32; i += 256){
    int row = i >> 5, j = i & 31;
    int gr = r0 + row;
    float4 v = (gr < NNN) ? ((const float4*)(news + (size_t)gr*DD))[j]
                          : make_float4(0.f,0.f,0.f,0.f);
    unsigned short* d = As + row*128 + j*4;
    d[0]=f2bf(v.x); d[1]=f2bf(v.y); d[2]=f2bf(v.z); d[3]=f2bf(v.w);
  }
  __syncthreads();
  const int wave = tid >> 6;
  const int lane = tid & 63;
  const int l15  = lane & 15;
  const int quad = lane >> 4;
  // A fragments: afr[mt][ks] = A[mt*16 + l15][ks*32 + quad*8 + 0..7]
  bf16x8 afr[4][4];
  #pragma unroll
  for (int mt=0; mt<4; mt++)
    #pragma unroll
    for (int ks=0; ks<4; ks++)
      afr[mt][ks] = *(const bf16x8*)(As + (mt*16 + l15)*128 + ks*32 + quad*8);
  __syncthreads();   // A-tile LDS now free; Os may be written
  const int nbase = wave * 64;
  #pragma unroll
  for (int nt=0; nt<4; nt++){
    const int n0 = nbase + nt*16;
    const int wr = 128 + n0 + l15;         // weight row (K cols 0..127 -> rows 128.., V -> 256..)
    bf16x8 bfr[4];
    #pragma unroll
    for (int ks=0; ks<4; ks++){
      const float4* p = (const float4*)(in_w + (size_t)wr*DD + ks*32 + quad*8);
      float4 v0 = p[0], v1 = p[1];
      bf16x8 b;
      b[0]=(short)f2bf(v0.x); b[1]=(short)f2bf(v0.y); b[2]=(short)f2bf(v0.z); b[3]=(short)f2bf(v0.w);
      b[4]=(short)f2bf(v1.x); b[5]=(short)f2bf(v1.y); b[6]=(short)f2bf(v1.z); b[7]=(short)f2bf(v1.w);
      bfr[ks] = b;
    }
    const float bias = in_b[wr];
    #pragma unroll
    for (int mt=0; mt<4; mt++){
      f32x4 acc = {0.f,0.f,0.f,0.f};
      #pragma unroll
      for (int ks=0; ks<4; ks++)
        acc = __builtin_amdgcn_mfma_f32_16x16x32_bf16(afr[mt][ks], bfr[ks], acc, 0,0,0);
      // C/D: col = l15 (-> n), row = quad*4 + r (-> m within tile)
      const int col = n0 + l15;
      const int rb  = mt*16 + quad*4;
      #pragma unroll
      for (int r=0;r<4;r++)
        Os[(rb + r)*260 + col] = f2bf(acc[r] + bias);
    }
  }
  __syncthreads();
  // coalesced store: 8B (4 bf16) chunks
  for (int c = tid; c < 64*64; c += 256){
    int row = c >> 6, col4 = (c & 63) * 4;
    int gr = r0 + row;
    if (gr >= NNN) continue;
    unsigned long long v = *(const unsigned long long*)(Os + row*260 + col4);
    if (col4 < 128) *(unsigned long long*)(nK + (size_t)gr*128 + col4) = v;
    else            *(unsigned long long*)(nV + (size_t)gr*128 + (col4-128)) = v;
  }
}

// ---------------------------------------------------------------------------
// 2) qh[p][c] = word_table[widx[p]] . wq[c] + bq[c]
__global__ __launch_bounds__(128, 2) void k_qh(
    const float* __restrict__ word_table, const int* __restrict__ widx,
    const float* __restrict__ in_w, const float* __restrict__ in_b,
    float* __restrict__ qh){
  __shared__ float xs[32][128];
  __shared__ int idx[32];
  const int c = threadIdx.x;
  float4 w[32];
  const float4* wr = (const float4*)(in_w + c*DD);
  #pragma unroll
  for (int j=0;j<32;j++) w[j] = wr[j];
  const float bias = in_b[c];
  const int p0 = blockIdx.x * 32;
  if (c < 32) idx[c] = widx[p0 + c];
  __syncthreads();
  for (int i=c; i<32*32; i+=128){
    int r = i>>5, j = i&31;
    ((float4*)xs[r])[j] = ((const float4*)(word_table + (size_t)idx[r]*DD))[j];
  }
  __syncthreads();
  for (int r=0;r<32;r++){
    const float4* x4 = (const float4*)xs[r];
    float acc = bias;
    #pragma unroll
    for (int j=0;j<32;j++) acc += dot4(w[j], x4[j]);
    qh[(size_t)(p0+r)*DD + c] = acc;
  }
}

// ---------------------------------------------------------------------------
// 3) per-(b,l) attention over 50 gathered projected bf16 K/V rows
__global__ __launch_bounds__(128) void k_attn(
    const float* __restrict__ qh, const unsigned short* __restrict__ nK,
    const unsigned short* __restrict__ nV, const int* __restrict__ ctx_ids,
    float* __restrict__ o_out){
  const int p = blockIdx.x;
  const int tid = threadIdx.x;
  const int h = tid >> 5;
  __shared__ int ids[KC];
  __shared__ float sc[NH][KC];
  if (tid < KC) ids[tid] = ctx_ids[(size_t)p*KC + tid];
  const float qd = qh[(size_t)p*DD + tid];
  __syncthreads();
  for (int k2=0;k2<KC;k2++){
    float pr = qd * bf2f(nK[(size_t)ids[k2]*DD + tid]);
    pr += __shfl_xor(pr, 16, 32);
    pr += __shfl_xor(pr, 8, 32);
    pr += __shfl_xor(pr, 4, 32);
    pr += __shfl_xor(pr, 2, 32);
    pr += __shfl_xor(pr, 1, 32);
    if ((tid & 31) == 0) sc[h][k2] = pr;
  }
  __syncthreads();
  if (tid < NH){
    const float scale = 0.17677669529663687f;  // 1/sqrt(32)
    float mx = -1e30f;
    for (int k2=0;k2<KC;k2++) mx = fmaxf(mx, sc[tid][k2]);
    float sm = 0.f;
    for (int k2=0;k2<KC;k2++){
      float ee = __expf((sc[tid][k2]-mx)*scale);
      sc[tid][k2] = ee; sm += ee;
    }
    float inv = 1.f/sm;
    for (int k2=0;k2<KC;k2++) sc[tid][k2] *= inv;
  }
  __syncthreads();
  float acc = 0.f;
  for (int k2=0;k2<KC;k2++) acc += sc[h][k2] * bf2f(nV[(size_t)ids[k2]*DD + tid]);
  o_out[(size_t)p*DD + tid] = acc;
}

// ---------------------------------------------------------------------------
// 4) doc = mask(widx==0) ? 0 : o @ wo^T + bo
__global__ __launch_bounds__(128, 2) void k_wo(
    const float* __restrict__ o_attn, const int* __restrict__ widx,
    const float* __restrict__ out_w, const float* __restrict__ out_b,
    float* __restrict__ doc){
  __shared__ float xs[32][128];
  const int c = threadIdx.x;
  float4 w[32];
  const float4* wr = (const float4*)(out_w + c*DD);
  #pragma unroll
  for (int j=0;j<32;j++) w[j] = wr[j];
  const float bias = out_b[c];
  const int p0 = blockIdx.x * 32;
  const float4* src = (const float4*)(o_attn + (size_t)p0*DD);
  float4* dst = (float4*)&xs[0][0];
  for (int i=c; i<32*32; i+=128) dst[i] = src[i];
  __syncthreads();
  for (int r=0;r<32;r++){
    const float4* x4 = (const float4*)xs[r];
    float acc = bias;
    #pragma unroll
    for (int j=0;j<32;j++) acc += dot4(w[j], x4[j]);
    int p = p0 + r;
    doc[(size_t)p*DD + c] = (widx[p] == 0) ? 0.0f : acc;
  }
}

// ---------------------------------------------------------------------------
// 5) transpose conv weights: Wt[(d*kk+jj)*C + c] = W[c][d][jj]
__global__ __launch_bounds__(256) void k_convprep(
    const float* __restrict__ w3, const float* __restrict__ w4,
    const float* __restrict__ w5, float* __restrict__ wt3,
    float* __restrict__ wt4, float* __restrict__ wt5){
  int e = blockIdx.x*256 + threadIdx.x;
  if (e < CC*DD*3){ int c = e/(DD*3), rm = e%(DD*3); wt3[rm*CC + c] = w3[e]; }
  if (e < CC*DD*4){ int c = e/(DD*4), rm = e%(DD*4); wt4[rm*CC + c] = w4[e]; }
  if (e < CC*DD*5){ int c = e/(DD*5), rm = e%(DD*5); wt5[rm*CC + c] = w5[e]; }
}

// ---------------------------------------------------------------------------
// 6) conv + max-pool (raw max per t-chunk; bias+relu applied at reduce)
__global__ __launch_bounds__(128) void k_conv(
    const float* __restrict__ doc, const float* __restrict__ wt3,
    const float* __restrict__ wt4, const float* __restrict__ wt5,
    float* __restrict__ convp){
  const int blk = blockIdx.x;
  const int ci = blk & 7;
  const int j  = (blk >> 3) % 3;
  const int b  = blk / 24;
  const int kk = 3 + j;
  const int T  = LL - kk + 1;
  const int t0 = ci * 32;
  const int len = (T - t0 < 32) ? (T - t0) : 32;
  const float* wt = (j==0) ? wt3 : (j==1) ? wt4 : wt5;
  __shared__ float xs[36][128];
  const int nrows = len + kk - 1;
  const float4* src = (const float4*)(doc + ((size_t)b*LL + t0)*DD);
  float4* dst = (float4*)&xs[0][0];
  for (int i=threadIdx.x; i<nrows*32; i+=128) dst[i] = src[i];
  __syncthreads();
  const int c = threadIdx.x;
  float acc[32];
  #pragma unroll
  for (int u=0;u<32;u++) acc[u] = 0.f;
  for (int d=0; d<DD; d++){
    for (int jj=0; jj<kk; jj++){
      float wv = wt[(d*kk+jj)*CC + c];
      #pragma unroll
      for (int u=0;u<32;u++) acc[u] += xs[u+jj][d] * wv;
    }
  }
  float m = -1e30f;
  for (int u=0;u<len;u++) m = fmaxf(m, acc[u]);
  convp[(((size_t)b*3 + j)*8 + ci)*CC + c] = m;
}

// ---------------------------------------------------------------------------
// 7) GRU over 3 steps; block per (module, b, half-of-16-seqs); 384 threads
__global__ __launch_bounds__(384, 1) void k_gru(
    const float* __restrict__ news_table, const float* __restrict__ user_table,
    const float* __restrict__ source_table,
    const int* __restrict__ news_ids, const int* __restrict__ nsn_src,
    const int* __restrict__ nsn_end, const int* __restrict__ nun_usr,
    const int* __restrict__ nun_end,
    const float* __restrict__ wih0, const float* __restrict__ whh0,
    const float* __restrict__ bih0, const float* __restrict__ bhh0,
    const float* __restrict__ wih1, const float* __restrict__ whh1,
    const float* __restrict__ bih1, const float* __restrict__ bhh1,
    float* __restrict__ enc){
  const int gb = blockIdx.x;
  const int m  = gb >> 6;
  const int b  = (gb >> 1) & 31;
  const int s0 = (gb & 1) * 8;
  const int tid = threadIdx.x;
  __shared__ float xs[8][128], hs[8][128];
  __shared__ float gi[384][8], gh[384][8];
  const float* Wih = m ? wih1 : wih0;
  const float* Whh = m ? whh1 : whh0;
  const float* bih = m ? bih1 : bih0;
  const float* bhh = m ? bhh1 : bhh0;
  for (int i=tid;i<8*128;i+=384) ((float*)hs)[i] = 0.f;
  const float bi = bih[tid], bh = bhh[tid];
  const float4* wi4 = (const float4*)(Wih + tid*DD);
  const float4* wh4 = (const float4*)(Whh + tid*DD);
  for (int t=0;t<3;t++){
    __syncthreads();
    for (int i=tid;i<8*128;i+=384){
      int u = i>>7, d = i&127;
      int s = s0 + u;
      int row; const float* tab;
      if (t==0){ row = news_ids[b]; tab = news_table; }
      else if (t==1){ row = m ? nun_usr[b*SS+s] : nsn_src[b*SS+s];
                      tab = m ? user_table : source_table; }
      else { row = m ? nun_end[b*SS+s] : nsn_end[b*SS+s]; tab = news_table; }
      xs[u][d] = tab[(size_t)row*DD + d];
    }
    __syncthreads();
    float aI[8], aH[8];
    #pragma unroll
    for (int u=0;u<8;u++){ aI[u]=bi; aH[u]=bh; }
    for (int j=0;j<32;j++){
      float4 wiv = wi4[j], whv = wh4[j];
      #pragma unroll
      for (int u=0;u<8;u++){
        aI[u] += dot4(wiv, ((const float4*)xs[u])[j]);
        aH[u] += dot4(whv, ((const float4*)hs[u])[j]);
      }
    }
    #pragma unroll
    for (int u=0;u<8;u++){ gi[tid][u]=aI[u]; gh[tid][u]=aH[u]; }
    __syncthreads();
    if (tid < 128){
      #pragma unroll
      for (int u=0;u<8;u++){
        float r = 1.f/(1.f+__expf(-(gi[tid][u]+gh[tid][u])));
        float z = 1.f/(1.f+__expf(-(gi[128+tid][u]+gh[128+tid][u])));
        float n = tanhf(gi[256+tid][u] + r*gh[256+tid][u]);
        hs[u][tid] = (1.f-z)*n + z*hs[u][tid];
      }
    }
  }
  __syncthreads();
  for (int i=tid;i<8*128;i+=384){
    int u=i>>7, d=i&127;
    enc[(((size_t)m*BB + b)*SS + (s0+u))*DD + d] = hs[u][d];
  }
}

// ---------------------------------------------------------------------------
// 8) meta-path MHA + residual + LN + mean over s; block per (module, b)
__global__ __launch_bounds__(128, 2) void k_metamha(
    const float* __restrict__ enc,
    const float* __restrict__ inw0, const float* __restrict__ inb0,
    const float* __restrict__ outw0, const float* __restrict__ outb0,
    const float* __restrict__ lng0, const float* __restrict__ lnb0,
    const float* __restrict__ inw1, const float* __restrict__ inb1,
    const float* __restrict__ outw1, const float* __restrict__ outb1,
    const float* __restrict__ lng1, const float* __restrict__ lnb1,
    float* __restrict__ meta_e){
  const int m = blockIdx.x >> 5;
  const int b = blockIdx.x & 31;
  const int c = threadIdx.x;
  const float* in_w  = m?inw1:inw0;  const float* in_b  = m?inb1:inb0;
  const float* out_w = m?outw1:outw0; const float* out_b = m?outb1:outb0;
  const float* lng   = m?lng1:lng0;  const float* lnb   = m?lnb1:lnb0;
  __shared__ float e[16][128], q[16][128], k[16][128], v[16][128];
  __shared__ float at[4][16][16];
  __shared__ float mu[16], rs[16];
  const float* esrc = enc + ((size_t)m*BB + b)*SS*DD;
  for (int i=c;i<16*128;i+=128) ((float*)e)[i] = esrc[i];
  __syncthreads();
  {
    float aq[16], ak[16], av[16];
    float bq = in_b[c], bk = in_b[128+c], bv = in_b[256+c];
    #pragma unroll
    for (int s=0;s<16;s++){ aq[s]=bq; ak[s]=bk; av[s]=bv; }
    const float4* wq4 = (const float4*)(in_w + c*DD);
    const float4* wk4 = (const float4*)(in_w + (128+c)*DD);
    const float4* wv4 = (const float4*)(in_w + (256+c)*DD);
    for (int j=0;j<32;j++){
      float4 a0=wq4[j], a1=wk4[j], a2=wv4[j];
      #pragma unroll
      for (int s=0;s<16;s++){
        float4 ev = ((const float4*)e[s])[j];
        aq[s]+=dot4(a0,ev); ak[s]+=dot4(a1,ev); av[s]+=dot4(a2,ev);
      }
    }
    #pragma unroll
    for (int s=0;s<16;s++){ q[s][c]=aq[s]; k[s][c]=ak[s]; v[s][c]=av[s]; }
  }
  __syncthreads();
  for (int r=0;r<8;r++){
    int lin = r*128 + c;
    int h = lin >> 8, qi = (lin>>4)&15, ki = lin&15;
    float sum=0.f;
    const float* qp = &q[qi][h*32];
    const float* kp = &k[ki][h*32];
    for (int x=0;x<32;x++) sum += qp[x]*kp[x];
    at[h][qi][ki] = sum * 0.17677669529663687f;
  }
  __syncthreads();
  if (c < 64){
    int h = c>>4, qi = c&15;
    float mx=-1e30f;
    for (int ki=0;ki<16;ki++) mx = fmaxf(mx, at[h][qi][ki]);
    float sm=0.f;
    for (int ki=0;ki<16;ki++){ float ee=__expf(at[h][qi][ki]-mx); at[h][qi][ki]=ee; sm+=ee; }
    float inv=1.f/sm;
    for (int ki=0;ki<16;ki++) at[h][qi][ki]*=inv;
  }
  __syncthreads();
  {
    int h = c>>5;
    float o[16];
    #pragma unroll
    for (int s=0;s<16;s++){
      float acc=0.f;
      for (int ki=0;ki<16;ki++) acc += at[h][s][ki]*v[ki][c];
      o[s]=acc;
    }
    __syncthreads();
    #pragma unroll
    for (int s=0;s<16;s++) q[s][c]=o[s];
  }
  __syncthreads();
  {
    float ay[16];
    float bo = out_b[c];
    #pragma unroll
    for (int s=0;s<16;s++) ay[s] = bo + e[s][c];
    const float4* wo4 = (const float4*)(out_w + c*DD);
    for (int j=0;j<32;j++){
      float4 wv_ = wo4[j];
      #pragma unroll
      for (int s=0;s<16;s++) ay[s] += dot4(wv_, ((const float4*)q[s])[j]);
    }
    __syncthreads();
    #pragma unroll
    for (int s=0;s<16;s++) e[s][c] = ay[s];
  }
  __syncthreads();
  if (c < 16){
    float sm=0.f;
    for (int d=0;d<128;d++) sm += e[c][d];
    float mean = sm*(1.f/128.f);
    float vs=0.f;
    for (int d=0;d<128;d++){ float df = e[c][d]-mean; vs += df*df; }
    mu[c]=mean; rs[c]=rsqrtf(vs*(1.f/128.f) + 1e-5f);
  }
  __syncthreads();
  {
    float g = lng[c], bb2 = lnb[c];
    float acc=0.f;
    #pragma unroll
    for (int s=0;s<16;s++) acc += (e[s][c]-mu[s])*rs[s]*g + bb2;
    meta_e[((size_t)m*BB+b)*DD + c] = acc * (1.f/16.f);
  }
}

// ---------------------------------------------------------------------------
// 9) pool-reduce + fc + meta gate + classifier; block per b
__global__ __launch_bounds__(128) void k_final(
    const float* __restrict__ convp,
    const float* __restrict__ cb3, const float* __restrict__ cb4,
    const float* __restrict__ cb5,
    const float* __restrict__ fc_w, const float* __restrict__ fc_b,
    const float* __restrict__ meta_e,
    const float* __restrict__ mp_w1, const float* __restrict__ mp_b1,
    const float* __restrict__ mp_w2, const float* __restrict__ mp_b2,
    const float* __restrict__ cls_w1, const float* __restrict__ cls_b1,
    const float* __restrict__ cls_w2, const float* __restrict__ cls_b2,
    float* __restrict__ out){
  const int b = blockIdx.x;
  const int c = threadIdx.x;
  __shared__ float pooled[384];
  __shared__ float comb[256];
  __shared__ float hcls[128];
  __shared__ float tt[2][64];
  __shared__ float wsc[2];
  for (int idx=c; idx<384; idx+=128){
    int j = idx >> 7, cc2 = idx & 127;
    const float* base = convp + (((size_t)b*3 + j)*8)*CC + cc2;
    float mx = -1e30f;
    for (int ci=0;ci<8;ci++) mx = fmaxf(mx, base[ci*CC]);
    const float* cb = (j==0)?cb3:(j==1)?cb4:cb5;
    pooled[idx] = fmaxf(mx + cb[cc2], 0.f);
  }
  __syncthreads();
  {
    float acc = fc_b[c];
    const float* wr = fc_w + (size_t)c*384;
    for (int i=0;i<384;i++) acc += pooled[i]*wr[i];
    comb[c] = acc;
  }
  if (c < 64){
    for (int m=0;m<2;m++){
      const float* ev = meta_e + ((size_t)m*BB+b)*DD;
      float acc = mp_b1[c];
      const float* wr = mp_w1 + (size_t)c*DD;
      for (int i=0;i<DD;i++) acc += ev[i]*wr[i];
      tt[m][c] = tanhf(acc);
    }
  }
  __syncthreads();
  if (c == 0){
    float s0 = mp_b2[0], s1 = mp_b2[0];
    for (int j=0;j<64;j++){ s0 += tt[0][j]*mp_w2[j]; s1 += tt[1][j]*mp_w2[j]; }
    float mx = fmaxf(s0,s1);
    float e0 = __expf(s0-mx), e1 = __expf(s1-mx);
    wsc[0] = e0/(e0+e1); wsc[1] = e1/(e0+e1);
  }
  __syncthreads();
  comb[128+c] = wsc[0]*meta_e[((size_t)b)*DD + c]
              + wsc[1]*meta_e[((size_t)(BB+b))*DD + c];
  __syncthreads();
  {
    float acc = cls_b1[c];
    const float* wr = cls_w1 + (size_t)c*256;
    for (int i=0;i<256;i++) acc += comb[i]*wr[i];
    hcls[c] = fmaxf(acc, 0.f);
  }
  __syncthreads();
  if (c < 2){
    float acc = cls_b2[c];
    const float* wr = cls_w2 + (size_t)c*DD;
    for (int i=0;i<DD;i++) acc += hcls[i]*wr[i];
    out[b*2 + c] = acc;
  }
}

// ---------------------------------------------------------------------------
extern "C" void kernel_launch(void* const* d_in, const int* in_sizes, int n_in,
                              void* d_out, int out_size, void* d_ws, size_t ws_size,
                              hipStream_t stream){
  const int* news_ids = (const int*)d_in[0];
  const int* nwi      = (const int*)d_in[1];
  const int* ctx_ids  = (const int*)d_in[2];
  const int* nsn_src  = (const int*)d_in[3];
  const int* nsn_end  = (const int*)d_in[4];
  const int* nun_usr  = (const int*)d_in[5];
  const int* nun_end  = (const int*)d_in[6];
  const float* word_table   = (const float*)d_in[7];
  const float* news_table   = (const float*)d_in[8];
  const float* user_table   = (const float*)d_in[9];
  const float* source_table = (const float*)d_in[10];
  const float* wa_in_w  = (const float*)d_in[11];
  const float* wa_in_b  = (const float*)d_in[12];
  const float* wa_out_w = (const float*)d_in[13];
  const float* wa_out_b = (const float*)d_in[14];
  const float* conv_w3 = (const float*)d_in[15];
  const float* conv_b3 = (const float*)d_in[16];
  const float* conv_w4 = (const float*)d_in[17];
  const float* conv_b4 = (const float*)d_in[18];
  const float* conv_w5 = (const float*)d_in[19];
  const float* conv_b5 = (const float*)d_in[20];
  const float* fc_w = (const float*)d_in[21];
  const float* fc_b = (const float*)d_in[22];
  const float* wih0 = (const float*)d_in[23];
  const float* whh0 = (const float*)d_in[24];
  const float* bih0 = (const float*)d_in[25];
  const float* bhh0 = (const float*)d_in[26];
  const float* inw0 = (const float*)d_in[27];
  const float* inb0 = (const float*)d_in[28];
  const float* outw0 = (const float*)d_in[29];
  const float* outb0 = (const float*)d_in[30];
  const float* lng0 = (const float*)d_in[31];
  const float* lnb0 = (const float*)d_in[32];
  const float* wih1 = (const float*)d_in[33];
  const float* whh1 = (const float*)d_in[34];
  const float* bih1 = (const float*)d_in[35];
  const float* bhh1 = (const float*)d_in[36];
  const float* inw1 = (const float*)d_in[37];
  const float* inb1 = (const float*)d_in[38];
  const float* outw1 = (const float*)d_in[39];
  const float* outb1 = (const float*)d_in[40];
  const float* lng1 = (const float*)d_in[41];
  const float* lnb1 = (const float*)d_in[42];
  const float* mp_w1 = (const float*)d_in[43];
  const float* mp_b1 = (const float*)d_in[44];
  const float* mp_w2 = (const float*)d_in[45];
  const float* mp_b2 = (const float*)d_in[46];
  const float* cls_w1 = (const float*)d_in[47];
  const float* cls_b1 = (const float*)d_in[48];
  const float* cls_w2 = (const float*)d_in[49];
  const float* cls_b2 = (const float*)d_in[50];

  // workspace layout
  char* wsb = (char*)d_ws;
  unsigned short* nK = (unsigned short*)wsb;                 // NNN*DD bf16
  unsigned short* nV = nK + (size_t)NNN*DD;                  // NNN*DD bf16
  float* qh     = (float*)(nV + (size_t)NNN*DD);
  float* o_at   = qh + (size_t)BB*LL*DD;
  float* doc    = o_at + (size_t)BB*LL*DD;
  float* wt3    = doc + (size_t)BB*LL*DD;
  float* wt4    = wt3 + CC*DD*3;
  float* wt5    = wt4 + CC*DD*4;
  float* convp  = wt5 + CC*DD*5;
  float* enc    = convp + BB*3*8*CC;
  float* meta_e = enc + (size_t)2*BB*SS*DD;
  const size_t need_bytes = (size_t)((char*)(meta_e + 2*BB*DD) - wsb);
  if (ws_size < need_bytes) return;

  k_projkv<<<dim3((NNN+63)/64), dim3(256), 0, stream>>>(news_table, wa_in_w, wa_in_b, nK, nV);
  k_qh<<<dim3(BB*LL/32), dim3(128), 0, stream>>>(word_table, nwi, wa_in_w, wa_in_b, qh);
  k_attn<<<dim3(BB*LL), dim3(128), 0, stream>>>(qh, nK, nV, ctx_ids, o_at);
  k_wo<<<dim3(BB*LL/32), dim3(128), 0, stream>>>(o_at, nwi, wa_out_w, wa_out_b, doc);
  k_convprep<<<dim3(320), dim3(256), 0, stream>>>(conv_w3, conv_w4, conv_w5, wt3, wt4, wt5);
  k_conv<<<dim3(BB*3*8), dim3(128), 0, stream>>>(doc, wt3, wt4, wt5, convp);
  k_gru<<<dim3(128), dim3(384), 0, stream>>>(news_table, user_table, source_table,
      news_ids, nsn_src, nsn_end, nun_usr, nun_end,
      wih0, whh0, bih0, bhh0, wih1, whh1, bih1, bhh1, enc);
  k_metamha<<<dim3(64), dim3(128), 0, stream>>>(enc,
      inw0, inb0, outw0, outb0, lng0, lnb0,
      inw1, inb1, outw1, outb1, lng1, lnb1, meta_e);
  k_final<<<dim3(BB), dim3(128), 0, stream>>>(convp, conv_b3, conv_b4, conv_b5,
      fc_w, fc_b, meta_e, mp_w1, mp_b1, mp_w2, mp_b2,
      cls_w1, cls_b1, cls_w2, cls_b2, (float*)d_out);
}

// Round 3
// 625.345 us; speedup vs baseline: 1.5359x; 1.2261x over previous
//
#include <hip/hip_runtime.h>
#include <hip/hip_bf16.h>

// Problem dims
#define BB 32
#define LL 256
#define KC 50
#define SS 16
#define DD 128
#define NH 4
#define CC 128
#define VV 50000
#define NNN 100000
#define NUU 50000
#define NSS 5000

typedef __attribute__((ext_vector_type(8))) short bf16x8;
typedef __attribute__((ext_vector_type(4))) float f32x4;

__device__ __forceinline__ float dot4(float4 a, float4 b){
  return a.x*b.x + a.y*b.y + a.z*b.z + a.w*b.w;
}

__device__ __forceinline__ unsigned short f2bf(float f){
  union { float f; unsigned int u; } v; v.f = f;
  unsigned int r = (v.u + 0x7FFFu + ((v.u >> 16) & 1u)) >> 16;
  return (unsigned short)r;
}
__device__ __forceinline__ float bf2f(unsigned short s){
  union { unsigned int u; float f; } v; v.u = ((unsigned int)s) << 16;
  return v.f;
}

// ---------------------------------------------------------------------------
// 1) nK/nV = bf16( news_table @ [wk;wv]^T + [bk;bv] )  via MFMA 16x16x32 bf16
__global__ __launch_bounds__(256) void k_projkv(
    const float* __restrict__ news, const float* __restrict__ in_w,
    const float* __restrict__ in_b, unsigned short* __restrict__ nK,
    unsigned short* __restrict__ nV){
  __shared__ __align__(16) char smem[64*260*2];
  unsigned short* As = (unsigned short*)smem;      // [64][128] bf16
  unsigned short* Os = (unsigned short*)smem;      // [64][260] bf16 (pad 4)
  const int tid = threadIdx.x;
  const int r0 = blockIdx.x * 64;
  for (int i = tid; i < 64*32; i += 256){
    int row = i >> 5, j = i & 31;
    int gr = r0 + row;
    float4 v = (gr < NNN) ? ((const float4*)(news + (size_t)gr*DD))[j]
                          : make_float4(0.f,0.f,0.f,0.f);
    unsigned short* d = As + row*128 + j*4;
    d[0]=f2bf(v.x); d[1]=f2bf(v.y); d[2]=f2bf(v.z); d[3]=f2bf(v.w);
  }
  __syncthreads();
  const int wave = tid >> 6;
  const int lane = tid & 63;
  const int l15  = lane & 15;
  const int quad = lane >> 4;
  bf16x8 afr[4][4];
  #pragma unroll
  for (int mt=0; mt<4; mt++)
    #pragma unroll
    for (int ks=0; ks<4; ks++)
      afr[mt][ks] = *(const bf16x8*)(As + (mt*16 + l15)*128 + ks*32 + quad*8);
  __syncthreads();
  const int nbase = wave * 64;
  #pragma unroll
  for (int nt=0; nt<4; nt++){
    const int n0 = nbase + nt*16;
    const int wr = 128 + n0 + l15;
    bf16x8 bfr[4];
    #pragma unroll
    for (int ks=0; ks<4; ks++){
      const float4* p = (const float4*)(in_w + (size_t)wr*DD + ks*32 + quad*8);
      float4 v0 = p[0], v1 = p[1];
      bf16x8 b;
      b[0]=(short)f2bf(v0.x); b[1]=(short)f2bf(v0.y); b[2]=(short)f2bf(v0.z); b[3]=(short)f2bf(v0.w);
      b[4]=(short)f2bf(v1.x); b[5]=(short)f2bf(v1.y); b[6]=(short)f2bf(v1.z); b[7]=(short)f2bf(v1.w);
      bfr[ks] = b;
    }
    const float bias = in_b[wr];
    #pragma unroll
    for (int mt=0; mt<4; mt++){
      f32x4 acc = {0.f,0.f,0.f,0.f};
      #pragma unroll
      for (int ks=0; ks<4; ks++)
        acc = __builtin_amdgcn_mfma_f32_16x16x32_bf16(afr[mt][ks], bfr[ks], acc, 0,0,0);
      const int col = n0 + l15;
      const int rb  = mt*16 + quad*4;
      #pragma unroll
      for (int r=0;r<4;r++)
        Os[(rb + r)*260 + col] = f2bf(acc[r] + bias);
    }
  }
  __syncthreads();
  for (int c = tid; c < 64*64; c += 256){
    int row = c >> 6, col4 = (c & 63) * 4;
    int gr = r0 + row;
    if (gr >= NNN) continue;
    unsigned long long v = *(const unsigned long long*)(Os + row*260 + col4);
    if (col4 < 128) *(unsigned long long*)(nK + (size_t)gr*128 + col4) = v;
    else            *(unsigned long long*)(nV + (size_t)gr*128 + (col4-128)) = v;
  }
}

// ---------------------------------------------------------------------------
// 2) qh[p][c] = word_table[widx[p]] . wq[c] + bq[c]
__global__ __launch_bounds__(128, 2) void k_qh(
    const float* __restrict__ word_table, const int* __restrict__ widx,
    const float* __restrict__ in_w, const float* __restrict__ in_b,
    float* __restrict__ qh){
  __shared__ float xs[32][128];
  __shared__ int idx[32];
  const int c = threadIdx.x;
  float4 w[32];
  const float4* wr = (const float4*)(in_w + c*DD);
  #pragma unroll
  for (int j=0;j<32;j++) w[j] = wr[j];
  const float bias = in_b[c];
  const int p0 = blockIdx.x * 32;
  if (c < 32) idx[c] = widx[p0 + c];
  __syncthreads();
  for (int i=c; i<32*32; i+=128){
    int r = i>>5, j = i&31;
    ((float4*)xs[r])[j] = ((const float4*)(word_table + (size_t)idx[r]*DD))[j];
  }
  __syncthreads();
  for (int r=0;r<32;r++){
    const float4* x4 = (const float4*)xs[r];
    float acc = bias;
    #pragma unroll
    for (int j=0;j<32;j++) acc += dot4(w[j], x4[j]);
    qh[(size_t)(p0+r)*DD + c] = acc;
  }
}

// ---------------------------------------------------------------------------
// 3) per-(b,l) attention over 50 gathered projected bf16 K/V rows
__global__ __launch_bounds__(128) void k_attn(
    const float* __restrict__ qh, const unsigned short* __restrict__ nK,
    const unsigned short* __restrict__ nV, const int* __restrict__ ctx_ids,
    float* __restrict__ o_out){
  const int p = blockIdx.x;
  const int tid = threadIdx.x;
  const int h = tid >> 5;
  __shared__ int ids[KC];
  __shared__ float sc[NH][KC];
  if (tid < KC) ids[tid] = ctx_ids[(size_t)p*KC + tid];
  const float qd = qh[(size_t)p*DD + tid];
  __syncthreads();
  for (int k2=0;k2<KC;k2++){
    float pr = qd * bf2f(nK[(size_t)ids[k2]*DD + tid]);
    pr += __shfl_xor(pr, 16, 32);
    pr += __shfl_xor(pr, 8, 32);
    pr += __shfl_xor(pr, 4, 32);
    pr += __shfl_xor(pr, 2, 32);
    pr += __shfl_xor(pr, 1, 32);
    if ((tid & 31) == 0) sc[h][k2] = pr;
  }
  __syncthreads();
  if (tid < NH){
    const float scale = 0.17677669529663687f;
    float mx = -1e30f;
    for (int k2=0;k2<KC;k2++) mx = fmaxf(mx, sc[tid][k2]);
    float sm = 0.f;
    for (int k2=0;k2<KC;k2++){
      float ee = __expf((sc[tid][k2]-mx)*scale);
      sc[tid][k2] = ee; sm += ee;
    }
    float inv = 1.f/sm;
    for (int k2=0;k2<KC;k2++) sc[tid][k2] *= inv;
  }
  __syncthreads();
  float acc = 0.f;
  for (int k2=0;k2<KC;k2++) acc += sc[h][k2] * bf2f(nV[(size_t)ids[k2]*DD + tid]);
  o_out[(size_t)p*DD + tid] = acc;
}

// ---------------------------------------------------------------------------
// 4) doc = mask(widx==0) ? 0 : o @ wo^T + bo
__global__ __launch_bounds__(128, 2) void k_wo(
    const float* __restrict__ o_attn, const int* __restrict__ widx,
    const float* __restrict__ out_w, const float* __restrict__ out_b,
    float* __restrict__ doc){
  __shared__ float xs[32][128];
  const int c = threadIdx.x;
  float4 w[32];
  const float4* wr = (const float4*)(out_w + c*DD);
  #pragma unroll
  for (int j=0;j<32;j++) w[j] = wr[j];
  const float bias = out_b[c];
  const int p0 = blockIdx.x * 32;
  const float4* src = (const float4*)(o_attn + (size_t)p0*DD);
  float4* dst = (float4*)&xs[0][0];
  for (int i=c; i<32*32; i+=128) dst[i] = src[i];
  __syncthreads();
  for (int r=0;r<32;r++){
    const float4* x4 = (const float4*)xs[r];
    float acc = bias;
    #pragma unroll
    for (int j=0;j<32;j++) acc += dot4(w[j], x4[j]);
    int p = p0 + r;
    doc[(size_t)p*DD + c] = (widx[p] == 0) ? 0.0f : acc;
  }
}

// ---------------------------------------------------------------------------
// 5) conv weights -> bf16, layout wb[jj][c][d] per conv
__global__ __launch_bounds__(256) void k_convprep(
    const float* __restrict__ w3, const float* __restrict__ w4,
    const float* __restrict__ w5, unsigned short* __restrict__ wb3,
    unsigned short* __restrict__ wb4, unsigned short* __restrict__ wb5){
  int e = blockIdx.x*256 + threadIdx.x;
  if (e < CC*DD*3){ int c=e/(DD*3), rm=e%(DD*3), d=rm/3, jj=rm%3;
    wb3[((size_t)jj*CC + c)*DD + d] = f2bf(w3[e]); }
  if (e < CC*DD*4){ int c=e/(DD*4), rm=e%(DD*4), d=rm/4, jj=rm%4;
    wb4[((size_t)jj*CC + c)*DD + d] = f2bf(w4[e]); }
  if (e < CC*DD*5){ int c=e/(DD*5), rm=e%(DD*5), d=rm/5, jj=rm%5;
    wb5[((size_t)jj*CC + c)*DD + d] = f2bf(w5[e]); }
}

// ---------------------------------------------------------------------------
// 6) conv as MFMA GEMM + fused max-over-t.
//    grid: (b,conv,chunk) = 32*3*4; 256 thr = 4 waves; wave w: t rows w*16..w*16+15
//    LDS doc tile: rows chunk*64 .. +64+kk-1 as bf16, row stride 136 (pad)
#define CROWS 68
#define CPAD 136
__global__ __launch_bounds__(256) void k_conv(
    const float* __restrict__ doc, const unsigned short* __restrict__ wb3,
    const unsigned short* __restrict__ wb4, const unsigned short* __restrict__ wb5,
    float* __restrict__ convp){
  __shared__ __align__(16) char smem[CROWS*CPAD*2];   // 18496 B
  unsigned short* ds = (unsigned short*)smem;
  float* smf = (float*)smem;                           // aliased epilogue buffer
  const int blk = blockIdx.x;
  const int chunk = blk & 3;
  const int j = (blk >> 2) % 3;
  const int b = blk / 12;
  const int kk = 3 + j;
  const int T = LL - kk + 1;
  const int t0 = chunk * 64;
  const int nrows = 64 + kk - 1;
  const unsigned short* wb = (j==0) ? wb3 : (j==1) ? wb4 : wb5;
  const int tid = threadIdx.x;
  // stage doc rows t0..t0+nrows-1 (zero-pad past row 255)
  for (int i = tid; i < nrows*32; i += 256){
    int row = i >> 5, q4 = i & 31;
    int gt = t0 + row;
    float4 v = (gt < LL) ? ((const float4*)(doc + ((size_t)b*LL + gt)*DD))[q4]
                         : make_float4(0.f,0.f,0.f,0.f);
    unsigned short* dp = ds + row*CPAD + q4*4;
    dp[0]=f2bf(v.x); dp[1]=f2bf(v.y); dp[2]=f2bf(v.z); dp[3]=f2bf(v.w);
  }
  __syncthreads();
  const int wave = tid >> 6;
  const int lane = tid & 63;
  const int l15  = lane & 15;
  const int quad = lane >> 4;
  f32x4 acc[8];
  #pragma unroll
  for (int nt=0;nt<8;nt++) acc[nt] = (f32x4){0.f,0.f,0.f,0.f};
  for (int jj=0; jj<kk; jj++){
    #pragma unroll
    for (int ks=0; ks<4; ks++){
      bf16x8 af = *(const bf16x8*)(ds + (wave*16 + l15 + jj)*CPAD + ks*32 + quad*8);
      #pragma unroll
      for (int nt=0; nt<8; nt++){
        bf16x8 bf = *(const bf16x8*)(wb + ((size_t)jj*CC + nt*16 + l15)*DD + ks*32 + quad*8);
        acc[nt] = __builtin_amdgcn_mfma_f32_16x16x32_bf16(af, bf, acc[nt], 0,0,0);
      }
    }
  }
  __syncthreads();   // done reading ds; smf may be written
  // epilogue: max over valid t rows (m = quad*4 + r), reduce across quads
  #pragma unroll
  for (int nt=0; nt<8; nt++){
    float mx = -1e30f;
    #pragma unroll
    for (int r=0;r<4;r++){
      int t = t0 + wave*16 + quad*4 + r;
      mx = fmaxf(mx, (t < T) ? acc[nt][r] : -1e30f);
    }
    mx = fmaxf(mx, __shfl_xor(mx, 16, 64));
    mx = fmaxf(mx, __shfl_xor(mx, 32, 64));
    if (quad == 0) smf[wave*128 + nt*16 + l15] = mx;
  }
  __syncthreads();
  if (tid < 128){
    float m4 = fmaxf(fmaxf(smf[tid], smf[128+tid]), fmaxf(smf[256+tid], smf[384+tid]));
    convp[(((size_t)b*3 + j)*4 + chunk)*CC + tid] = m4;
  }
}

// ---------------------------------------------------------------------------
// 7) GRU over 3 steps; block per (module, b, half-of-16-seqs); 384 threads
__global__ __launch_bounds__(384, 1) void k_gru(
    const float* __restrict__ news_table, const float* __restrict__ user_table,
    const float* __restrict__ source_table,
    const int* __restrict__ news_ids, const int* __restrict__ nsn_src,
    const int* __restrict__ nsn_end, const int* __restrict__ nun_usr,
    const int* __restrict__ nun_end,
    const float* __restrict__ wih0, const float* __restrict__ whh0,
    const float* __restrict__ bih0, const float* __restrict__ bhh0,
    const float* __restrict__ wih1, const float* __restrict__ whh1,
    const float* __restrict__ bih1, const float* __restrict__ bhh1,
    float* __restrict__ enc){
  const int gb = blockIdx.x;
  const int m  = gb >> 6;
  const int b  = (gb >> 1) & 31;
  const int s0 = (gb & 1) * 8;
  const int tid = threadIdx.x;
  __shared__ float xs[8][128], hs[8][128];
  __shared__ float gi[384][8], gh[384][8];
  const float* Wih = m ? wih1 : wih0;
  const float* Whh = m ? whh1 : whh0;
  const float* bih = m ? bih1 : bih0;
  const float* bhh = m ? bhh1 : bhh0;
  for (int i=tid;i<8*128;i+=384) ((float*)hs)[i] = 0.f;
  const float bi = bih[tid], bh = bhh[tid];
  const float4* wi4 = (const float4*)(Wih + tid*DD);
  const float4* wh4 = (const float4*)(Whh + tid*DD);
  for (int t=0;t<3;t++){
    __syncthreads();
    for (int i=tid;i<8*128;i+=384){
      int u = i>>7, d = i&127;
      int s = s0 + u;
      int row; const float* tab;
      if (t==0){ row = news_ids[b]; tab = news_table; }
      else if (t==1){ row = m ? nun_usr[b*SS+s] : nsn_src[b*SS+s];
                      tab = m ? user_table : source_table; }
      else { row = m ? nun_end[b*SS+s] : nsn_end[b*SS+s]; tab = news_table; }
      xs[u][d] = tab[(size_t)row*DD + d];
    }
    __syncthreads();
    float aI[8], aH[8];
    #pragma unroll
    for (int u=0;u<8;u++){ aI[u]=bi; aH[u]=bh; }
    for (int j=0;j<32;j++){
      float4 wiv = wi4[j], whv = wh4[j];
      #pragma unroll
      for (int u=0;u<8;u++){
        aI[u] += dot4(wiv, ((const float4*)xs[u])[j]);
        aH[u] += dot4(whv, ((const float4*)hs[u])[j]);
      }
    }
    #pragma unroll
    for (int u=0;u<8;u++){ gi[tid][u]=aI[u]; gh[tid][u]=aH[u]; }
    __syncthreads();
    if (tid < 128){
      #pragma unroll
      for (int u=0;u<8;u++){
        float r = 1.f/(1.f+__expf(-(gi[tid][u]+gh[tid][u])));
        float z = 1.f/(1.f+__expf(-(gi[128+tid][u]+gh[128+tid][u])));
        float n = tanhf(gi[256+tid][u] + r*gh[256+tid][u]);
        hs[u][tid] = (1.f-z)*n + z*hs[u][tid];
      }
    }
  }
  __syncthreads();
  for (int i=tid;i<8*128;i+=384){
    int u=i>>7, d=i&127;
    enc[(((size_t)m*BB + b)*SS + (s0+u))*DD + d] = hs[u][d];
  }
}

// ---------------------------------------------------------------------------
// 8) meta-path MHA + residual + LN + mean over s; block per (module, b)
__global__ __launch_bounds__(128, 2) void k_metamha(
    const float* __restrict__ enc,
    const float* __restrict__ inw0, const float* __restrict__ inb0,
    const float* __restrict__ outw0, const float* __restrict__ outb0,
    const float* __restrict__ lng0, const float* __restrict__ lnb0,
    const float* __restrict__ inw1, const float* __restrict__ inb1,
    const float* __restrict__ outw1, const float* __restrict__ outb1,
    const float* __restrict__ lng1, const float* __restrict__ lnb1,
    float* __restrict__ meta_e){
  const int m = blockIdx.x >> 5;
  const int b = blockIdx.x & 31;
  const int c = threadIdx.x;
  const float* in_w  = m?inw1:inw0;  const float* in_b  = m?inb1:inb0;
  const float* out_w = m?outw1:outw0; const float* out_b = m?outb1:outb0;
  const float* lng   = m?lng1:lng0;  const float* lnb   = m?lnb1:lnb0;
  __shared__ float e[16][128], q[16][128], k[16][128], v[16][128];
  __shared__ float at[4][16][16];
  __shared__ float mu[16], rs[16];
  const float* esrc = enc + ((size_t)m*BB + b)*SS*DD;
  for (int i=c;i<16*128;i+=128) ((float*)e)[i] = esrc[i];
  __syncthreads();
  {
    float aq[16], ak[16], av[16];
    float bq = in_b[c], bk = in_b[128+c], bv = in_b[256+c];
    #pragma unroll
    for (int s=0;s<16;s++){ aq[s]=bq; ak[s]=bk; av[s]=bv; }
    const float4* wq4 = (const float4*)(in_w + c*DD);
    const float4* wk4 = (const float4*)(in_w + (128+c)*DD);
    const float4* wv4 = (const float4*)(in_w + (256+c)*DD);
    for (int j=0;j<32;j++){
      float4 a0=wq4[j], a1=wk4[j], a2=wv4[j];
      #pragma unroll
      for (int s=0;s<16;s++){
        float4 ev = ((const float4*)e[s])[j];
        aq[s]+=dot4(a0,ev); ak[s]+=dot4(a1,ev); av[s]+=dot4(a2,ev);
      }
    }
    #pragma unroll
    for (int s=0;s<16;s++){ q[s][c]=aq[s]; k[s][c]=ak[s]; v[s][c]=av[s]; }
  }
  __syncthreads();
  for (int r=0;r<8;r++){
    int lin = r*128 + c;
    int h = lin >> 8, qi = (lin>>4)&15, ki = lin&15;
    float sum=0.f;
    const float* qp = &q[qi][h*32];
    const float* kp = &k[ki][h*32];
    for (int x=0;x<32;x++) sum += qp[x]*kp[x];
    at[h][qi][ki] = sum * 0.17677669529663687f;
  }
  __syncthreads();
  if (c < 64){
    int h = c>>4, qi = c&15;
    float mx=-1e30f;
    for (int ki=0;ki<16;ki++) mx = fmaxf(mx, at[h][qi][ki]);
    float sm=0.f;
    for (int ki=0;ki<16;ki++){ float ee=__expf(at[h][qi][ki]-mx); at[h][qi][ki]=ee; sm+=ee; }
    float inv=1.f/sm;
    for (int ki=0;ki<16;ki++) at[h][qi][ki]*=inv;
  }
  __syncthreads();
  {
    int h = c>>5;
    float o[16];
    #pragma unroll
    for (int s=0;s<16;s++){
      float acc=0.f;
      for (int ki=0;ki<16;ki++) acc += at[h][s][ki]*v[ki][c];
      o[s]=acc;
    }
    __syncthreads();
    #pragma unroll
    for (int s=0;s<16;s++) q[s][c]=o[s];
  }
  __syncthreads();
  {
    float ay[16];
    float bo = out_b[c];
    #pragma unroll
    for (int s=0;s<16;s++) ay[s] = bo + e[s][c];
    const float4* wo4 = (const float4*)(out_w + c*DD);
    for (int j=0;j<32;j++){
      float4 wv_ = wo4[j];
      #pragma unroll
      for (int s=0;s<16;s++) ay[s] += dot4(wv_, ((const float4*)q[s])[j]);
    }
    __syncthreads();
    #pragma unroll
    for (int s=0;s<16;s++) e[s][c] = ay[s];
  }
  __syncthreads();
  if (c < 16){
    float sm=0.f;
    for (int d=0;d<128;d++) sm += e[c][d];
    float mean = sm*(1.f/128.f);
    float vs=0.f;
    for (int d=0;d<128;d++){ float df = e[c][d]-mean; vs += df*df; }
    mu[c]=mean; rs[c]=rsqrtf(vs*(1.f/128.f) + 1e-5f);
  }
  __syncthreads();
  {
    float g = lng[c], bb2 = lnb[c];
    float acc=0.f;
    #pragma unroll
    for (int s=0;s<16;s++) acc += (e[s][c]-mu[s])*rs[s]*g + bb2;
    meta_e[((size_t)m*BB+b)*DD + c] = acc * (1.f/16.f);
  }
}

// ---------------------------------------------------------------------------
// 9) pool-reduce + fc + meta gate + classifier; block per b
__global__ __launch_bounds__(128) void k_final(
    const float* __restrict__ convp,
    const float* __restrict__ cb3, const float* __restrict__ cb4,
    const float* __restrict__ cb5,
    const float* __restrict__ fc_w, const float* __restrict__ fc_b,
    const float* __restrict__ meta_e,
    const float* __restrict__ mp_w1, const float* __restrict__ mp_b1,
    const float* __restrict__ mp_w2, const float* __restrict__ mp_b2,
    const float* __restrict__ cls_w1, const float* __restrict__ cls_b1,
    const float* __restrict__ cls_w2, const float* __restrict__ cls_b2,
    float* __restrict__ out){
  const int b = blockIdx.x;
  const int c = threadIdx.x;
  __shared__ float pooled[384];
  __shared__ float comb[256];
  __shared__ float hcls[128];
  __shared__ float tt[2][64];
  __shared__ float wsc[2];
  for (int idx=c; idx<384; idx+=128){
    int j = idx >> 7, cc2 = idx & 127;
    const float* base = convp + (((size_t)b*3 + j)*4)*CC + cc2;
    float mx = -1e30f;
    for (int ci=0;ci<4;ci++) mx = fmaxf(mx, base[ci*CC]);
    const float* cb = (j==0)?cb3:(j==1)?cb4:cb5;
    pooled[idx] = fmaxf(mx + cb[cc2], 0.f);
  }
  __syncthreads();
  {
    float acc = fc_b[c];
    const float* wr = fc_w + (size_t)c*384;
    for (int i=0;i<384;i++) acc += pooled[i]*wr[i];
    comb[c] = acc;
  }
  if (c < 64){
    for (int m=0;m<2;m++){
      const float* ev = meta_e + ((size_t)m*BB+b)*DD;
      float acc = mp_b1[c];
      const float* wr = mp_w1 + (size_t)c*DD;
      for (int i=0;i<DD;i++) acc += ev[i]*wr[i];
      tt[m][c] = tanhf(acc);
    }
  }
  __syncthreads();
  if (c == 0){
    float s0 = mp_b2[0], s1 = mp_b2[0];
    for (int j=0;j<64;j++){ s0 += tt[0][j]*mp_w2[j]; s1 += tt[1][j]*mp_w2[j]; }
    float mx = fmaxf(s0,s1);
    float e0 = __expf(s0-mx), e1 = __expf(s1-mx);
    wsc[0] = e0/(e0+e1); wsc[1] = e1/(e0+e1);
  }
  __syncthreads();
  comb[128+c] = wsc[0]*meta_e[((size_t)b)*DD + c]
              + wsc[1]*meta_e[((size_t)(BB+b))*DD + c];
  __syncthreads();
  {
    float acc = cls_b1[c];
    const float* wr = cls_w1 + (size_t)c*256;
    for (int i=0;i<256;i++) acc += comb[i]*wr[i];
    hcls[c] = fmaxf(acc, 0.f);
  }
  __syncthreads();
  if (c < 2){
    float acc = cls_b2[c];
    const float* wr = cls_w2 + (size_t)c*DD;
    for (int i=0;i<DD;i++) acc += hcls[i]*wr[i];
    out[b*2 + c] = acc;
  }
}

// ---------------------------------------------------------------------------
extern "C" void kernel_launch(void* const* d_in, const int* in_sizes, int n_in,
                              void* d_out, int out_size, void* d_ws, size_t ws_size,
                              hipStream_t stream){
  const int* news_ids = (const int*)d_in[0];
  const int* nwi      = (const int*)d_in[1];
  const int* ctx_ids  = (const int*)d_in[2];
  const int* nsn_src  = (const int*)d_in[3];
  const int* nsn_end  = (const int*)d_in[4];
  const int* nun_usr  = (const int*)d_in[5];
  const int* nun_end  = (const int*)d_in[6];
  const float* word_table   = (const float*)d_in[7];
  const float* news_table   = (const float*)d_in[8];
  const float* user_table   = (const float*)d_in[9];
  const float* source_table = (const float*)d_in[10];
  const float* wa_in_w  = (const float*)d_in[11];
  const float* wa_in_b  = (const float*)d_in[12];
  const float* wa_out_w = (const float*)d_in[13];
  const float* wa_out_b = (const float*)d_in[14];
  const float* conv_w3 = (const float*)d_in[15];
  const float* conv_b3 = (const float*)d_in[16];
  const float* conv_w4 = (const float*)d_in[17];
  const float* conv_b4 = (const float*)d_in[18];
  const float* conv_w5 = (const float*)d_in[19];
  const float* conv_b5 = (const float*)d_in[20];
  const float* fc_w = (const float*)d_in[21];
  const float* fc_b = (const float*)d_in[22];
  const float* wih0 = (const float*)d_in[23];
  const float* whh0 = (const float*)d_in[24];
  const float* bih0 = (const float*)d_in[25];
  const float* bhh0 = (const float*)d_in[26];
  const float* inw0 = (const float*)d_in[27];
  const float* inb0 = (const float*)d_in[28];
  const float* outw0 = (const float*)d_in[29];
  const float* outb0 = (const float*)d_in[30];
  const float* lng0 = (const float*)d_in[31];
  const float* lnb0 = (const float*)d_in[32];
  const float* wih1 = (const float*)d_in[33];
  const float* whh1 = (const float*)d_in[34];
  const float* bih1 = (const float*)d_in[35];
  const float* bhh1 = (const float*)d_in[36];
  const float* inw1 = (const float*)d_in[37];
  const float* inb1 = (const float*)d_in[38];
  const float* outw1 = (const float*)d_in[39];
  const float* outb1 = (const float*)d_in[40];
  const float* lng1 = (const float*)d_in[41];
  const float* lnb1 = (const float*)d_in[42];
  const float* mp_w1 = (const float*)d_in[43];
  const float* mp_b1 = (const float*)d_in[44];
  const float* mp_w2 = (const float*)d_in[45];
  const float* mp_b2 = (const float*)d_in[46];
  const float* cls_w1 = (const float*)d_in[47];
  const float* cls_b1 = (const float*)d_in[48];
  const float* cls_w2 = (const float*)d_in[49];
  const float* cls_b2 = (const float*)d_in[50];

  // workspace layout
  char* wsb = (char*)d_ws;
  unsigned short* nK = (unsigned short*)wsb;                 // NNN*DD bf16
  unsigned short* nV = nK + (size_t)NNN*DD;                  // NNN*DD bf16
  unsigned short* wb3 = nV + (size_t)NNN*DD;                 // CC*DD*3 bf16
  unsigned short* wb4 = wb3 + (size_t)CC*DD*3;
  unsigned short* wb5 = wb4 + (size_t)CC*DD*4;
  float* qh     = (float*)(wb5 + (size_t)CC*DD*5 + 4);       // 8B align ok
  float* o_at   = qh + (size_t)BB*LL*DD;
  float* doc    = o_at + (size_t)BB*LL*DD;
  float* convp  = doc + (size_t)BB*LL*DD;
  float* enc    = convp + BB*3*4*CC;
  float* meta_e = enc + (size_t)2*BB*SS*DD;
  const size_t need_bytes = (size_t)((char*)(meta_e + 2*BB*DD) - wsb);
  if (ws_size < need_bytes) return;

  k_projkv<<<dim3((NNN+63)/64), dim3(256), 0, stream>>>(news_table, wa_in_w, wa_in_b, nK, nV);
  k_qh<<<dim3(BB*LL/32), dim3(128), 0, stream>>>(word_table, nwi, wa_in_w, wa_in_b, qh);
  k_attn<<<dim3(BB*LL), dim3(128), 0, stream>>>(qh, nK, nV, ctx_ids, o_at);
  k_wo<<<dim3(BB*LL/32), dim3(128), 0, stream>>>(o_at, nwi, wa_out_w, wa_out_b, doc);
  k_convprep<<<dim3(320), dim3(256), 0, stream>>>(conv_w3, conv_w4, conv_w5, wb3, wb4, wb5);
  k_conv<<<dim3(BB*3*4), dim3(256), 0, stream>>>(doc, wb3, wb4, wb5, convp);
  k_gru<<<dim3(128), dim3(384), 0, stream>>>(news_table, user_table, source_table,
      news_ids, nsn_src, nsn_end, nun_usr, nun_end,
      wih0, whh0, bih0, bhh0, wih1, whh1, bih1, bhh1, enc);
  k_metamha<<<dim3(64), dim3(128), 0, stream>>>(enc,
      inw0, inb0, outw0, outb0, lng0, lnb0,
      inw1, inb1, outw1, outb1, lng1, lnb1, meta_e);
  k_final<<<dim3(BB), dim3(128), 0, stream>>>(convp, conv_b3, conv_b4, conv_b5,
      fc_w, fc_b, meta_e, mp_w1, mp_b1, mp_w2, mp_b2,
      cls_w1, cls_b1, cls_w2, cls_b2, (float*)d_out);
}

// Round 4
// 523.519 us; speedup vs baseline: 1.8347x; 1.1945x over previous
//
#include <hip/hip_runtime.h>
#include <hip/hip_bf16.h>

// Problem dims
#define BB 32
#define LL 256
#define KC 50
#define SS 16
#define DD 128
#define NH 4
#define CC 128
#define VV 50000
#define NNN 100000
#define NUU 50000
#define NSS 5000

typedef __attribute__((ext_vector_type(8))) short bf16x8;
typedef __attribute__((ext_vector_type(8))) unsigned short u16x8;
typedef __attribute__((ext_vector_type(4))) float f32x4;

__device__ __forceinline__ float dot4(float4 a, float4 b){
  return a.x*b.x + a.y*b.y + a.z*b.z + a.w*b.w;
}

__device__ __forceinline__ unsigned short f2bf(float f){
  union { float f; unsigned int u; } v; v.f = f;
  unsigned int r = (v.u + 0x7FFFu + ((v.u >> 16) & 1u)) >> 16;
  return (unsigned short)r;
}
__device__ __forceinline__ float bf2f(unsigned short s){
  union { unsigned int u; float f; } v; v.u = ((unsigned int)s) << 16;
  return v.f;
}

// ---------------------------------------------------------------------------
// 1) nK/nV = bf16( news_table @ [wk;wv]^T + [bk;bv] )  via MFMA 16x16x32 bf16
__global__ __launch_bounds__(256) void k_projkv(
    const float* __restrict__ news, const float* __restrict__ in_w,
    const float* __restrict__ in_b, unsigned short* __restrict__ nK,
    unsigned short* __restrict__ nV){
  __shared__ __align__(16) char smem[64*260*2];
  unsigned short* As = (unsigned short*)smem;      // [64][128] bf16
  unsigned short* Os = (unsigned short*)smem;      // [64][260] bf16 (pad 4)
  const int tid = threadIdx.x;
  const int r0 = blockIdx.x * 64;
  for (int i = tid; i < 64*32; i += 256){
    int row = i >> 5, j = i & 31;
    int gr = r0 + row;
    float4 v = (gr < NNN) ? ((const float4*)(news + (size_t)gr*DD))[j]
                          : make_float4(0.f,0.f,0.f,0.f);
    unsigned short* d = As + row*128 + j*4;
    d[0]=f2bf(v.x); d[1]=f2bf(v.y); d[2]=f2bf(v.z); d[3]=f2bf(v.w);
  }
  __syncthreads();
  const int wave = tid >> 6;
  const int lane = tid & 63;
  const int l15  = lane & 15;
  const int quad = lane >> 4;
  bf16x8 afr[4][4];
  #pragma unroll
  for (int mt=0; mt<4; mt++)
    #pragma unroll
    for (int ks=0; ks<4; ks++)
      afr[mt][ks] = *(const bf16x8*)(As + (mt*16 + l15)*128 + ks*32 + quad*8);
  __syncthreads();
  const int nbase = wave * 64;
  #pragma unroll
  for (int nt=0; nt<4; nt++){
    const int n0 = nbase + nt*16;
    const int wr = 128 + n0 + l15;
    bf16x8 bfr[4];
    #pragma unroll
    for (int ks=0; ks<4; ks++){
      const float4* p = (const float4*)(in_w + (size_t)wr*DD + ks*32 + quad*8);
      float4 v0 = p[0], v1 = p[1];
      bf16x8 b;
      b[0]=(short)f2bf(v0.x); b[1]=(short)f2bf(v0.y); b[2]=(short)f2bf(v0.z); b[3]=(short)f2bf(v0.w);
      b[4]=(short)f2bf(v1.x); b[5]=(short)f2bf(v1.y); b[6]=(short)f2bf(v1.z); b[7]=(short)f2bf(v1.w);
      bfr[ks] = b;
    }
    const float bias = in_b[wr];
    #pragma unroll
    for (int mt=0; mt<4; mt++){
      f32x4 acc = {0.f,0.f,0.f,0.f};
      #pragma unroll
      for (int ks=0; ks<4; ks++)
        acc = __builtin_amdgcn_mfma_f32_16x16x32_bf16(afr[mt][ks], bfr[ks], acc, 0,0,0);
      const int col = n0 + l15;
      const int rb  = mt*16 + quad*4;
      #pragma unroll
      for (int r=0;r<4;r++)
        Os[(rb + r)*260 + col] = f2bf(acc[r] + bias);
    }
  }
  __syncthreads();
  for (int c = tid; c < 64*64; c += 256){
    int row = c >> 6, col4 = (c & 63) * 4;
    int gr = r0 + row;
    if (gr >= NNN) continue;
    unsigned long long v = *(const unsigned long long*)(Os + row*260 + col4);
    if (col4 < 128) *(unsigned long long*)(nK + (size_t)gr*128 + col4) = v;
    else            *(unsigned long long*)(nV + (size_t)gr*128 + (col4-128)) = v;
  }
}

// ---------------------------------------------------------------------------
// 2) qh[p][c] = word_table[widx[p]] . wq[c] + bq[c]
__global__ __launch_bounds__(128, 2) void k_qh(
    const float* __restrict__ word_table, const int* __restrict__ widx,
    const float* __restrict__ in_w, const float* __restrict__ in_b,
    float* __restrict__ qh){
  __shared__ float xs[32][128];
  __shared__ int idx[32];
  const int c = threadIdx.x;
  float4 w[32];
  const float4* wr = (const float4*)(in_w + c*DD);
  #pragma unroll
  for (int j=0;j<32;j++) w[j] = wr[j];
  const float bias = in_b[c];
  const int p0 = blockIdx.x * 32;
  if (c < 32) idx[c] = widx[p0 + c];
  __syncthreads();
  for (int i=c; i<32*32; i+=128){
    int r = i>>5, j = i&31;
    ((float4*)xs[r])[j] = ((const float4*)(word_table + (size_t)idx[r]*DD))[j];
  }
  __syncthreads();
  for (int r=0;r<32;r++){
    const float4* x4 = (const float4*)xs[r];
    float acc = bias;
    #pragma unroll
    for (int j=0;j<32;j++) acc += dot4(w[j], x4[j]);
    qh[(size_t)(p0+r)*DD + c] = acc;
  }
}

// ---------------------------------------------------------------------------
// 3) per-(b,l) attention, one wave per token, 16B vector gathers.
//    lane = r*16 + g : r in [0,4) = row-subset, g in [0,16) = 8-dim group.
__global__ __launch_bounds__(64) void k_attn(
    const float* __restrict__ qh, const unsigned short* __restrict__ nK,
    const unsigned short* __restrict__ nV, const int* __restrict__ ctx_ids,
    float* __restrict__ o_out){
  const int p = blockIdx.x;
  const int lane = threadIdx.x;
  const int r = lane >> 4;
  const int g = lane & 15;
  const int h = g >> 2;           // head owning dims g*8..g*8+7
  __shared__ int ids[52];
  __shared__ float sc[NH][52];
  if (lane < KC) ids[lane] = ctx_ids[(size_t)p*KC + lane];
  float qv[8];
  {
    const float4* qp = (const float4*)(qh + (size_t)p*DD + g*8);
    float4 q0 = qp[0], q1 = qp[1];
    qv[0]=q0.x; qv[1]=q0.y; qv[2]=q0.z; qv[3]=q0.w;
    qv[4]=q1.x; qv[5]=q1.y; qv[6]=q1.z; qv[7]=q1.w;
  }
  __syncthreads();
  // scores: 13 iterations x 4 rows
  for (int kb=0; kb<13; kb++){
    int k2 = kb*4 + r;
    int row = ids[(k2 < KC) ? k2 : 0];
    u16x8 kv = *(const u16x8*)(nK + (size_t)row*DD + g*8);
    float pr = 0.f;
    #pragma unroll
    for (int j=0;j<8;j++) pr += qv[j]*bf2f(kv[j]);
    pr += __shfl_xor(pr, 1, 64);
    pr += __shfl_xor(pr, 2, 64);   // reduced over the 4 g's of head h
    if ((g & 3) == 0 && k2 < KC) sc[h][k2] = pr;
  }
  __syncthreads();
  // softmax: lane = (hh, kc); each handles k = kc, kc+16, kc+32, kc+48
  {
    const int hh = lane >> 4, kc = lane & 15;
    const float scale = 0.17677669529663687f;
    float mx = -1e30f;
    #pragma unroll
    for (int q4=0;q4<4;q4++){ int k2=kc+q4*16; if (k2<KC) mx = fmaxf(mx, sc[hh][k2]); }
    mx = fmaxf(mx, __shfl_xor(mx, 1, 64));
    mx = fmaxf(mx, __shfl_xor(mx, 2, 64));
    mx = fmaxf(mx, __shfl_xor(mx, 4, 64));
    mx = fmaxf(mx, __shfl_xor(mx, 8, 64));
    float sm = 0.f;
    float ev[4];
    #pragma unroll
    for (int q4=0;q4<4;q4++){
      int k2=kc+q4*16;
      ev[q4] = (k2<KC) ? __expf((sc[hh][k2]-mx)*scale) : 0.f;
      sm += ev[q4];
    }
    sm += __shfl_xor(sm, 1, 64);
    sm += __shfl_xor(sm, 2, 64);
    sm += __shfl_xor(sm, 4, 64);
    sm += __shfl_xor(sm, 8, 64);
    float inv = 1.f/sm;
    #pragma unroll
    for (int q4=0;q4<4;q4++){ int k2=kc+q4*16; if (k2<KC) sc[hh][k2] = ev[q4]*inv; }
  }
  __syncthreads();
  // V accumulate
  float acc[8];
  #pragma unroll
  for (int j=0;j<8;j++) acc[j]=0.f;
  for (int kb=0; kb<13; kb++){
    int k2 = kb*4 + r;
    int row = ids[(k2 < KC) ? k2 : 0];
    float w = (k2 < KC) ? sc[h][k2] : 0.f;
    u16x8 vv = *(const u16x8*)(nV + (size_t)row*DD + g*8);
    #pragma unroll
    for (int j=0;j<8;j++) acc[j] += w*bf2f(vv[j]);
  }
  #pragma unroll
  for (int j=0;j<8;j++){
    acc[j] += __shfl_xor(acc[j], 16, 64);
    acc[j] += __shfl_xor(acc[j], 32, 64);
  }
  if (r == 0){
    float4* op = (float4*)(o_out + (size_t)p*DD + g*8);
    op[0] = make_float4(acc[0],acc[1],acc[2],acc[3]);
    op[1] = make_float4(acc[4],acc[5],acc[6],acc[7]);
  }
}

// ---------------------------------------------------------------------------
// 4) doc = mask(widx==0) ? 0 : o @ wo^T + bo
__global__ __launch_bounds__(128, 2) void k_wo(
    const float* __restrict__ o_attn, const int* __restrict__ widx,
    const float* __restrict__ out_w, const float* __restrict__ out_b,
    float* __restrict__ doc){
  __shared__ float xs[32][128];
  const int c = threadIdx.x;
  float4 w[32];
  const float4* wr = (const float4*)(out_w + c*DD);
  #pragma unroll
  for (int j=0;j<32;j++) w[j] = wr[j];
  const float bias = out_b[c];
  const int p0 = blockIdx.x * 32;
  const float4* src = (const float4*)(o_attn + (size_t)p0*DD);
  float4* dst = (float4*)&xs[0][0];
  for (int i=c; i<32*32; i+=128) dst[i] = src[i];
  __syncthreads();
  for (int r=0;r<32;r++){
    const float4* x4 = (const float4*)xs[r];
    float acc = bias;
    #pragma unroll
    for (int j=0;j<32;j++) acc += dot4(w[j], x4[j]);
    int p = p0 + r;
    doc[(size_t)p*DD + c] = (widx[p] == 0) ? 0.0f : acc;
  }
}

// ---------------------------------------------------------------------------
// 5) conv weights -> bf16, layout wb[jj][c][d] per conv
__global__ __launch_bounds__(256) void k_convprep(
    const float* __restrict__ w3, const float* __restrict__ w4,
    const float* __restrict__ w5, unsigned short* __restrict__ wb3,
    unsigned short* __restrict__ wb4, unsigned short* __restrict__ wb5){
  int e = blockIdx.x*256 + threadIdx.x;
  if (e < CC*DD*3){ int c=e/(DD*3), rm=e%(DD*3), d=rm/3, jj=rm%3;
    wb3[((size_t)jj*CC + c)*DD + d] = f2bf(w3[e]); }
  if (e < CC*DD*4){ int c=e/(DD*4), rm=e%(DD*4), d=rm/4, jj=rm%4;
    wb4[((size_t)jj*CC + c)*DD + d] = f2bf(w4[e]); }
  if (e < CC*DD*5){ int c=e/(DD*5), rm=e%(DD*5), d=rm/5, jj=rm%5;
    wb5[((size_t)jj*CC + c)*DD + d] = f2bf(w5[e]); }
}

// ---------------------------------------------------------------------------
// 6) conv as MFMA GEMM + fused max-over-t.
#define CROWS 68
#define CPAD 136
__global__ __launch_bounds__(256) void k_conv(
    const float* __restrict__ doc, const unsigned short* __restrict__ wb3,
    const unsigned short* __restrict__ wb4, const unsigned short* __restrict__ wb5,
    float* __restrict__ convp){
  __shared__ __align__(16) char smem[CROWS*CPAD*2];
  unsigned short* ds = (unsigned short*)smem;
  float* smf = (float*)smem;
  const int blk = blockIdx.x;
  const int chunk = blk & 3;
  const int j = (blk >> 2) % 3;
  const int b = blk / 12;
  const int kk = 3 + j;
  const int T = LL - kk + 1;
  const int t0 = chunk * 64;
  const int nrows = 64 + kk - 1;
  const unsigned short* wb = (j==0) ? wb3 : (j==1) ? wb4 : wb5;
  const int tid = threadIdx.x;
  for (int i = tid; i < nrows*32; i += 256){
    int row = i >> 5, q4 = i & 31;
    int gt = t0 + row;
    float4 v = (gt < LL) ? ((const float4*)(doc + ((size_t)b*LL + gt)*DD))[q4]
                         : make_float4(0.f,0.f,0.f,0.f);
    unsigned short* dp = ds + row*CPAD + q4*4;
    dp[0]=f2bf(v.x); dp[1]=f2bf(v.y); dp[2]=f2bf(v.z); dp[3]=f2bf(v.w);
  }
  __syncthreads();
  const int wave = tid >> 6;
  const int lane = tid & 63;
  const int l15  = lane & 15;
  const int quad = lane >> 4;
  f32x4 acc[8];
  #pragma unroll
  for (int nt=0;nt<8;nt++) acc[nt] = (f32x4){0.f,0.f,0.f,0.f};
  for (int jj=0; jj<kk; jj++){
    #pragma unroll
    for (int ks=0; ks<4; ks++){
      bf16x8 af = *(const bf16x8*)(ds + (wave*16 + l15 + jj)*CPAD + ks*32 + quad*8);
      #pragma unroll
      for (int nt=0; nt<8; nt++){
        bf16x8 bf = *(const bf16x8*)(wb + ((size_t)jj*CC + nt*16 + l15)*DD + ks*32 + quad*8);
        acc[nt] = __builtin_amdgcn_mfma_f32_16x16x32_bf16(af, bf, acc[nt], 0,0,0);
      }
    }
  }
  __syncthreads();
  #pragma unroll
  for (int nt=0; nt<8; nt++){
    float mx = -1e30f;
    #pragma unroll
    for (int r=0;r<4;r++){
      int t = t0 + wave*16 + quad*4 + r;
      mx = fmaxf(mx, (t < T) ? acc[nt][r] : -1e30f);
    }
    mx = fmaxf(mx, __shfl_xor(mx, 16, 64));
    mx = fmaxf(mx, __shfl_xor(mx, 32, 64));
    if (quad == 0) smf[wave*128 + nt*16 + l15] = mx;
  }
  __syncthreads();
  if (tid < 128){
    float m4 = fmaxf(fmaxf(smf[tid], smf[128+tid]), fmaxf(smf[256+tid], smf[384+tid]));
    convp[(((size_t)b*3 + j)*4 + chunk)*CC + tid] = m4;
  }
}

// ---------------------------------------------------------------------------
// 7) GRU over 3 steps; block per (module, b, half-of-16-seqs); 384 threads
__global__ __launch_bounds__(384, 1) void k_gru(
    const float* __restrict__ news_table, const float* __restrict__ user_table,
    const float* __restrict__ source_table,
    const int* __restrict__ news_ids, const int* __restrict__ nsn_src,
    const int* __restrict__ nsn_end, const int* __restrict__ nun_usr,
    const int* __restrict__ nun_end,
    const float* __restrict__ wih0, const float* __restrict__ whh0,
    const float* __restrict__ bih0, const float* __restrict__ bhh0,
    const float* __restrict__ wih1, const float* __restrict__ whh1,
    const float* __restrict__ bih1, const float* __restrict__ bhh1,
    float* __restrict__ enc){
  const int gb = blockIdx.x;
  const int m  = gb >> 6;
  const int b  = (gb >> 1) & 31;
  const int s0 = (gb & 1) * 8;
  const int tid = threadIdx.x;
  __shared__ float xs[8][128], hs[8][128];
  __shared__ float gi[384][8], gh[384][8];
  const float* Wih = m ? wih1 : wih0;
  const float* Whh = m ? whh1 : whh0;
  const float* bih = m ? bih1 : bih0;
  const float* bhh = m ? bhh1 : bhh0;
  for (int i=tid;i<8*128;i+=384) ((float*)hs)[i] = 0.f;
  const float bi = bih[tid], bh = bhh[tid];
  const float4* wi4 = (const float4*)(Wih + tid*DD);
  const float4* wh4 = (const float4*)(Whh + tid*DD);
  for (int t=0;t<3;t++){
    __syncthreads();
    for (int i=tid;i<8*128;i+=384){
      int u = i>>7, d = i&127;
      int s = s0 + u;
      int row; const float* tab;
      if (t==0){ row = news_ids[b]; tab = news_table; }
      else if (t==1){ row = m ? nun_usr[b*SS+s] : nsn_src[b*SS+s];
                      tab = m ? user_table : source_table; }
      else { row = m ? nun_end[b*SS+s] : nsn_end[b*SS+s]; tab = news_table; }
      xs[u][d] = tab[(size_t)row*DD + d];
    }
    __syncthreads();
    float aI[8], aH[8];
    #pragma unroll
    for (int u=0;u<8;u++){ aI[u]=bi; aH[u]=bh; }
    for (int j=0;j<32;j++){
      float4 wiv = wi4[j], whv = wh4[j];
      #pragma unroll
      for (int u=0;u<8;u++){
        aI[u] += dot4(wiv, ((const float4*)xs[u])[j]);
        aH[u] += dot4(whv, ((const float4*)hs[u])[j]);
      }
    }
    #pragma unroll
    for (int u=0;u<8;u++){ gi[tid][u]=aI[u]; gh[tid][u]=aH[u]; }
    __syncthreads();
    if (tid < 128){
      #pragma unroll
      for (int u=0;u<8;u++){
        float r = 1.f/(1.f+__expf(-(gi[tid][u]+gh[tid][u])));
        float z = 1.f/(1.f+__expf(-(gi[128+tid][u]+gh[128+tid][u])));
        float n = tanhf(gi[256+tid][u] + r*gh[256+tid][u]);
        hs[u][tid] = (1.f-z)*n + z*hs[u][tid];
      }
    }
  }
  __syncthreads();
  for (int i=tid;i<8*128;i+=384){
    int u=i>>7, d=i&127;
    enc[(((size_t)m*BB + b)*SS + (s0+u))*DD + d] = hs[u][d];
  }
}

// ---------------------------------------------------------------------------
// 8) meta-path MHA + residual + LN + mean over s; block per (module, b)
__global__ __launch_bounds__(128, 2) void k_metamha(
    const float* __restrict__ enc,
    const float* __restrict__ inw0, const float* __restrict__ inb0,
    const float* __restrict__ outw0, const float* __restrict__ outb0,
    const float* __restrict__ lng0, const float* __restrict__ lnb0,
    const float* __restrict__ inw1, const float* __restrict__ inb1,
    const float* __restrict__ outw1, const float* __restrict__ outb1,
    const float* __restrict__ lng1, const float* __restrict__ lnb1,
    float* __restrict__ meta_e){
  const int m = blockIdx.x >> 5;
  const int b = blockIdx.x & 31;
  const int c = threadIdx.x;
  const float* in_w  = m?inw1:inw0;  const float* in_b  = m?inb1:inb0;
  const float* out_w = m?outw1:outw0; const float* out_b = m?outb1:outb0;
  const float* lng   = m?lng1:lng0;  const float* lnb   = m?lnb1:lnb0;
  __shared__ float e[16][128], q[16][128], k[16][128], v[16][128];
  __shared__ float at[4][16][16];
  __shared__ float mu[16], rs[16];
  const float* esrc = enc + ((size_t)m*BB + b)*SS*DD;
  for (int i=c;i<16*128;i+=128) ((float*)e)[i] = esrc[i];
  __syncthreads();
  {
    float aq[16], ak[16], av[16];
    float bq = in_b[c], bk = in_b[128+c], bv = in_b[256+c];
    #pragma unroll
    for (int s=0;s<16;s++){ aq[s]=bq; ak[s]=bk; av[s]=bv; }
    const float4* wq4 = (const float4*)(in_w + c*DD);
    const float4* wk4 = (const float4*)(in_w + (128+c)*DD);
    const float4* wv4 = (const float4*)(in_w + (256+c)*DD);
    for (int j=0;j<32;j++){
      float4 a0=wq4[j], a1=wk4[j], a2=wv4[j];
      #pragma unroll
      for (int s=0;s<16;s++){
        float4 ev = ((const float4*)e[s])[j];
        aq[s]+=dot4(a0,ev); ak[s]+=dot4(a1,ev); av[s]+=dot4(a2,ev);
      }
    }
    #pragma unroll
    for (int s=0;s<16;s++){ q[s][c]=aq[s]; k[s][c]=ak[s]; v[s][c]=av[s]; }
  }
  __syncthreads();
  for (int r=0;r<8;r++){
    int lin = r*128 + c;
    int h = lin >> 8, qi = (lin>>4)&15, ki = lin&15;
    float sum=0.f;
    const float* qp = &q[qi][h*32];
    const float* kp = &k[ki][h*32];
    for (int x=0;x<32;x++) sum += qp[x]*kp[x];
    at[h][qi][ki] = sum * 0.17677669529663687f;
  }
  __syncthreads();
  if (c < 64){
    int h = c>>4, qi = c&15;
    float mx=-1e30f;
    for (int ki=0;ki<16;ki++) mx = fmaxf(mx, at[h][qi][ki]);
    float sm=0.f;
    for (int ki=0;ki<16;ki++){ float ee=__expf(at[h][qi][ki]-mx); at[h][qi][ki]=ee; sm+=ee; }
    float inv=1.f/sm;
    for (int ki=0;ki<16;ki++) at[h][qi][ki]*=inv;
  }
  __syncthreads();
  {
    int h = c>>5;
    float o[16];
    #pragma unroll
    for (int s=0;s<16;s++){
      float acc=0.f;
      for (int ki=0;ki<16;ki++) acc += at[h][s][ki]*v[ki][c];
      o[s]=acc;
    }
    __syncthreads();
    #pragma unroll
    for (int s=0;s<16;s++) q[s][c]=o[s];
  }
  __syncthreads();
  {
    float ay[16];
    float bo = out_b[c];
    #pragma unroll
    for (int s=0;s<16;s++) ay[s] = bo + e[s][c];
    const float4* wo4 = (const float4*)(out_w + c*DD);
    for (int j=0;j<32;j++){
      float4 wv_ = wo4[j];
      #pragma unroll
      for (int s=0;s<16;s++) ay[s] += dot4(wv_, ((const float4*)q[s])[j]);
    }
    __syncthreads();
    #pragma unroll
    for (int s=0;s<16;s++) e[s][c] = ay[s];
  }
  __syncthreads();
  if (c < 16){
    float sm=0.f;
    for (int d=0;d<128;d++) sm += e[c][d];
    float mean = sm*(1.f/128.f);
    float vs=0.f;
    for (int d=0;d<128;d++){ float df = e[c][d]-mean; vs += df*df; }
    mu[c]=mean; rs[c]=rsqrtf(vs*(1.f/128.f) + 1e-5f);
  }
  __syncthreads();
  {
    float g = lng[c], bb2 = lnb[c];
    float acc=0.f;
    #pragma unroll
    for (int s=0;s<16;s++) acc += (e[s][c]-mu[s])*rs[s]*g + bb2;
    meta_e[((size_t)m*BB+b)*DD + c] = acc * (1.f/16.f);
  }
}

// ---------------------------------------------------------------------------
// 9) pool-reduce + fc + meta gate + classifier; block per b
__global__ __launch_bounds__(128) void k_final(
    const float* __restrict__ convp,
    const float* __restrict__ cb3, const float* __restrict__ cb4,
    const float* __restrict__ cb5,
    const float* __restrict__ fc_w, const float* __restrict__ fc_b,
    const float* __restrict__ meta_e,
    const float* __restrict__ mp_w1, const float* __restrict__ mp_b1,
    const float* __restrict__ mp_w2, const float* __restrict__ mp_b2,
    const float* __restrict__ cls_w1, const float* __restrict__ cls_b1,
    const float* __restrict__ cls_w2, const float* __restrict__ cls_b2,
    float* __restrict__ out){
  const int b = blockIdx.x;
  const int c = threadIdx.x;
  __shared__ float pooled[384];
  __shared__ float comb[256];
  __shared__ float hcls[128];
  __shared__ float tt[2][64];
  __shared__ float wsc[2];
  for (int idx=c; idx<384; idx+=128){
    int j = idx >> 7, cc2 = idx & 127;
    const float* base = convp + (((size_t)b*3 + j)*4)*CC + cc2;
    float mx = -1e30f;
    for (int ci=0;ci<4;ci++) mx = fmaxf(mx, base[ci*CC]);
    const float* cb = (j==0)?cb3:(j==1)?cb4:cb5;
    pooled[idx] = fmaxf(mx + cb[cc2], 0.f);
  }
  __syncthreads();
  {
    float acc = fc_b[c];
    const float* wr = fc_w + (size_t)c*384;
    for (int i=0;i<384;i++) acc += pooled[i]*wr[i];
    comb[c] = acc;
  }
  if (c < 64){
    for (int m=0;m<2;m++){
      const float* ev = meta_e + ((size_t)m*BB+b)*DD;
      float acc = mp_b1[c];
      const float* wr = mp_w1 + (size_t)c*DD;
      for (int i=0;i<DD;i++) acc += ev[i]*wr[i];
      tt[m][c] = tanhf(acc);
    }
  }
  __syncthreads();
  if (c == 0){
    float s0 = mp_b2[0], s1 = mp_b2[0];
    for (int j=0;j<64;j++){ s0 += tt[0][j]*mp_w2[j]; s1 += tt[1][j]*mp_w2[j]; }
    float mx = fmaxf(s0,s1);
    float e0 = __expf(s0-mx), e1 = __expf(s1-mx);
    wsc[0] = e0/(e0+e1); wsc[1] = e1/(e0+e1);
  }
  __syncthreads();
  comb[128+c] = wsc[0]*meta_e[((size_t)b)*DD + c]
              + wsc[1]*meta_e[((size_t)(BB+b))*DD + c];
  __syncthreads();
  {
    float acc = cls_b1[c];
    const float* wr = cls_w1 + (size_t)c*256;
    for (int i=0;i<256;i++) acc += comb[i]*wr[i];
    hcls[c] = fmaxf(acc, 0.f);
  }
  __syncthreads();
  if (c < 2){
    float acc = cls_b2[c];
    const float* wr = cls_w2 + (size_t)c*DD;
    for (int i=0;i<DD;i++) acc += hcls[i]*wr[i];
    out[b*2 + c] = acc;
  }
}

// ---------------------------------------------------------------------------
extern "C" void kernel_launch(void* const* d_in, const int* in_sizes, int n_in,
                              void* d_out, int out_size, void* d_ws, size_t ws_size,
                              hipStream_t stream){
  const int* news_ids = (const int*)d_in[0];
  const int* nwi      = (const int*)d_in[1];
  const int* ctx_ids  = (const int*)d_in[2];
  const int* nsn_src  = (const int*)d_in[3];
  const int* nsn_end  = (const int*)d_in[4];
  const int* nun_usr  = (const int*)d_in[5];
  const int* nun_end  = (const int*)d_in[6];
  const float* word_table   = (const float*)d_in[7];
  const float* news_table   = (const float*)d_in[8];
  const float* user_table   = (const float*)d_in[9];
  const float* source_table = (const float*)d_in[10];
  const float* wa_in_w  = (const float*)d_in[11];
  const float* wa_in_b  = (const float*)d_in[12];
  const float* wa_out_w = (const float*)d_in[13];
  const float* wa_out_b = (const float*)d_in[14];
  const float* conv_w3 = (const float*)d_in[15];
  const float* conv_b3 = (const float*)d_in[16];
  const float* conv_w4 = (const float*)d_in[17];
  const float* conv_b4 = (const float*)d_in[18];
  const float* conv_w5 = (const float*)d_in[19];
  const float* conv_b5 = (const float*)d_in[20];
  const float* fc_w = (const float*)d_in[21];
  const float* fc_b = (const float*)d_in[22];
  const float* wih0 = (const float*)d_in[23];
  const float* whh0 = (const float*)d_in[24];
  const float* bih0 = (const float*)d_in[25];
  const float* bhh0 = (const float*)d_in[26];
  const float* inw0 = (const float*)d_in[27];
  const float* inb0 = (const float*)d_in[28];
  const float* outw0 = (const float*)d_in[29];
  const float* outb0 = (const float*)d_in[30];
  const float* lng0 = (const float*)d_in[31];
  const float* lnb0 = (const float*)d_in[32];
  const float* wih1 = (const float*)d_in[33];
  const float* whh1 = (const float*)d_in[34];
  const float* bih1 = (const float*)d_in[35];
  const float* bhh1 = (const float*)d_in[36];
  const float* inw1 = (const float*)d_in[37];
  const float* inb1 = (const float*)d_in[38];
  const float* outw1 = (const float*)d_in[39];
  const float* outb1 = (const float*)d_in[40];
  const float* lng1 = (const float*)d_in[41];
  const float* lnb1 = (const float*)d_in[42];
  const float* mp_w1 = (const float*)d_in[43];
  const float* mp_b1 = (const float*)d_in[44];
  const float* mp_w2 = (const float*)d_in[45];
  const float* mp_b2 = (const float*)d_in[46];
  const float* cls_w1 = (const float*)d_in[47];
  const float* cls_b1 = (const float*)d_in[48];
  const float* cls_w2 = (const float*)d_in[49];
  const float* cls_b2 = (const float*)d_in[50];

  // workspace layout
  char* wsb = (char*)d_ws;
  unsigned short* nK = (unsigned short*)wsb;                 // NNN*DD bf16
  unsigned short* nV = nK + (size_t)NNN*DD;                  // NNN*DD bf16
  unsigned short* wb3 = nV + (size_t)NNN*DD;                 // CC*DD*3 bf16
  unsigned short* wb4 = wb3 + (size_t)CC*DD*3;
  unsigned short* wb5 = wb4 + (size_t)CC*DD*4;
  float* qh     = (float*)(wb5 + (size_t)CC*DD*5 + 4);
  float* o_at   = qh + (size_t)BB*LL*DD;
  float* doc    = o_at + (size_t)BB*LL*DD;
  float* convp  = doc + (size_t)BB*LL*DD;
  float* enc    = convp + BB*3*4*CC;
  float* meta_e = enc + (size_t)2*BB*SS*DD;
  const size_t need_bytes = (size_t)((char*)(meta_e + 2*BB*DD) - wsb);
  if (ws_size < need_bytes) return;

  k_projkv<<<dim3((NNN+63)/64), dim3(256), 0, stream>>>(news_table, wa_in_w, wa_in_b, nK, nV);
  k_qh<<<dim3(BB*LL/32), dim3(128), 0, stream>>>(word_table, nwi, wa_in_w, wa_in_b, qh);
  k_attn<<<dim3(BB*LL), dim3(64), 0, stream>>>(qh, nK, nV, ctx_ids, o_at);
  k_wo<<<dim3(BB*LL/32), dim3(128), 0, stream>>>(o_at, nwi, wa_out_w, wa_out_b, doc);
  k_convprep<<<dim3(320), dim3(256), 0, stream>>>(conv_w3, conv_w4, conv_w5, wb3, wb4, wb5);
  k_conv<<<dim3(BB*3*4), dim3(256), 0, stream>>>(doc, wb3, wb4, wb5, convp);
  k_gru<<<dim3(128), dim3(384), 0, stream>>>(news_table, user_table, source_table,
      news_ids, nsn_src, nsn_end, nun_usr, nun_end,
      wih0, whh0, bih0, bhh0, wih1, whh1, bih1, bhh1, enc);
  k_metamha<<<dim3(64), dim3(128), 0, stream>>>(enc,
      inw0, inb0, outw0, outb0, lng0, lnb0,
      inw1, inb1, outw1, outb1, lng1, lnb1, meta_e);
  k_final<<<dim3(BB), dim3(128), 0, stream>>>(convp, conv_b3, conv_b4, conv_b5,
      fc_w, fc_b, meta_e, mp_w1, mp_b1, mp_w2, mp_b2,
      cls_w1, cls_b1, cls_w2, cls_b2, (float*)d_out);
}

// Round 5
// 483.100 us; speedup vs baseline: 1.9882x; 1.0837x over previous
//
#include <hip/hip_runtime.h>
#include <hip/hip_bf16.h>

// Problem dims
#define BB 32
#define LL 256
#define KC 50
#define SS 16
#define DD 128
#define NH 4
#define CC 128
#define VV 50000
#define NNN 100000
#define NUU 50000
#define NSS 5000

typedef __attribute__((ext_vector_type(8))) short bf16x8;
typedef __attribute__((ext_vector_type(8))) unsigned short u16x8;
typedef __attribute__((ext_vector_type(4))) float f32x4;

__device__ __forceinline__ float dot4(float4 a, float4 b){
  return a.x*b.x + a.y*b.y + a.z*b.z + a.w*b.w;
}

__device__ __forceinline__ unsigned short f2bf(float f){
  union { float f; unsigned int u; } v; v.f = f;
  unsigned int r = (v.u + 0x7FFFu + ((v.u >> 16) & 1u)) >> 16;
  return (unsigned short)r;
}
__device__ __forceinline__ float bf2f(unsigned short s){
  union { unsigned int u; float f; } v; v.u = ((unsigned int)s) << 16;
  return v.f;
}

// ---------------------------------------------------------------------------
// 1) nK/nV = bf16( news_table @ [wk;wv]^T + [bk;bv] )  via MFMA 16x16x32 bf16
__global__ __launch_bounds__(256) void k_projkv(
    const float* __restrict__ news, const float* __restrict__ in_w,
    const float* __restrict__ in_b, unsigned short* __restrict__ nK,
    unsigned short* __restrict__ nV){
  __shared__ __align__(16) char smem[64*260*2];
  unsigned short* As = (unsigned short*)smem;      // [64][128] bf16
  unsigned short* Os = (unsigned short*)smem;      // [64][260] bf16 (pad 4)
  const int tid = threadIdx.x;
  const int r0 = blockIdx.x * 64;
  for (int i = tid; i < 64*32; i += 256){
    int row = i >> 5, j = i & 31;
    int gr = r0 + row;
    float4 v = (gr < NNN) ? ((const float4*)(news + (size_t)gr*DD))[j]
                          : make_float4(0.f,0.f,0.f,0.f);
    unsigned short* d = As + row*128 + j*4;
    d[0]=f2bf(v.x); d[1]=f2bf(v.y); d[2]=f2bf(v.z); d[3]=f2bf(v.w);
  }
  __syncthreads();
  const int wave = tid >> 6;
  const int lane = tid & 63;
  const int l15  = lane & 15;
  const int quad = lane >> 4;
  bf16x8 afr[4][4];
  #pragma unroll
  for (int mt=0; mt<4; mt++)
    #pragma unroll
    for (int ks=0; ks<4; ks++)
      afr[mt][ks] = *(const bf16x8*)(As + (mt*16 + l15)*128 + ks*32 + quad*8);
  __syncthreads();
  const int nbase = wave * 64;
  #pragma unroll
  for (int nt=0; nt<4; nt++){
    const int n0 = nbase + nt*16;
    const int wr = 128 + n0 + l15;
    bf16x8 bfr[4];
    #pragma unroll
    for (int ks=0; ks<4; ks++){
      const float4* p = (const float4*)(in_w + (size_t)wr*DD + ks*32 + quad*8);
      float4 v0 = p[0], v1 = p[1];
      bf16x8 b;
      b[0]=(short)f2bf(v0.x); b[1]=(short)f2bf(v0.y); b[2]=(short)f2bf(v0.z); b[3]=(short)f2bf(v0.w);
      b[4]=(short)f2bf(v1.x); b[5]=(short)f2bf(v1.y); b[6]=(short)f2bf(v1.z); b[7]=(short)f2bf(v1.w);
      bfr[ks] = b;
    }
    const float bias = in_b[wr];
    #pragma unroll
    for (int mt=0; mt<4; mt++){
      f32x4 acc = {0.f,0.f,0.f,0.f};
      #pragma unroll
      for (int ks=0; ks<4; ks++)
        acc = __builtin_amdgcn_mfma_f32_16x16x32_bf16(afr[mt][ks], bfr[ks], acc, 0,0,0);
      const int col = n0 + l15;
      const int rb  = mt*16 + quad*4;
      #pragma unroll
      for (int r=0;r<4;r++)
        Os[(rb + r)*260 + col] = f2bf(acc[r] + bias);
    }
  }
  __syncthreads();
  for (int c = tid; c < 64*64; c += 256){
    int row = c >> 6, col4 = (c & 63) * 4;
    int gr = r0 + row;
    if (gr >= NNN) continue;
    unsigned long long v = *(const unsigned long long*)(Os + row*260 + col4);
    if (col4 < 128) *(unsigned long long*)(nK + (size_t)gr*128 + col4) = v;
    else            *(unsigned long long*)(nV + (size_t)gr*128 + (col4-128)) = v;
  }
}

// ---------------------------------------------------------------------------
// 2) qh[p][c] = word_table[widx[p]] . wq[c] + bq[c]
__global__ __launch_bounds__(128, 2) void k_qh(
    const float* __restrict__ word_table, const int* __restrict__ widx,
    const float* __restrict__ in_w, const float* __restrict__ in_b,
    float* __restrict__ qh){
  __shared__ float xs[32][128];
  __shared__ int idx[32];
  const int c = threadIdx.x;
  float4 w[32];
  const float4* wr = (const float4*)(in_w + c*DD);
  #pragma unroll
  for (int j=0;j<32;j++) w[j] = wr[j];
  const float bias = in_b[c];
  const int p0 = blockIdx.x * 32;
  if (c < 32) idx[c] = widx[p0 + c];
  __syncthreads();
  for (int i=c; i<32*32; i+=128){
    int r = i>>5, j = i&31;
    ((float4*)xs[r])[j] = ((const float4*)(word_table + (size_t)idx[r]*DD))[j];
  }
  __syncthreads();
  for (int r=0;r<32;r++){
    const float4* x4 = (const float4*)xs[r];
    float acc = bias;
    #pragma unroll
    for (int j=0;j<32;j++) acc += dot4(w[j], x4[j]);
    qh[(size_t)(p0+r)*DD + c] = acc;
  }
}

// ---------------------------------------------------------------------------
// 3) per-(b,l) attention, one wave per token, 16B vector gathers.
__global__ __launch_bounds__(64) void k_attn(
    const float* __restrict__ qh, const unsigned short* __restrict__ nK,
    const unsigned short* __restrict__ nV, const int* __restrict__ ctx_ids,
    float* __restrict__ o_out){
  const int p = blockIdx.x;
  const int lane = threadIdx.x;
  const int r = lane >> 4;
  const int g = lane & 15;
  const int h = g >> 2;
  __shared__ int ids[52];
  __shared__ float sc[NH][52];
  if (lane < KC) ids[lane] = ctx_ids[(size_t)p*KC + lane];
  float qv[8];
  {
    const float4* qp = (const float4*)(qh + (size_t)p*DD + g*8);
    float4 q0 = qp[0], q1 = qp[1];
    qv[0]=q0.x; qv[1]=q0.y; qv[2]=q0.z; qv[3]=q0.w;
    qv[4]=q1.x; qv[5]=q1.y; qv[6]=q1.z; qv[7]=q1.w;
  }
  __syncthreads();
  for (int kb=0; kb<13; kb++){
    int k2 = kb*4 + r;
    int row = ids[(k2 < KC) ? k2 : 0];
    u16x8 kv = *(const u16x8*)(nK + (size_t)row*DD + g*8);
    float pr = 0.f;
    #pragma unroll
    for (int j=0;j<8;j++) pr += qv[j]*bf2f(kv[j]);
    pr += __shfl_xor(pr, 1, 64);
    pr += __shfl_xor(pr, 2, 64);
    if ((g & 3) == 0 && k2 < KC) sc[h][k2] = pr;
  }
  __syncthreads();
  {
    const int hh = lane >> 4, kc = lane & 15;
    const float scale = 0.17677669529663687f;
    float mx = -1e30f;
    #pragma unroll
    for (int q4=0;q4<4;q4++){ int k2=kc+q4*16; if (k2<KC) mx = fmaxf(mx, sc[hh][k2]); }
    mx = fmaxf(mx, __shfl_xor(mx, 1, 64));
    mx = fmaxf(mx, __shfl_xor(mx, 2, 64));
    mx = fmaxf(mx, __shfl_xor(mx, 4, 64));
    mx = fmaxf(mx, __shfl_xor(mx, 8, 64));
    float sm = 0.f;
    float ev[4];
    #pragma unroll
    for (int q4=0;q4<4;q4++){
      int k2=kc+q4*16;
      ev[q4] = (k2<KC) ? __expf((sc[hh][k2]-mx)*scale) : 0.f;
      sm += ev[q4];
    }
    sm += __shfl_xor(sm, 1, 64);
    sm += __shfl_xor(sm, 2, 64);
    sm += __shfl_xor(sm, 4, 64);
    sm += __shfl_xor(sm, 8, 64);
    float inv = 1.f/sm;
    #pragma unroll
    for (int q4=0;q4<4;q4++){ int k2=kc+q4*16; if (k2<KC) sc[hh][k2] = ev[q4]*inv; }
  }
  __syncthreads();
  float acc[8];
  #pragma unroll
  for (int j=0;j<8;j++) acc[j]=0.f;
  for (int kb=0; kb<13; kb++){
    int k2 = kb*4 + r;
    int row = ids[(k2 < KC) ? k2 : 0];
    float w = (k2 < KC) ? sc[h][k2] : 0.f;
    u16x8 vv = *(const u16x8*)(nV + (size_t)row*DD + g*8);
    #pragma unroll
    for (int j=0;j<8;j++) acc[j] += w*bf2f(vv[j]);
  }
  #pragma unroll
  for (int j=0;j<8;j++){
    acc[j] += __shfl_xor(acc[j], 16, 64);
    acc[j] += __shfl_xor(acc[j], 32, 64);
  }
  if (r == 0){
    float4* op = (float4*)(o_out + (size_t)p*DD + g*8);
    op[0] = make_float4(acc[0],acc[1],acc[2],acc[3]);
    op[1] = make_float4(acc[4],acc[5],acc[6],acc[7]);
  }
}

// ---------------------------------------------------------------------------
// 4) doc = mask(widx==0) ? 0 : o @ wo^T + bo
__global__ __launch_bounds__(128, 2) void k_wo(
    const float* __restrict__ o_attn, const int* __restrict__ widx,
    const float* __restrict__ out_w, const float* __restrict__ out_b,
    float* __restrict__ doc){
  __shared__ float xs[32][128];
  const int c = threadIdx.x;
  float4 w[32];
  const float4* wr = (const float4*)(out_w + c*DD);
  #pragma unroll
  for (int j=0;j<32;j++) w[j] = wr[j];
  const float bias = out_b[c];
  const int p0 = blockIdx.x * 32;
  const float4* src = (const float4*)(o_attn + (size_t)p0*DD);
  float4* dst = (float4*)&xs[0][0];
  for (int i=c; i<32*32; i+=128) dst[i] = src[i];
  __syncthreads();
  for (int r=0;r<32;r++){
    const float4* x4 = (const float4*)xs[r];
    float acc = bias;
    #pragma unroll
    for (int j=0;j<32;j++) acc += dot4(w[j], x4[j]);
    int p = p0 + r;
    doc[(size_t)p*DD + c] = (widx[p] == 0) ? 0.0f : acc;
  }
}

// ---------------------------------------------------------------------------
// 5) conv weights -> bf16, layout wb[jj][c][d] per conv
__global__ __launch_bounds__(256) void k_convprep(
    const float* __restrict__ w3, const float* __restrict__ w4,
    const float* __restrict__ w5, unsigned short* __restrict__ wb3,
    unsigned short* __restrict__ wb4, unsigned short* __restrict__ wb5){
  int e = blockIdx.x*256 + threadIdx.x;
  if (e < CC*DD*3){ int c=e/(DD*3), rm=e%(DD*3), d=rm/3, jj=rm%3;
    wb3[((size_t)jj*CC + c)*DD + d] = f2bf(w3[e]); }
  if (e < CC*DD*4){ int c=e/(DD*4), rm=e%(DD*4), d=rm/4, jj=rm%4;
    wb4[((size_t)jj*CC + c)*DD + d] = f2bf(w4[e]); }
  if (e < CC*DD*5){ int c=e/(DD*5), rm=e%(DD*5), d=rm/5, jj=rm%5;
    wb5[((size_t)jj*CC + c)*DD + d] = f2bf(w5[e]); }
}

// ---------------------------------------------------------------------------
// 5b) GRU weights -> bf16, contiguous cast: wgb = [m][ih/hh][384][128]
__global__ __launch_bounds__(256) void k_gruprep(
    const float* __restrict__ wih0, const float* __restrict__ whh0,
    const float* __restrict__ wih1, const float* __restrict__ whh1,
    unsigned short* __restrict__ wgb){
  int e = blockIdx.x*256 + threadIdx.x;
  if (e < 384*DD){
    wgb[e]            = f2bf(wih0[e]);
    wgb[49152 + e]    = f2bf(whh0[e]);
    wgb[98304 + e]    = f2bf(wih1[e]);
    wgb[147456 + e]   = f2bf(whh1[e]);
  }
}

// ---------------------------------------------------------------------------
// 6) conv as MFMA GEMM + fused max-over-t.
#define CROWS 68
#define CPAD 136
__global__ __launch_bounds__(256) void k_conv(
    const float* __restrict__ doc, const unsigned short* __restrict__ wb3,
    const unsigned short* __restrict__ wb4, const unsigned short* __restrict__ wb5,
    float* __restrict__ convp){
  __shared__ __align__(16) char smem[CROWS*CPAD*2];
  unsigned short* ds = (unsigned short*)smem;
  float* smf = (float*)smem;
  const int blk = blockIdx.x;
  const int chunk = blk & 3;
  const int j = (blk >> 2) % 3;
  const int b = blk / 12;
  const int kk = 3 + j;
  const int T = LL - kk + 1;
  const int t0 = chunk * 64;
  const int nrows = 64 + kk - 1;
  const unsigned short* wb = (j==0) ? wb3 : (j==1) ? wb4 : wb5;
  const int tid = threadIdx.x;
  for (int i = tid; i < nrows*32; i += 256){
    int row = i >> 5, q4 = i & 31;
    int gt = t0 + row;
    float4 v = (gt < LL) ? ((const float4*)(doc + ((size_t)b*LL + gt)*DD))[q4]
                         : make_float4(0.f,0.f,0.f,0.f);
    unsigned short* dp = ds + row*CPAD + q4*4;
    dp[0]=f2bf(v.x); dp[1]=f2bf(v.y); dp[2]=f2bf(v.z); dp[3]=f2bf(v.w);
  }
  __syncthreads();
  const int wave = tid >> 6;
  const int lane = tid & 63;
  const int l15  = lane & 15;
  const int quad = lane >> 4;
  f32x4 acc[8];
  #pragma unroll
  for (int nt=0;nt<8;nt++) acc[nt] = (f32x4){0.f,0.f,0.f,0.f};
  for (int jj=0; jj<kk; jj++){
    #pragma unroll
    for (int ks=0; ks<4; ks++){
      bf16x8 af = *(const bf16x8*)(ds + (wave*16 + l15 + jj)*CPAD + ks*32 + quad*8);
      #pragma unroll
      for (int nt=0; nt<8; nt++){
        bf16x8 bf = *(const bf16x8*)(wb + ((size_t)jj*CC + nt*16 + l15)*DD + ks*32 + quad*8);
        acc[nt] = __builtin_amdgcn_mfma_f32_16x16x32_bf16(af, bf, acc[nt], 0,0,0);
      }
    }
  }
  __syncthreads();
  #pragma unroll
  for (int nt=0; nt<8; nt++){
    float mx = -1e30f;
    #pragma unroll
    for (int r=0;r<4;r++){
      int t = t0 + wave*16 + quad*4 + r;
      mx = fmaxf(mx, (t < T) ? acc[nt][r] : -1e30f);
    }
    mx = fmaxf(mx, __shfl_xor(mx, 16, 64));
    mx = fmaxf(mx, __shfl_xor(mx, 32, 64));
    if (quad == 0) smf[wave*128 + nt*16 + l15] = mx;
  }
  __syncthreads();
  if (tid < 128){
    float m4 = fmaxf(fmaxf(smf[tid], smf[128+tid]), fmaxf(smf[256+tid], smf[384+tid]));
    convp[(((size_t)b*3 + j)*4 + chunk)*CC + tid] = m4;
  }
}

// ---------------------------------------------------------------------------
// 7) GRU via MFMA; block per (module, b, 8-seq half); 256 thr = 4 waves.
//    x/h mirrored bf16 in LDS (M-tile padded 8->16); h master fp32 in LDS.
#define GSTR 392
__global__ __launch_bounds__(256) void k_gru(
    const float* __restrict__ news_table, const float* __restrict__ user_table,
    const float* __restrict__ source_table,
    const int* __restrict__ news_ids, const int* __restrict__ nsn_src,
    const int* __restrict__ nsn_end, const int* __restrict__ nun_usr,
    const int* __restrict__ nun_end,
    const unsigned short* __restrict__ wgb,
    const float* __restrict__ bih0, const float* __restrict__ bhh0,
    const float* __restrict__ bih1, const float* __restrict__ bhh1,
    float* __restrict__ enc){
  __shared__ __align__(16) unsigned short xs[16][CPAD];
  __shared__ __align__(16) unsigned short hs[16][CPAD];
  __shared__ float hf[8][128];
  __shared__ float gi[8][GSTR];
  __shared__ float gh[8][GSTR];
  const int blk = blockIdx.x;
  const int m  = blk >> 6;
  const int b  = (blk >> 1) & 31;
  const int s0 = (blk & 1) * 8;
  const int tid = threadIdx.x;
  const int wave = tid >> 6, lane = tid & 63, l15 = lane & 15, quad = lane >> 4;
  const unsigned short* Wih = wgb + (size_t)m*2*384*DD;
  const unsigned short* Whh = Wih + 384*DD;
  const float* bih = m ? bih1 : bih0;
  const float* bhh = m ? bhh1 : bhh0;
  for (int i=tid;i<16*CPAD;i+=256){ (&xs[0][0])[i]=0; (&hs[0][0])[i]=0; }
  for (int i=tid;i<8*128;i+=256) (&hf[0][0])[i]=0.f;
  __syncthreads();
  for (int t=0;t<3;t++){
    {
      int s = tid >> 5, j = tid & 31;
      int row; const float* tab;
      if (t==0){ row = news_ids[b]; tab = news_table; }
      else if (t==1){ row = m ? nun_usr[b*SS+s0+s] : nsn_src[b*SS+s0+s];
                      tab = m ? user_table : source_table; }
      else { row = m ? nun_end[b*SS+s0+s] : nsn_end[b*SS+s0+s]; tab = news_table; }
      float4 v = ((const float4*)(tab + (size_t)row*DD))[j];
      unsigned short* dp = &xs[s][j*4];
      dp[0]=f2bf(v.x); dp[1]=f2bf(v.y); dp[2]=f2bf(v.z); dp[3]=f2bf(v.w);
    }
    __syncthreads();
    bf16x8 ax[4], ah[4];
    #pragma unroll
    for (int ks=0;ks<4;ks++){
      ax[ks] = *(const bf16x8*)&xs[l15][ks*32+quad*8];
      ah[ks] = *(const bf16x8*)&hs[l15][ks*32+quad*8];
    }
    #pragma unroll
    for (int nt=0;nt<6;nt++){
      const int n0 = wave*96 + nt*16;
      f32x4 ga = {0.f,0.f,0.f,0.f}, ha = {0.f,0.f,0.f,0.f};
      #pragma unroll
      for (int ks=0;ks<4;ks++){
        bf16x8 bi = *(const bf16x8*)(Wih + (size_t)(n0+l15)*DD + ks*32+quad*8);
        ga = __builtin_amdgcn_mfma_f32_16x16x32_bf16(ax[ks], bi, ga, 0,0,0);
        bf16x8 bh = *(const bf16x8*)(Whh + (size_t)(n0+l15)*DD + ks*32+quad*8);
        ha = __builtin_amdgcn_mfma_f32_16x16x32_bf16(ah[ks], bh, ha, 0,0,0);
      }
      if (quad < 2){
        #pragma unroll
        for (int r=0;r<4;r++){
          gi[quad*4+r][n0+l15] = ga[r];
          gh[quad*4+r][n0+l15] = ha[r];
        }
      }
    }
    __syncthreads();
    #pragma unroll
    for (int k=0;k<4;k++){
      int it = tid + k*256;
      int s = it >> 7, g = it & 127;
      float rr = 1.f/(1.f+__expf(-(gi[s][g] + gh[s][g] + bih[g] + bhh[g])));
      float zz = 1.f/(1.f+__expf(-(gi[s][128+g] + gh[s][128+g] + bih[128+g] + bhh[128+g])));
      float nn = tanhf(gi[s][256+g] + bih[256+g] + rr*(gh[s][256+g] + bhh[256+g]));
      float hnew = (1.f-zz)*nn + zz*hf[s][g];
      hf[s][g] = hnew;
      hs[s][g] = f2bf(hnew);
    }
    __syncthreads();
  }
  {
    int s = tid >> 5, j = tid & 31;
    float4 v = ((const float4*)hf[s])[j];
    ((float4*)(enc + (((size_t)m*BB + b)*SS + (s0+s))*DD))[j] = v;
  }
}

// ---------------------------------------------------------------------------
// 8) meta-path MHA + residual + LN + mean over s; block per (module, b)
__global__ __launch_bounds__(128, 2) void k_metamha(
    const float* __restrict__ enc,
    const float* __restrict__ inw0, const float* __restrict__ inb0,
    const float* __restrict__ outw0, const float* __restrict__ outb0,
    const float* __restrict__ lng0, const float* __restrict__ lnb0,
    const float* __restrict__ inw1, const float* __restrict__ inb1,
    const float* __restrict__ outw1, const float* __restrict__ outb1,
    const float* __restrict__ lng1, const float* __restrict__ lnb1,
    float* __restrict__ meta_e){
  const int m = blockIdx.x >> 5;
  const int b = blockIdx.x & 31;
  const int c = threadIdx.x;
  const float* in_w  = m?inw1:inw0;  const float* in_b  = m?inb1:inb0;
  const float* out_w = m?outw1:outw0; const float* out_b = m?outb1:outb0;
  const float* lng   = m?lng1:lng0;  const float* lnb   = m?lnb1:lnb0;
  __shared__ float e[16][128], q[16][128], k[16][128], v[16][128];
  __shared__ float at[4][16][16];
  __shared__ float mu[16], rs[16];
  const float* esrc = enc + ((size_t)m*BB + b)*SS*DD;
  for (int i=c;i<16*128;i+=128) ((float*)e)[i] = esrc[i];
  __syncthreads();
  {
    float aq[16], ak[16], av[16];
    float bq = in_b[c], bk = in_b[128+c], bv = in_b[256+c];
    #pragma unroll
    for (int s=0;s<16;s++){ aq[s]=bq; ak[s]=bk; av[s]=bv; }
    const float4* wq4 = (const float4*)(in_w + c*DD);
    const float4* wk4 = (const float4*)(in_w + (128+c)*DD);
    const float4* wv4 = (const float4*)(in_w + (256+c)*DD);
    for (int j=0;j<32;j++){
      float4 a0=wq4[j], a1=wk4[j], a2=wv4[j];
      #pragma unroll
      for (int s=0;s<16;s++){
        float4 ev = ((const float4*)e[s])[j];
        aq[s]+=dot4(a0,ev); ak[s]+=dot4(a1,ev); av[s]+=dot4(a2,ev);
      }
    }
    #pragma unroll
    for (int s=0;s<16;s++){ q[s][c]=aq[s]; k[s][c]=ak[s]; v[s][c]=av[s]; }
  }
  __syncthreads();
  for (int r=0;r<8;r++){
    int lin = r*128 + c;
    int h = lin >> 8, qi = (lin>>4)&15, ki = lin&15;
    float sum=0.f;
    const float* qp = &q[qi][h*32];
    const float* kp = &k[ki][h*32];
    for (int x=0;x<32;x++) sum += qp[x]*kp[x];
    at[h][qi][ki] = sum * 0.17677669529663687f;
  }
  __syncthreads();
  if (c < 64){
    int h = c>>4, qi = c&15;
    float mx=-1e30f;
    for (int ki=0;ki<16;ki++) mx = fmaxf(mx, at[h][qi][ki]);
    float sm=0.f;
    for (int ki=0;ki<16;ki++){ float ee=__expf(at[h][qi][ki]-mx); at[h][qi][ki]=ee; sm+=ee; }
    float inv=1.f/sm;
    for (int ki=0;ki<16;ki++) at[h][qi][ki]*=inv;
  }
  __syncthreads();
  {
    int h = c>>5;
    float o[16];
    #pragma unroll
    for (int s=0;s<16;s++){
      float acc=0.f;
      for (int ki=0;ki<16;ki++) acc += at[h][s][ki]*v[ki][c];
      o[s]=acc;
    }
    __syncthreads();
    #pragma unroll
    for (int s=0;s<16;s++) q[s][c]=o[s];
  }
  __syncthreads();
  {
    float ay[16];
    float bo = out_b[c];
    #pragma unroll
    for (int s=0;s<16;s++) ay[s] = bo + e[s][c];
    const float4* wo4 = (const float4*)(out_w + c*DD);
    for (int j=0;j<32;j++){
      float4 wv_ = wo4[j];
      #pragma unroll
      for (int s=0;s<16;s++) ay[s] += dot4(wv_, ((const float4*)q[s])[j]);
    }
    __syncthreads();
    #pragma unroll
    for (int s=0;s<16;s++) e[s][c] = ay[s];
  }
  __syncthreads();
  if (c < 16){
    float sm=0.f;
    for (int d=0;d<128;d++) sm += e[c][d];
    float mean = sm*(1.f/128.f);
    float vs=0.f;
    for (int d=0;d<128;d++){ float df = e[c][d]-mean; vs += df*df; }
    mu[c]=mean; rs[c]=rsqrtf(vs*(1.f/128.f) + 1e-5f);
  }
  __syncthreads();
  {
    float g = lng[c], bb2 = lnb[c];
    float acc=0.f;
    #pragma unroll
    for (int s=0;s<16;s++) acc += (e[s][c]-mu[s])*rs[s]*g + bb2;
    meta_e[((size_t)m*BB+b)*DD + c] = acc * (1.f/16.f);
  }
}

// ---------------------------------------------------------------------------
// 9) pool-reduce + fc + meta gate + classifier; block per b
__global__ __launch_bounds__(128) void k_final(
    const float* __restrict__ convp,
    const float* __restrict__ cb3, const float* __restrict__ cb4,
    const float* __restrict__ cb5,
    const float* __restrict__ fc_w, const float* __restrict__ fc_b,
    const float* __restrict__ meta_e,
    const float* __restrict__ mp_w1, const float* __restrict__ mp_b1,
    const float* __restrict__ mp_w2, const float* __restrict__ mp_b2,
    const float* __restrict__ cls_w1, const float* __restrict__ cls_b1,
    const float* __restrict__ cls_w2, const float* __restrict__ cls_b2,
    float* __restrict__ out){
  const int b = blockIdx.x;
  const int c = threadIdx.x;
  __shared__ float pooled[384];
  __shared__ float comb[256];
  __shared__ float hcls[128];
  __shared__ float tt[2][64];
  __shared__ float wsc[2];
  for (int idx=c; idx<384; idx+=128){
    int j = idx >> 7, cc2 = idx & 127;
    const float* base = convp + (((size_t)b*3 + j)*4)*CC + cc2;
    float mx = -1e30f;
    for (int ci=0;ci<4;ci++) mx = fmaxf(mx, base[ci*CC]);
    const float* cb = (j==0)?cb3:(j==1)?cb4:cb5;
    pooled[idx] = fmaxf(mx + cb[cc2], 0.f);
  }
  __syncthreads();
  {
    float acc = fc_b[c];
    const float* wr = fc_w + (size_t)c*384;
    for (int i=0;i<384;i++) acc += pooled[i]*wr[i];
    comb[c] = acc;
  }
  if (c < 64){
    for (int m=0;m<2;m++){
      const float* ev = meta_e + ((size_t)m*BB+b)*DD;
      float acc = mp_b1[c];
      const float* wr = mp_w1 + (size_t)c*DD;
      for (int i=0;i<DD;i++) acc += ev[i]*wr[i];
      tt[m][c] = tanhf(acc);
    }
  }
  __syncthreads();
  if (c == 0){
    float s0 = mp_b2[0], s1 = mp_b2[0];
    for (int j=0;j<64;j++){ s0 += tt[0][j]*mp_w2[j]; s1 += tt[1][j]*mp_w2[j]; }
    float mx = fmaxf(s0,s1);
    float e0 = __expf(s0-mx), e1 = __expf(s1-mx);
    wsc[0] = e0/(e0+e1); wsc[1] = e1/(e0+e1);
  }
  __syncthreads();
  comb[128+c] = wsc[0]*meta_e[((size_t)b)*DD + c]
              + wsc[1]*meta_e[((size_t)(BB+b))*DD + c];
  __syncthreads();
  {
    float acc = cls_b1[c];
    const float* wr = cls_w1 + (size_t)c*256;
    for (int i=0;i<256;i++) acc += comb[i]*wr[i];
    hcls[c] = fmaxf(acc, 0.f);
  }
  __syncthreads();
  if (c < 2){
    float acc = cls_b2[c];
    const float* wr = cls_w2 + (size_t)c*DD;
    for (int i=0;i<DD;i++) acc += hcls[i]*wr[i];
    out[b*2 + c] = acc;
  }
}

// ---------------------------------------------------------------------------
extern "C" void kernel_launch(void* const* d_in, const int* in_sizes, int n_in,
                              void* d_out, int out_size, void* d_ws, size_t ws_size,
                              hipStream_t stream){
  const int* news_ids = (const int*)d_in[0];
  const int* nwi      = (const int*)d_in[1];
  const int* ctx_ids  = (const int*)d_in[2];
  const int* nsn_src  = (const int*)d_in[3];
  const int* nsn_end  = (const int*)d_in[4];
  const int* nun_usr  = (const int*)d_in[5];
  const int* nun_end  = (const int*)d_in[6];
  const float* word_table   = (const float*)d_in[7];
  const float* news_table   = (const float*)d_in[8];
  const float* user_table   = (const float*)d_in[9];
  const float* source_table = (const float*)d_in[10];
  const float* wa_in_w  = (const float*)d_in[11];
  const float* wa_in_b  = (const float*)d_in[12];
  const float* wa_out_w = (const float*)d_in[13];
  const float* wa_out_b = (const float*)d_in[14];
  const float* conv_w3 = (const float*)d_in[15];
  const float* conv_b3 = (const float*)d_in[16];
  const float* conv_w4 = (const float*)d_in[17];
  const float* conv_b4 = (const float*)d_in[18];
  const float* conv_w5 = (const float*)d_in[19];
  const float* conv_b5 = (const float*)d_in[20];
  const float* fc_w = (const float*)d_in[21];
  const float* fc_b = (const float*)d_in[22];
  const float* wih0 = (const float*)d_in[23];
  const float* whh0 = (const float*)d_in[24];
  const float* bih0 = (const float*)d_in[25];
  const float* bhh0 = (const float*)d_in[26];
  const float* inw0 = (const float*)d_in[27];
  const float* inb0 = (const float*)d_in[28];
  const float* outw0 = (const float*)d_in[29];
  const float* outb0 = (const float*)d_in[30];
  const float* lng0 = (const float*)d_in[31];
  const float* lnb0 = (const float*)d_in[32];
  const float* wih1 = (const float*)d_in[33];
  const float* whh1 = (const float*)d_in[34];
  const float* bih1 = (const float*)d_in[35];
  const float* bhh1 = (const float*)d_in[36];
  const float* inw1 = (const float*)d_in[37];
  const float* inb1 = (const float*)d_in[38];
  const float* outw1 = (const float*)d_in[39];
  const float* outb1 = (const float*)d_in[40];
  const float* lng1 = (const float*)d_in[41];
  const float* lnb1 = (const float*)d_in[42];
  const float* mp_w1 = (const float*)d_in[43];
  const float* mp_b1 = (const float*)d_in[44];
  const float* mp_w2 = (const float*)d_in[45];
  const float* mp_b2 = (const float*)d_in[46];
  const float* cls_w1 = (const float*)d_in[47];
  const float* cls_b1 = (const float*)d_in[48];
  const float* cls_w2 = (const float*)d_in[49];
  const float* cls_b2 = (const float*)d_in[50];

  // workspace layout
  char* wsb = (char*)d_ws;
  unsigned short* nK = (unsigned short*)wsb;                 // NNN*DD bf16
  unsigned short* nV = nK + (size_t)NNN*DD;                  // NNN*DD bf16
  unsigned short* wb3 = nV + (size_t)NNN*DD;                 // CC*DD*3 bf16
  unsigned short* wb4 = wb3 + (size_t)CC*DD*3;
  unsigned short* wb5 = wb4 + (size_t)CC*DD*4;
  unsigned short* wgb = wb5 + (size_t)CC*DD*5;               // 4*384*128 bf16
  float* qh     = (float*)(wgb + (size_t)4*384*DD);
  float* o_at   = qh + (size_t)BB*LL*DD;
  float* doc    = o_at + (size_t)BB*LL*DD;
  float* convp  = doc + (size_t)BB*LL*DD;
  float* enc    = convp + BB*3*4*CC;
  float* meta_e = enc + (size_t)2*BB*SS*DD;
  const size_t need_bytes = (size_t)((char*)(meta_e + 2*BB*DD) - wsb);
  if (ws_size < need_bytes) return;

  k_projkv<<<dim3((NNN+63)/64), dim3(256), 0, stream>>>(news_table, wa_in_w, wa_in_b, nK, nV);
  k_qh<<<dim3(BB*LL/32), dim3(128), 0, stream>>>(word_table, nwi, wa_in_w, wa_in_b, qh);
  k_attn<<<dim3(BB*LL), dim3(64), 0, stream>>>(qh, nK, nV, ctx_ids, o_at);
  k_wo<<<dim3(BB*LL/32), dim3(128), 0, stream>>>(o_at, nwi, wa_out_w, wa_out_b, doc);
  k_convprep<<<dim3(320), dim3(256), 0, stream>>>(conv_w3, conv_w4, conv_w5, wb3, wb4, wb5);
  k_gruprep<<<dim3(192), dim3(256), 0, stream>>>(wih0, whh0, wih1, whh1, wgb);
  k_conv<<<dim3(BB*3*4), dim3(256), 0, stream>>>(doc, wb3, wb4, wb5, convp);
  k_gru<<<dim3(128), dim3(256), 0, stream>>>(news_table, user_table, source_table,
      news_ids, nsn_src, nsn_end, nun_usr, nun_end,
      wgb, bih0, bhh0, bih1, bhh1, enc);
  k_metamha<<<dim3(64), dim3(128), 0, stream>>>(enc,
      inw0, inb0, outw0, outb0, lng0, lnb0,
      inw1, inb1, outw1, outb1, lng1, lnb1, meta_e);
  k_final<<<dim3(BB), dim3(128), 0, stream>>>(convp, conv_b3, conv_b4, conv_b5,
      fc_w, fc_b, meta_e, mp_w1, mp_b1, mp_w2, mp_b2,
      cls_w1, cls_b1, cls_w2, cls_b2, (float*)d_out);
}

// Round 6
// 403.392 us; speedup vs baseline: 2.3810x; 1.1976x over previous
//
#include <hip/hip_runtime.h>
#include <hip/hip_bf16.h>

// Problem dims
#define BB 32
#define LL 256
#define KC 50
#define SS 16
#define DD 128
#define NH 4
#define CC 128
#define VV 50000
#define NNN 100000
#define NUU 50000
#define NSS 5000

typedef __attribute__((ext_vector_type(8))) short bf16x8;
typedef __attribute__((ext_vector_type(8))) unsigned short u16x8;
typedef __attribute__((ext_vector_type(4))) float f32x4;

#define APAD 132   // LDS row stride (shorts): 66 words -> uniform bank spread for b128 frag reads

__device__ __forceinline__ float dot4(float4 a, float4 b){
  return a.x*b.x + a.y*b.y + a.z*b.z + a.w*b.w;
}

__device__ __forceinline__ unsigned short f2bf(float f){
  union { float f; unsigned int u; } v; v.f = f;
  unsigned int r = (v.u + 0x7FFFu + ((v.u >> 16) & 1u)) >> 16;
  return (unsigned short)r;
}
__device__ __forceinline__ float bf2f(unsigned short s){
  union { unsigned int u; float f; } v; v.u = ((unsigned int)s) << 16;
  return v.f;
}

// ---------------------------------------------------------------------------
// 0) weight prep: wab = bf16[ in_w (384x128) ; out_w (128x128) ]
__global__ __launch_bounds__(256) void k_wprep(
    const float* __restrict__ in_w, const float* __restrict__ out_w,
    unsigned short* __restrict__ wab){
  int e = blockIdx.x*256 + threadIdx.x;
  if (e < 384*DD) wab[e] = f2bf(in_w[e]);
  else if (e < 512*DD) wab[e] = f2bf(out_w[e - 384*DD]);
}

// ---------------------------------------------------------------------------
// 1) nK/nV = bf16( news_table @ [wk;wv]^T + [bk;bv] )  via MFMA 16x16x32 bf16
//    wkvb = wab+128*DD (rows 128..383 of in_w, pre-cast bf16)
__global__ __launch_bounds__(256) void k_projkv(
    const float* __restrict__ news, const unsigned short* __restrict__ wkvb,
    const float* __restrict__ in_b, unsigned short* __restrict__ nK,
    unsigned short* __restrict__ nV){
  __shared__ __align__(16) char smem[64*260*2];
  unsigned short* As = (unsigned short*)smem;      // [64][APAD] bf16
  unsigned short* Os = (unsigned short*)smem;      // [64][260] bf16 (pad 4)
  const int tid = threadIdx.x;
  const int r0 = blockIdx.x * 64;
  for (int i = tid; i < 64*32; i += 256){
    int row = i >> 5, j = i & 31;
    int gr = r0 + row;
    float4 v = (gr < NNN) ? ((const float4*)(news + (size_t)gr*DD))[j]
                          : make_float4(0.f,0.f,0.f,0.f);
    unsigned short* d = As + row*APAD + j*4;
    d[0]=f2bf(v.x); d[1]=f2bf(v.y); d[2]=f2bf(v.z); d[3]=f2bf(v.w);
  }
  __syncthreads();
  const int wave = tid >> 6;
  const int lane = tid & 63;
  const int l15  = lane & 15;
  const int quad = lane >> 4;
  bf16x8 afr[4][4];
  #pragma unroll
  for (int mt=0; mt<4; mt++)
    #pragma unroll
    for (int ks=0; ks<4; ks++)
      afr[mt][ks] = *(const bf16x8*)(As + (mt*16 + l15)*APAD + ks*32 + quad*8);
  __syncthreads();   // As free; Os may be written
  const int nbase = wave * 64;
  #pragma unroll
  for (int nt=0; nt<4; nt++){
    const int n0 = nbase + nt*16;
    bf16x8 bfr[4];
    #pragma unroll
    for (int ks=0; ks<4; ks++)
      bfr[ks] = *(const bf16x8*)(wkvb + (size_t)(n0+l15)*DD + ks*32 + quad*8);
    const float bias = in_b[128 + n0 + l15];
    #pragma unroll
    for (int mt=0; mt<4; mt++){
      f32x4 acc = {0.f,0.f,0.f,0.f};
      #pragma unroll
      for (int ks=0; ks<4; ks++)
        acc = __builtin_amdgcn_mfma_f32_16x16x32_bf16(afr[mt][ks], bfr[ks], acc, 0,0,0);
      const int col = n0 + l15;
      const int rb  = mt*16 + quad*4;
      #pragma unroll
      for (int r=0;r<4;r++)
        Os[(rb + r)*260 + col] = f2bf(acc[r] + bias);
    }
  }
  __syncthreads();
  for (int c = tid; c < 64*64; c += 256){
    int row = c >> 6, col4 = (c & 63) * 4;
    int gr = r0 + row;
    if (gr >= NNN) continue;
    unsigned long long v = *(const unsigned long long*)(Os + row*260 + col4);
    if (col4 < 128) *(unsigned long long*)(nK + (size_t)gr*128 + col4) = v;
    else            *(unsigned long long*)(nV + (size_t)gr*128 + (col4-128)) = v;
  }
}

// ---------------------------------------------------------------------------
// 2) qh = gather(word_table, widx) @ wq^T + bq   via MFMA; direct C stores
//    wqb = wab (rows 0..127)
__global__ __launch_bounds__(256) void k_qh(
    const float* __restrict__ word_table, const int* __restrict__ widx,
    const unsigned short* __restrict__ wqb, const float* __restrict__ in_b,
    float* __restrict__ qh){
  __shared__ __align__(16) unsigned short As[64*APAD];
  __shared__ int idx[64];
  const int tid = threadIdx.x;
  const int p0 = blockIdx.x * 64;
  if (tid < 64) idx[tid] = widx[p0 + tid];
  __syncthreads();
  for (int i = tid; i < 64*32; i += 256){
    int row = i >> 5, j = i & 31;
    float4 v = ((const float4*)(word_table + (size_t)idx[row]*DD))[j];
    unsigned short* d = As + row*APAD + j*4;
    d[0]=f2bf(v.x); d[1]=f2bf(v.y); d[2]=f2bf(v.z); d[3]=f2bf(v.w);
  }
  __syncthreads();
  const int wave = tid >> 6;
  const int lane = tid & 63;
  const int l15  = lane & 15;
  const int quad = lane >> 4;
  bf16x8 afr[4][4];
  #pragma unroll
  for (int mt=0; mt<4; mt++)
    #pragma unroll
    for (int ks=0; ks<4; ks++)
      afr[mt][ks] = *(const bf16x8*)(As + (mt*16 + l15)*APAD + ks*32 + quad*8);
  #pragma unroll
  for (int nt=0; nt<2; nt++){
    const int n0 = wave*32 + nt*16;
    bf16x8 bfr[4];
    #pragma unroll
    for (int ks=0; ks<4; ks++)
      bfr[ks] = *(const bf16x8*)(wqb + (size_t)(n0+l15)*DD + ks*32 + quad*8);
    const float bias = in_b[n0 + l15];
    #pragma unroll
    for (int mt=0; mt<4; mt++){
      f32x4 acc = {0.f,0.f,0.f,0.f};
      #pragma unroll
      for (int ks=0; ks<4; ks++)
        acc = __builtin_amdgcn_mfma_f32_16x16x32_bf16(afr[mt][ks], bfr[ks], acc, 0,0,0);
      #pragma unroll
      for (int r=0;r<4;r++){
        int m = mt*16 + quad*4 + r;
        qh[(size_t)(p0+m)*DD + n0 + l15] = acc[r] + bias;
      }
    }
  }
}

// ---------------------------------------------------------------------------
// 3) per-(b,l) attention, one wave per token, 16B vector gathers.
__global__ __launch_bounds__(64) void k_attn(
    const float* __restrict__ qh, const unsigned short* __restrict__ nK,
    const unsigned short* __restrict__ nV, const int* __restrict__ ctx_ids,
    float* __restrict__ o_out){
  const int p = blockIdx.x;
  const int lane = threadIdx.x;
  const int r = lane >> 4;
  const int g = lane & 15;
  const int h = g >> 2;
  __shared__ int ids[52];
  __shared__ float sc[NH][52];
  if (lane < KC) ids[lane] = ctx_ids[(size_t)p*KC + lane];
  float qv[8];
  {
    const float4* qp = (const float4*)(qh + (size_t)p*DD + g*8);
    float4 q0 = qp[0], q1 = qp[1];
    qv[0]=q0.x; qv[1]=q0.y; qv[2]=q0.z; qv[3]=q0.w;
    qv[4]=q1.x; qv[5]=q1.y; qv[6]=q1.z; qv[7]=q1.w;
  }
  __syncthreads();
  for (int kb=0; kb<13; kb++){
    int k2 = kb*4 + r;
    int row = ids[(k2 < KC) ? k2 : 0];
    u16x8 kv = *(const u16x8*)(nK + (size_t)row*DD + g*8);
    float pr = 0.f;
    #pragma unroll
    for (int j=0;j<8;j++) pr += qv[j]*bf2f(kv[j]);
    pr += __shfl_xor(pr, 1, 64);
    pr += __shfl_xor(pr, 2, 64);
    if ((g & 3) == 0 && k2 < KC) sc[h][k2] = pr;
  }
  __syncthreads();
  {
    const int hh = lane >> 4, kc = lane & 15;
    const float scale = 0.17677669529663687f;
    float mx = -1e30f;
    #pragma unroll
    for (int q4=0;q4<4;q4++){ int k2=kc+q4*16; if (k2<KC) mx = fmaxf(mx, sc[hh][k2]); }
    mx = fmaxf(mx, __shfl_xor(mx, 1, 64));
    mx = fmaxf(mx, __shfl_xor(mx, 2, 64));
    mx = fmaxf(mx, __shfl_xor(mx, 4, 64));
    mx = fmaxf(mx, __shfl_xor(mx, 8, 64));
    float sm = 0.f;
    float ev[4];
    #pragma unroll
    for (int q4=0;q4<4;q4++){
      int k2=kc+q4*16;
      ev[q4] = (k2<KC) ? __expf((sc[hh][k2]-mx)*scale) : 0.f;
      sm += ev[q4];
    }
    sm += __shfl_xor(sm, 1, 64);
    sm += __shfl_xor(sm, 2, 64);
    sm += __shfl_xor(sm, 4, 64);
    sm += __shfl_xor(sm, 8, 64);
    float inv = 1.f/sm;
    #pragma unroll
    for (int q4=0;q4<4;q4++){ int k2=kc+q4*16; if (k2<KC) sc[hh][k2] = ev[q4]*inv; }
  }
  __syncthreads();
  float acc[8];
  #pragma unroll
  for (int j=0;j<8;j++) acc[j]=0.f;
  for (int kb=0; kb<13; kb++){
    int k2 = kb*4 + r;
    int row = ids[(k2 < KC) ? k2 : 0];
    float w = (k2 < KC) ? sc[h][k2] : 0.f;
    u16x8 vv = *(const u16x8*)(nV + (size_t)row*DD + g*8);
    #pragma unroll
    for (int j=0;j<8;j++) acc[j] += w*bf2f(vv[j]);
  }
  #pragma unroll
  for (int j=0;j<8;j++){
    acc[j] += __shfl_xor(acc[j], 16, 64);
    acc[j] += __shfl_xor(acc[j], 32, 64);
  }
  if (r == 0){
    float4* op = (float4*)(o_out + (size_t)p*DD + g*8);
    op[0] = make_float4(acc[0],acc[1],acc[2],acc[3]);
    op[1] = make_float4(acc[4],acc[5],acc[6],acc[7]);
  }
}

// ---------------------------------------------------------------------------
// 4) doc = mask(widx==0) ? 0 : o @ wo^T + bo   via MFMA; wob = wab + 384*DD
__global__ __launch_bounds__(256) void k_wo(
    const float* __restrict__ o_attn, const int* __restrict__ widx,
    const unsigned short* __restrict__ wob, const float* __restrict__ out_b,
    float* __restrict__ doc){
  __shared__ __align__(16) unsigned short As[64*APAD];
  __shared__ int wm[64];
  const int tid = threadIdx.x;
  const int p0 = blockIdx.x * 64;
  if (tid < 64) wm[tid] = widx[p0 + tid];
  for (int i = tid; i < 64*32; i += 256){
    int row = i >> 5, j = i & 31;
    float4 v = ((const float4*)(o_attn + (size_t)(p0+row)*DD))[j];
    unsigned short* d = As + row*APAD + j*4;
    d[0]=f2bf(v.x); d[1]=f2bf(v.y); d[2]=f2bf(v.z); d[3]=f2bf(v.w);
  }
  __syncthreads();
  const int wave = tid >> 6;
  const int lane = tid & 63;
  const int l15  = lane & 15;
  const int quad = lane >> 4;
  bf16x8 afr[4][4];
  #pragma unroll
  for (int mt=0; mt<4; mt++)
    #pragma unroll
    for (int ks=0; ks<4; ks++)
      afr[mt][ks] = *(const bf16x8*)(As + (mt*16 + l15)*APAD + ks*32 + quad*8);
  #pragma unroll
  for (int nt=0; nt<2; nt++){
    const int n0 = wave*32 + nt*16;
    bf16x8 bfr[4];
    #pragma unroll
    for (int ks=0; ks<4; ks++)
      bfr[ks] = *(const bf16x8*)(wob + (size_t)(n0+l15)*DD + ks*32 + quad*8);
    const float bias = out_b[n0 + l15];
    #pragma unroll
    for (int mt=0; mt<4; mt++){
      f32x4 acc = {0.f,0.f,0.f,0.f};
      #pragma unroll
      for (int ks=0; ks<4; ks++)
        acc = __builtin_amdgcn_mfma_f32_16x16x32_bf16(afr[mt][ks], bfr[ks], acc, 0,0,0);
      #pragma unroll
      for (int r=0;r<4;r++){
        int m = mt*16 + quad*4 + r;
        doc[(size_t)(p0+m)*DD + n0 + l15] = (wm[m] == 0) ? 0.0f : (acc[r] + bias);
      }
    }
  }
}

// ---------------------------------------------------------------------------
// 5) conv weights -> bf16, layout wb[jj][c][d] per conv
__global__ __launch_bounds__(256) void k_convprep(
    const float* __restrict__ w3, const float* __restrict__ w4,
    const float* __restrict__ w5, unsigned short* __restrict__ wb3,
    unsigned short* __restrict__ wb4, unsigned short* __restrict__ wb5){
  int e = blockIdx.x*256 + threadIdx.x;
  if (e < CC*DD*3){ int c=e/(DD*3), rm=e%(DD*3), d=rm/3, jj=rm%3;
    wb3[((size_t)jj*CC + c)*DD + d] = f2bf(w3[e]); }
  if (e < CC*DD*4){ int c=e/(DD*4), rm=e%(DD*4), d=rm/4, jj=rm%4;
    wb4[((size_t)jj*CC + c)*DD + d] = f2bf(w4[e]); }
  if (e < CC*DD*5){ int c=e/(DD*5), rm=e%(DD*5), d=rm/5, jj=rm%5;
    wb5[((size_t)jj*CC + c)*DD + d] = f2bf(w5[e]); }
}

// ---------------------------------------------------------------------------
// 5b) GRU weights -> bf16
__global__ __launch_bounds__(256) void k_gruprep(
    const float* __restrict__ wih0, const float* __restrict__ whh0,
    const float* __restrict__ wih1, const float* __restrict__ whh1,
    unsigned short* __restrict__ wgb){
  int e = blockIdx.x*256 + threadIdx.x;
  if (e < 384*DD){
    wgb[e]            = f2bf(wih0[e]);
    wgb[49152 + e]    = f2bf(whh0[e]);
    wgb[98304 + e]    = f2bf(wih1[e]);
    wgb[147456 + e]   = f2bf(whh1[e]);
  }
}

// ---------------------------------------------------------------------------
// 6) conv as MFMA GEMM + fused max-over-t.
#define CROWS 68
#define CPAD 136
__global__ __launch_bounds__(256) void k_conv(
    const float* __restrict__ doc, const unsigned short* __restrict__ wb3,
    const unsigned short* __restrict__ wb4, const unsigned short* __restrict__ wb5,
    float* __restrict__ convp){
  __shared__ __align__(16) char smem[CROWS*CPAD*2];
  unsigned short* ds = (unsigned short*)smem;
  float* smf = (float*)smem;
  const int blk = blockIdx.x;
  const int chunk = blk & 3;
  const int j = (blk >> 2) % 3;
  const int b = blk / 12;
  const int kk = 3 + j;
  const int T = LL - kk + 1;
  const int t0 = chunk * 64;
  const int nrows = 64 + kk - 1;
  const unsigned short* wb = (j==0) ? wb3 : (j==1) ? wb4 : wb5;
  const int tid = threadIdx.x;
  for (int i = tid; i < nrows*32; i += 256){
    int row = i >> 5, q4 = i & 31;
    int gt = t0 + row;
    float4 v = (gt < LL) ? ((const float4*)(doc + ((size_t)b*LL + gt)*DD))[q4]
                         : make_float4(0.f,0.f,0.f,0.f);
    unsigned short* dp = ds + row*CPAD + q4*4;
    dp[0]=f2bf(v.x); dp[1]=f2bf(v.y); dp[2]=f2bf(v.z); dp[3]=f2bf(v.w);
  }
  __syncthreads();
  const int wave = tid >> 6;
  const int lane = tid & 63;
  const int l15  = lane & 15;
  const int quad = lane >> 4;
  f32x4 acc[8];
  #pragma unroll
  for (int nt=0;nt<8;nt++) acc[nt] = (f32x4){0.f,0.f,0.f,0.f};
  for (int jj=0; jj<kk; jj++){
    #pragma unroll
    for (int ks=0; ks<4; ks++){
      bf16x8 af = *(const bf16x8*)(ds + (wave*16 + l15 + jj)*CPAD + ks*32 + quad*8);
      #pragma unroll
      for (int nt=0; nt<8; nt++){
        bf16x8 bf = *(const bf16x8*)(wb + ((size_t)jj*CC + nt*16 + l15)*DD + ks*32 + quad*8);
        acc[nt] = __builtin_amdgcn_mfma_f32_16x16x32_bf16(af, bf, acc[nt], 0,0,0);
      }
    }
  }
  __syncthreads();
  #pragma unroll
  for (int nt=0; nt<8; nt++){
    float mx = -1e30f;
    #pragma unroll
    for (int r=0;r<4;r++){
      int t = t0 + wave*16 + quad*4 + r;
      mx = fmaxf(mx, (t < T) ? acc[nt][r] : -1e30f);
    }
    mx = fmaxf(mx, __shfl_xor(mx, 16, 64));
    mx = fmaxf(mx, __shfl_xor(mx, 32, 64));
    if (quad == 0) smf[wave*128 + nt*16 + l15] = mx;
  }
  __syncthreads();
  if (tid < 128){
    float m4 = fmaxf(fmaxf(smf[tid], smf[128+tid]), fmaxf(smf[256+tid], smf[384+tid]));
    convp[(((size_t)b*3 + j)*4 + chunk)*CC + tid] = m4;
  }
}

// ---------------------------------------------------------------------------
// 7) GRU via MFMA; block per (module, b, 8-seq half); 256 thr = 4 waves.
#define GSTR 392
__global__ __launch_bounds__(256) void k_gru(
    const float* __restrict__ news_table, const float* __restrict__ user_table,
    const float* __restrict__ source_table,
    const int* __restrict__ news_ids, const int* __restrict__ nsn_src,
    const int* __restrict__ nsn_end, const int* __restrict__ nun_usr,
    const int* __restrict__ nun_end,
    const unsigned short* __restrict__ wgb,
    const float* __restrict__ bih0, const float* __restrict__ bhh0,
    const float* __restrict__ bih1, const float* __restrict__ bhh1,
    float* __restrict__ enc){
  __shared__ __align__(16) unsigned short xs[16][CPAD];
  __shared__ __align__(16) unsigned short hs[16][CPAD];
  __shared__ float hf[8][128];
  __shared__ float gi[8][GSTR];
  __shared__ float gh[8][GSTR];
  const int blk = blockIdx.x;
  const int m  = blk >> 6;
  const int b  = (blk >> 1) & 31;
  const int s0 = (blk & 1) * 8;
  const int tid = threadIdx.x;
  const int wave = tid >> 6, lane = tid & 63, l15 = lane & 15, quad = lane >> 4;
  const unsigned short* Wih = wgb + (size_t)m*2*384*DD;
  const unsigned short* Whh = Wih + 384*DD;
  const float* bih = m ? bih1 : bih0;
  const float* bhh = m ? bhh1 : bhh0;
  for (int i=tid;i<16*CPAD;i+=256){ (&xs[0][0])[i]=0; (&hs[0][0])[i]=0; }
  for (int i=tid;i<8*128;i+=256) (&hf[0][0])[i]=0.f;
  __syncthreads();
  for (int t=0;t<3;t++){
    {
      int s = tid >> 5, j = tid & 31;
      int row; const float* tab;
      if (t==0){ row = news_ids[b]; tab = news_table; }
      else if (t==1){ row = m ? nun_usr[b*SS+s0+s] : nsn_src[b*SS+s0+s];
                      tab = m ? user_table : source_table; }
      else { row = m ? nun_end[b*SS+s0+s] : nsn_end[b*SS+s0+s]; tab = news_table; }
      float4 v = ((const float4*)(tab + (size_t)row*DD))[j];
      unsigned short* dp = &xs[s][j*4];
      dp[0]=f2bf(v.x); dp[1]=f2bf(v.y); dp[2]=f2bf(v.z); dp[3]=f2bf(v.w);
    }
    __syncthreads();
    bf16x8 ax[4], ah[4];
    #pragma unroll
    for (int ks=0;ks<4;ks++){
      ax[ks] = *(const bf16x8*)&xs[l15][ks*32+quad*8];
      ah[ks] = *(const bf16x8*)&hs[l15][ks*32+quad*8];
    }
    #pragma unroll
    for (int nt=0;nt<6;nt++){
      const int n0 = wave*96 + nt*16;
      f32x4 ga = {0.f,0.f,0.f,0.f}, ha = {0.f,0.f,0.f,0.f};
      #pragma unroll
      for (int ks=0;ks<4;ks++){
        bf16x8 bi = *(const bf16x8*)(Wih + (size_t)(n0+l15)*DD + ks*32+quad*8);
        ga = __builtin_amdgcn_mfma_f32_16x16x32_bf16(ax[ks], bi, ga, 0,0,0);
        bf16x8 bh = *(const bf16x8*)(Whh + (size_t)(n0+l15)*DD + ks*32+quad*8);
        ha = __builtin_amdgcn_mfma_f32_16x16x32_bf16(ah[ks], bh, ha, 0,0,0);
      }
      if (quad < 2){
        #pragma unroll
        for (int r=0;r<4;r++){
          gi[quad*4+r][n0+l15] = ga[r];
          gh[quad*4+r][n0+l15] = ha[r];
        }
      }
    }
    __syncthreads();
    #pragma unroll
    for (int k=0;k<4;k++){
      int it = tid + k*256;
      int s = it >> 7, g = it & 127;
      float rr = 1.f/(1.f+__expf(-(gi[s][g] + gh[s][g] + bih[g] + bhh[g])));
      float zz = 1.f/(1.f+__expf(-(gi[s][128+g] + gh[s][128+g] + bih[128+g] + bhh[128+g])));
      float nn = tanhf(gi[s][256+g] + bih[256+g] + rr*(gh[s][256+g] + bhh[256+g]));
      float hnew = (1.f-zz)*nn + zz*hf[s][g];
      hf[s][g] = hnew;
      hs[s][g] = f2bf(hnew);
    }
    __syncthreads();
  }
  {
    int s = tid >> 5, j = tid & 31;
    float4 v = ((const float4*)hf[s])[j];
    ((float4*)(enc + (((size_t)m*BB + b)*SS + (s0+s))*DD))[j] = v;
  }
}

// ---------------------------------------------------------------------------
// 8) meta-path MHA + residual + LN + mean over s; block per (module, b)
__global__ __launch_bounds__(128, 2) void k_metamha(
    const float* __restrict__ enc,
    const float* __restrict__ inw0, const float* __restrict__ inb0,
    const float* __restrict__ outw0, const float* __restrict__ outb0,
    const float* __restrict__ lng0, const float* __restrict__ lnb0,
    const float* __restrict__ inw1, const float* __restrict__ inb1,
    const float* __restrict__ outw1, const float* __restrict__ outb1,
    const float* __restrict__ lng1, const float* __restrict__ lnb1,
    float* __restrict__ meta_e){
  const int m = blockIdx.x >> 5;
  const int b = blockIdx.x & 31;
  const int c = threadIdx.x;
  const float* in_w  = m?inw1:inw0;  const float* in_b  = m?inb1:inb0;
  const float* out_w = m?outw1:outw0; const float* out_b = m?outb1:outb0;
  const float* lng   = m?lng1:lng0;  const float* lnb   = m?lnb1:lnb0;
  __shared__ float e[16][128], q[16][128], k[16][128], v[16][128];
  __shared__ float at[4][16][16];
  __shared__ float mu[16], rs[16];
  const float* esrc = enc + ((size_t)m*BB + b)*SS*DD;
  for (int i=c;i<16*128;i+=128) ((float*)e)[i] = esrc[i];
  __syncthreads();
  {
    float aq[16], ak[16], av[16];
    float bq = in_b[c], bk = in_b[128+c], bv = in_b[256+c];
    #pragma unroll
    for (int s=0;s<16;s++){ aq[s]=bq; ak[s]=bk; av[s]=bv; }
    const float4* wq4 = (const float4*)(in_w + c*DD);
    const float4* wk4 = (const float4*)(in_w + (128+c)*DD);
    const float4* wv4 = (const float4*)(in_w + (256+c)*DD);
    for (int j=0;j<32;j++){
      float4 a0=wq4[j], a1=wk4[j], a2=wv4[j];
      #pragma unroll
      for (int s=0;s<16;s++){
        float4 ev = ((const float4*)e[s])[j];
        aq[s]+=dot4(a0,ev); ak[s]+=dot4(a1,ev); av[s]+=dot4(a2,ev);
      }
    }
    #pragma unroll
    for (int s=0;s<16;s++){ q[s][c]=aq[s]; k[s][c]=ak[s]; v[s][c]=av[s]; }
  }
  __syncthreads();
  for (int r=0;r<8;r++){
    int lin = r*128 + c;
    int h = lin >> 8, qi = (lin>>4)&15, ki = lin&15;
    float sum=0.f;
    const float* qp = &q[qi][h*32];
    const float* kp = &k[ki][h*32];
    for (int x=0;x<32;x++) sum += qp[x]*kp[x];
    at[h][qi][ki] = sum * 0.17677669529663687f;
  }
  __syncthreads();
  if (c < 64){
    int h = c>>4, qi = c&15;
    float mx=-1e30f;
    for (int ki=0;ki<16;ki++) mx = fmaxf(mx, at[h][qi][ki]);
    float sm=0.f;
    for (int ki=0;ki<16;ki++){ float ee=__expf(at[h][qi][ki]-mx); at[h][qi][ki]=ee; sm+=ee; }
    float inv=1.f/sm;
    for (int ki=0;ki<16;ki++) at[h][qi][ki]*=inv;
  }
  __syncthreads();
  {
    int h = c>>5;
    float o[16];
    #pragma unroll
    for (int s=0;s<16;s++){
      float acc=0.f;
      for (int ki=0;ki<16;ki++) acc += at[h][s][ki]*v[ki][c];
      o[s]=acc;
    }
    __syncthreads();
    #pragma unroll
    for (int s=0;s<16;s++) q[s][c]=o[s];
  }
  __syncthreads();
  {
    float ay[16];
    float bo = out_b[c];
    #pragma unroll
    for (int s=0;s<16;s++) ay[s] = bo + e[s][c];
    const float4* wo4 = (const float4*)(out_w + c*DD);
    for (int j=0;j<32;j++){
      float4 wv_ = wo4[j];
      #pragma unroll
      for (int s=0;s<16;s++) ay[s] += dot4(wv_, ((const float4*)q[s])[j]);
    }
    __syncthreads();
    #pragma unroll
    for (int s=0;s<16;s++) e[s][c] = ay[s];
  }
  __syncthreads();
  if (c < 16){
    float sm=0.f;
    for (int d=0;d<128;d++) sm += e[c][d];
    float mean = sm*(1.f/128.f);
    float vs=0.f;
    for (int d=0;d<128;d++){ float df = e[c][d]-mean; vs += df*df; }
    mu[c]=mean; rs[c]=rsqrtf(vs*(1.f/128.f) + 1e-5f);
  }
  __syncthreads();
  {
    float g = lng[c], bb2 = lnb[c];
    float acc=0.f;
    #pragma unroll
    for (int s=0;s<16;s++) acc += (e[s][c]-mu[s])*rs[s]*g + bb2;
    meta_e[((size_t)m*BB+b)*DD + c] = acc * (1.f/16.f);
  }
}

// ---------------------------------------------------------------------------
// 9) pool-reduce + fc + meta gate + classifier; block per b
__global__ __launch_bounds__(128) void k_final(
    const float* __restrict__ convp,
    const float* __restrict__ cb3, const float* __restrict__ cb4,
    const float* __restrict__ cb5,
    const float* __restrict__ fc_w, const float* __restrict__ fc_b,
    const float* __restrict__ meta_e,
    const float* __restrict__ mp_w1, const float* __restrict__ mp_b1,
    const float* __restrict__ mp_w2, const float* __restrict__ mp_b2,
    const float* __restrict__ cls_w1, const float* __restrict__ cls_b1,
    const float* __restrict__ cls_w2, const float* __restrict__ cls_b2,
    float* __restrict__ out){
  const int b = blockIdx.x;
  const int c = threadIdx.x;
  __shared__ float pooled[384];
  __shared__ float comb[256];
  __shared__ float hcls[128];
  __shared__ float tt[2][64];
  __shared__ float wsc[2];
  for (int idx=c; idx<384; idx+=128){
    int j = idx >> 7, cc2 = idx & 127;
    const float* base = convp + (((size_t)b*3 + j)*4)*CC + cc2;
    float mx = -1e30f;
    for (int ci=0;ci<4;ci++) mx = fmaxf(mx, base[ci*CC]);
    const float* cb = (j==0)?cb3:(j==1)?cb4:cb5;
    pooled[idx] = fmaxf(mx + cb[cc2], 0.f);
  }
  __syncthreads();
  {
    float acc = fc_b[c];
    const float* wr = fc_w + (size_t)c*384;
    for (int i=0;i<384;i++) acc += pooled[i]*wr[i];
    comb[c] = acc;
  }
  if (c < 64){
    for (int m=0;m<2;m++){
      const float* ev = meta_e + ((size_t)m*BB+b)*DD;
      float acc = mp_b1[c];
      const float* wr = mp_w1 + (size_t)c*DD;
      for (int i=0;i<DD;i++) acc += ev[i]*wr[i];
      tt[m][c] = tanhf(acc);
    }
  }
  __syncthreads();
  if (c == 0){
    float s0 = mp_b2[0], s1 = mp_b2[0];
    for (int j=0;j<64;j++){ s0 += tt[0][j]*mp_w2[j]; s1 += tt[1][j]*mp_w2[j]; }
    float mx = fmaxf(s0,s1);
    float e0 = __expf(s0-mx), e1 = __expf(s1-mx);
    wsc[0] = e0/(e0+e1); wsc[1] = e1/(e0+e1);
  }
  __syncthreads();
  comb[128+c] = wsc[0]*meta_e[((size_t)b)*DD + c]
              + wsc[1]*meta_e[((size_t)(BB+b))*DD + c];
  __syncthreads();
  {
    float acc = cls_b1[c];
    const float* wr = cls_w1 + (size_t)c*256;
    for (int i=0;i<256;i++) acc += comb[i]*wr[i];
    hcls[c] = fmaxf(acc, 0.f);
  }
  __syncthreads();
  if (c < 2){
    float acc = cls_b2[c];
    const float* wr = cls_w2 + (size_t)c*DD;
    for (int i=0;i<DD;i++) acc += hcls[i]*wr[i];
    out[b*2 + c] = acc;
  }
}

// ---------------------------------------------------------------------------
extern "C" void kernel_launch(void* const* d_in, const int* in_sizes, int n_in,
                              void* d_out, int out_size, void* d_ws, size_t ws_size,
                              hipStream_t stream){
  const int* news_ids = (const int*)d_in[0];
  const int* nwi      = (const int*)d_in[1];
  const int* ctx_ids  = (const int*)d_in[2];
  const int* nsn_src  = (const int*)d_in[3];
  const int* nsn_end  = (const int*)d_in[4];
  const int* nun_usr  = (const int*)d_in[5];
  const int* nun_end  = (const int*)d_in[6];
  const float* word_table   = (const float*)d_in[7];
  const float* news_table   = (const float*)d_in[8];
  const float* user_table   = (const float*)d_in[9];
  const float* source_table = (const float*)d_in[10];
  const float* wa_in_w  = (const float*)d_in[11];
  const float* wa_in_b  = (const float*)d_in[12];
  const float* wa_out_w = (const float*)d_in[13];
  const float* wa_out_b = (const float*)d_in[14];
  const float* conv_w3 = (const float*)d_in[15];
  const float* conv_b3 = (const float*)d_in[16];
  const float* conv_w4 = (const float*)d_in[17];
  const float* conv_b4 = (const float*)d_in[18];
  const float* conv_w5 = (const float*)d_in[19];
  const float* conv_b5 = (const float*)d_in[20];
  const float* fc_w = (const float*)d_in[21];
  const float* fc_b = (const float*)d_in[22];
  const float* wih0 = (const float*)d_in[23];
  const float* whh0 = (const float*)d_in[24];
  const float* bih0 = (const float*)d_in[25];
  const float* bhh0 = (const float*)d_in[26];
  const float* inw0 = (const float*)d_in[27];
  const float* inb0 = (const float*)d_in[28];
  const float* outw0 = (const float*)d_in[29];
  const float* outb0 = (const float*)d_in[30];
  const float* lng0 = (const float*)d_in[31];
  const float* lnb0 = (const float*)d_in[32];
  const float* wih1 = (const float*)d_in[33];
  const float* whh1 = (const float*)d_in[34];
  const float* bih1 = (const float*)d_in[35];
  const float* bhh1 = (const float*)d_in[36];
  const float* inw1 = (const float*)d_in[37];
  const float* inb1 = (const float*)d_in[38];
  const float* outw1 = (const float*)d_in[39];
  const float* outb1 = (const float*)d_in[40];
  const float* lng1 = (const float*)d_in[41];
  const float* lnb1 = (const float*)d_in[42];
  const float* mp_w1 = (const float*)d_in[43];
  const float* mp_b1 = (const float*)d_in[44];
  const float* mp_w2 = (const float*)d_in[45];
  const float* mp_b2 = (const float*)d_in[46];
  const float* cls_w1 = (const float*)d_in[47];
  const float* cls_b1 = (const float*)d_in[48];
  const float* cls_w2 = (const float*)d_in[49];
  const float* cls_b2 = (const float*)d_in[50];

  // workspace layout
  char* wsb = (char*)d_ws;
  unsigned short* nK = (unsigned short*)wsb;                 // NNN*DD bf16
  unsigned short* nV = nK + (size_t)NNN*DD;                  // NNN*DD bf16
  unsigned short* wb3 = nV + (size_t)NNN*DD;                 // CC*DD*3 bf16
  unsigned short* wb4 = wb3 + (size_t)CC*DD*3;
  unsigned short* wb5 = wb4 + (size_t)CC*DD*4;
  unsigned short* wgb = wb5 + (size_t)CC*DD*5;               // 4*384*128 bf16
  unsigned short* wab = wgb + (size_t)4*384*DD;              // 512*128 bf16
  float* qh     = (float*)(wab + (size_t)512*DD);
  float* o_at   = qh + (size_t)BB*LL*DD;
  float* doc    = o_at + (size_t)BB*LL*DD;
  float* convp  = doc + (size_t)BB*LL*DD;
  float* enc    = convp + BB*3*4*CC;
  float* meta_e = enc + (size_t)2*BB*SS*DD;
  const size_t need_bytes = (size_t)((char*)(meta_e + 2*BB*DD) - wsb);
  if (ws_size < need_bytes) return;

  const unsigned short* wqb  = wab;                // rows 0..127 (wq)
  const unsigned short* wkvb = wab + (size_t)128*DD;  // rows 128..383 (wk;wv)
  const unsigned short* wob  = wab + (size_t)384*DD;  // out_w

  k_wprep<<<dim3(256), dim3(256), 0, stream>>>(wa_in_w, wa_out_w, wab);
  k_projkv<<<dim3((NNN+63)/64), dim3(256), 0, stream>>>(news_table, wkvb, wa_in_b, nK, nV);
  k_qh<<<dim3(BB*LL/64), dim3(256), 0, stream>>>(word_table, nwi, wqb, wa_in_b, qh);
  k_attn<<<dim3(BB*LL), dim3(64), 0, stream>>>(qh, nK, nV, ctx_ids, o_at);
  k_wo<<<dim3(BB*LL/64), dim3(256), 0, stream>>>(o_at, nwi, wob, wa_out_b, doc);
  k_convprep<<<dim3(320), dim3(256), 0, stream>>>(conv_w3, conv_w4, conv_w5, wb3, wb4, wb5);
  k_gruprep<<<dim3(192), dim3(256), 0, stream>>>(wih0, whh0, wih1, whh1, wgb);
  k_conv<<<dim3(BB*3*4), dim3(256), 0, stream>>>(doc, wb3, wb4, wb5, convp);
  k_gru<<<dim3(128), dim3(256), 0, stream>>>(news_table, user_table, source_table,
      news_ids, nsn_src, nsn_end, nun_usr, nun_end,
      wgb, bih0, bhh0, bih1, bhh1, enc);
  k_metamha<<<dim3(64), dim3(128), 0, stream>>>(enc,
      inw0, inb0, outw0, outb0, lng0, lnb0,
      inw1, inb1, outw1, outb1, lng1, lnb1, meta_e);
  k_final<<<dim3(BB), dim3(128), 0, stream>>>(convp, conv_b3, conv_b4, conv_b5,
      fc_w, fc_b, meta_e, mp_w1, mp_b1, mp_w2, mp_b2,
      cls_w1, cls_b1, cls_w2, cls_b2, (float*)d_out);
}

// Round 7
// 396.718 us; speedup vs baseline: 2.4211x; 1.0168x over previous
//
#include <hip/hip_runtime.h>
#include <hip/hip_bf16.h>

// Problem dims
#define BB 32
#define LL 256
#define KC 50
#define SS 16
#define DD 128
#define NH 4
#define CC 128
#define VV 50000
#define NNN 100000
#define NUU 50000
#define NSS 5000

typedef __attribute__((ext_vector_type(8))) short bf16x8;
typedef __attribute__((ext_vector_type(8))) unsigned short u16x8;
typedef __attribute__((ext_vector_type(4))) float f32x4;

#define APAD 132   // LDS row stride (shorts): 66 words -> uniform bank spread for b128 frag reads

__device__ __forceinline__ float dot4(float4 a, float4 b){
  return a.x*b.x + a.y*b.y + a.z*b.z + a.w*b.w;
}

__device__ __forceinline__ unsigned short f2bf(float f){
  union { float f; unsigned int u; } v; v.f = f;
  unsigned int r = (v.u + 0x7FFFu + ((v.u >> 16) & 1u)) >> 16;
  return (unsigned short)r;
}
__device__ __forceinline__ float bf2f(unsigned short s){
  union { unsigned int u; float f; } v; v.u = ((unsigned int)s) << 16;
  return v.f;
}

// ---------------------------------------------------------------------------
// 0) unified weight prep: conv wb3/4/5, GRU wgb, word-attn wab  (one launch)
__global__ __launch_bounds__(256) void k_prep(
    const float* __restrict__ w3, const float* __restrict__ w4,
    const float* __restrict__ w5,
    const float* __restrict__ wih0, const float* __restrict__ whh0,
    const float* __restrict__ wih1, const float* __restrict__ whh1,
    const float* __restrict__ in_w, const float* __restrict__ out_w,
    unsigned short* __restrict__ wb3, unsigned short* __restrict__ wb4,
    unsigned short* __restrict__ wb5, unsigned short* __restrict__ wgb,
    unsigned short* __restrict__ wab){
  int e = blockIdx.x*256 + threadIdx.x;
  if (e < CC*DD*3){ int c=e/(DD*3), rm=e%(DD*3), d=rm/3, jj=rm%3;
    wb3[((size_t)jj*CC + c)*DD + d] = f2bf(w3[e]); }
  if (e < CC*DD*4){ int c=e/(DD*4), rm=e%(DD*4), d=rm/4, jj=rm%4;
    wb4[((size_t)jj*CC + c)*DD + d] = f2bf(w4[e]); }
  if (e < CC*DD*5){ int c=e/(DD*5), rm=e%(DD*5), d=rm/5, jj=rm%5;
    wb5[((size_t)jj*CC + c)*DD + d] = f2bf(w5[e]); }
  if (e < 384*DD){
    wgb[e]          = f2bf(wih0[e]);
    wgb[49152 + e]  = f2bf(whh0[e]);
    wgb[98304 + e]  = f2bf(wih1[e]);
    wgb[147456 + e] = f2bf(whh1[e]);
    wab[e]          = f2bf(in_w[e]);
  }
  if (e >= 384*DD && e < 512*DD) wab[e] = f2bf(out_w[e - 384*DD]);
}

// ---------------------------------------------------------------------------
// 1) nK/nV = bf16( news_table @ [wk;wv]^T + [bk;bv] )  via MFMA 16x16x32 bf16
//    Single 64x132 LDS buffer aliased A-tile / Out-tile; two output passes
//    (K cols then V cols) -> 16.9 KB LDS -> 8 blocks/CU residency.
__global__ __launch_bounds__(256) void k_projkv(
    const float* __restrict__ news, const unsigned short* __restrict__ wkvb,
    const float* __restrict__ in_b, unsigned short* __restrict__ nK,
    unsigned short* __restrict__ nV){
  __shared__ __align__(16) unsigned short Ts[64*APAD];   // 16896 B
  const int tid = threadIdx.x;
  const int r0 = blockIdx.x * 64;
  // stage A tile as bf16
  for (int i = tid; i < 64*32; i += 256){
    int row = i >> 5, j = i & 31;
    int gr = r0 + row;
    float4 v = (gr < NNN) ? ((const float4*)(news + (size_t)gr*DD))[j]
                          : make_float4(0.f,0.f,0.f,0.f);
    unsigned short* d = Ts + row*APAD + j*4;
    d[0]=f2bf(v.x); d[1]=f2bf(v.y); d[2]=f2bf(v.z); d[3]=f2bf(v.w);
  }
  __syncthreads();
  const int wave = tid >> 6;
  const int lane = tid & 63;
  const int l15  = lane & 15;
  const int quad = lane >> 4;
  bf16x8 afr[4][4];
  #pragma unroll
  for (int mt=0; mt<4; mt++)
    #pragma unroll
    for (int ks=0; ks<4; ks++)
      afr[mt][ks] = *(const bf16x8*)(Ts + (mt*16 + l15)*APAD + ks*32 + quad*8);
  __syncthreads();   // A consumed into registers; Ts now reusable as Out-tile
  for (int pass=0; pass<2; pass++){
    unsigned short* outp = pass ? nV : nK;
    #pragma unroll
    for (int t=0; t<2; t++){
      const int n0 = wave*32 + t*16;                 // col within 128-half
      bf16x8 bfr[4];
      #pragma unroll
      for (int ks=0; ks<4; ks++)
        bfr[ks] = *(const bf16x8*)(wkvb + (size_t)(pass*128 + n0 + l15)*DD + ks*32 + quad*8);
      const float bias = in_b[128 + pass*128 + n0 + l15];
      #pragma unroll
      for (int mt=0; mt<4; mt++){
        f32x4 acc = {0.f,0.f,0.f,0.f};
        #pragma unroll
        for (int ks=0; ks<4; ks++)
          acc = __builtin_amdgcn_mfma_f32_16x16x32_bf16(afr[mt][ks], bfr[ks], acc, 0,0,0);
        const int col = n0 + l15;
        const int rb  = mt*16 + quad*4;
        #pragma unroll
        for (int r=0;r<4;r++)
          Ts[(rb + r)*APAD + col] = f2bf(acc[r] + bias);
      }
    }
    __syncthreads();
    for (int c = tid; c < 64*32; c += 256){
      int row = c >> 5, col4 = (c & 31) * 4;
      int gr = r0 + row;
      if (gr < NNN)
        *(unsigned long long*)(outp + (size_t)gr*128 + col4) =
            *(const unsigned long long*)(Ts + row*APAD + col4);
    }
    __syncthreads();
  }
}

// ---------------------------------------------------------------------------
// 2) qh = gather(word_table, widx) @ wq^T + bq   via MFMA; direct C stores
__global__ __launch_bounds__(256) void k_qh(
    const float* __restrict__ word_table, const int* __restrict__ widx,
    const unsigned short* __restrict__ wqb, const float* __restrict__ in_b,
    float* __restrict__ qh){
  __shared__ __align__(16) unsigned short As[64*APAD];
  __shared__ int idx[64];
  const int tid = threadIdx.x;
  const int p0 = blockIdx.x * 64;
  if (tid < 64) idx[tid] = widx[p0 + tid];
  __syncthreads();
  for (int i = tid; i < 64*32; i += 256){
    int row = i >> 5, j = i & 31;
    float4 v = ((const float4*)(word_table + (size_t)idx[row]*DD))[j];
    unsigned short* d = As + row*APAD + j*4;
    d[0]=f2bf(v.x); d[1]=f2bf(v.y); d[2]=f2bf(v.z); d[3]=f2bf(v.w);
  }
  __syncthreads();
  const int wave = tid >> 6;
  const int lane = tid & 63;
  const int l15  = lane & 15;
  const int quad = lane >> 4;
  bf16x8 afr[4][4];
  #pragma unroll
  for (int mt=0; mt<4; mt++)
    #pragma unroll
    for (int ks=0; ks<4; ks++)
      afr[mt][ks] = *(const bf16x8*)(As + (mt*16 + l15)*APAD + ks*32 + quad*8);
  #pragma unroll
  for (int nt=0; nt<2; nt++){
    const int n0 = wave*32 + nt*16;
    bf16x8 bfr[4];
    #pragma unroll
    for (int ks=0; ks<4; ks++)
      bfr[ks] = *(const bf16x8*)(wqb + (size_t)(n0+l15)*DD + ks*32 + quad*8);
    const float bias = in_b[n0 + l15];
    #pragma unroll
    for (int mt=0; mt<4; mt++){
      f32x4 acc = {0.f,0.f,0.f,0.f};
      #pragma unroll
      for (int ks=0; ks<4; ks++)
        acc = __builtin_amdgcn_mfma_f32_16x16x32_bf16(afr[mt][ks], bfr[ks], acc, 0,0,0);
      #pragma unroll
      for (int r=0;r<4;r++){
        int m = mt*16 + quad*4 + r;
        qh[(size_t)(p0+m)*DD + n0 + l15] = acc[r] + bias;
      }
    }
  }
}

// ---------------------------------------------------------------------------
// 3) per-(b,l) attention, one wave per token, 16B vector gathers.
__global__ __launch_bounds__(64) void k_attn(
    const float* __restrict__ qh, const unsigned short* __restrict__ nK,
    const unsigned short* __restrict__ nV, const int* __restrict__ ctx_ids,
    float* __restrict__ o_out){
  const int p = blockIdx.x;
  const int lane = threadIdx.x;
  const int r = lane >> 4;
  const int g = lane & 15;
  const int h = g >> 2;
  __shared__ int ids[52];
  __shared__ float sc[NH][52];
  if (lane < KC) ids[lane] = ctx_ids[(size_t)p*KC + lane];
  float qv[8];
  {
    const float4* qp = (const float4*)(qh + (size_t)p*DD + g*8);
    float4 q0 = qp[0], q1 = qp[1];
    qv[0]=q0.x; qv[1]=q0.y; qv[2]=q0.z; qv[3]=q0.w;
    qv[4]=q1.x; qv[5]=q1.y; qv[6]=q1.z; qv[7]=q1.w;
  }
  __syncthreads();
  for (int kb=0; kb<13; kb++){
    int k2 = kb*4 + r;
    int row = ids[(k2 < KC) ? k2 : 0];
    u16x8 kv = *(const u16x8*)(nK + (size_t)row*DD + g*8);
    float pr = 0.f;
    #pragma unroll
    for (int j=0;j<8;j++) pr += qv[j]*bf2f(kv[j]);
    pr += __shfl_xor(pr, 1, 64);
    pr += __shfl_xor(pr, 2, 64);
    if ((g & 3) == 0 && k2 < KC) sc[h][k2] = pr;
  }
  __syncthreads();
  {
    const int hh = lane >> 4, kc = lane & 15;
    const float scale = 0.17677669529663687f;
    float mx = -1e30f;
    #pragma unroll
    for (int q4=0;q4<4;q4++){ int k2=kc+q4*16; if (k2<KC) mx = fmaxf(mx, sc[hh][k2]); }
    mx = fmaxf(mx, __shfl_xor(mx, 1, 64));
    mx = fmaxf(mx, __shfl_xor(mx, 2, 64));
    mx = fmaxf(mx, __shfl_xor(mx, 4, 64));
    mx = fmaxf(mx, __shfl_xor(mx, 8, 64));
    float sm = 0.f;
    float ev[4];
    #pragma unroll
    for (int q4=0;q4<4;q4++){
      int k2=kc+q4*16;
      ev[q4] = (k2<KC) ? __expf((sc[hh][k2]-mx)*scale) : 0.f;
      sm += ev[q4];
    }
    sm += __shfl_xor(sm, 1, 64);
    sm += __shfl_xor(sm, 2, 64);
    sm += __shfl_xor(sm, 4, 64);
    sm += __shfl_xor(sm, 8, 64);
    float inv = 1.f/sm;
    #pragma unroll
    for (int q4=0;q4<4;q4++){ int k2=kc+q4*16; if (k2<KC) sc[hh][k2] = ev[q4]*inv; }
  }
  __syncthreads();
  float acc[8];
  #pragma unroll
  for (int j=0;j<8;j++) acc[j]=0.f;
  for (int kb=0; kb<13; kb++){
    int k2 = kb*4 + r;
    int row = ids[(k2 < KC) ? k2 : 0];
    float w = (k2 < KC) ? sc[h][k2] : 0.f;
    u16x8 vv = *(const u16x8*)(nV + (size_t)row*DD + g*8);
    #pragma unroll
    for (int j=0;j<8;j++) acc[j] += w*bf2f(vv[j]);
  }
  #pragma unroll
  for (int j=0;j<8;j++){
    acc[j] += __shfl_xor(acc[j], 16, 64);
    acc[j] += __shfl_xor(acc[j], 32, 64);
  }
  if (r == 0){
    float4* op = (float4*)(o_out + (size_t)p*DD + g*8);
    op[0] = make_float4(acc[0],acc[1],acc[2],acc[3]);
    op[1] = make_float4(acc[4],acc[5],acc[6],acc[7]);
  }
}

// ---------------------------------------------------------------------------
// 4) doc = mask(widx==0) ? 0 : o @ wo^T + bo   via MFMA
__global__ __launch_bounds__(256) void k_wo(
    const float* __restrict__ o_attn, const int* __restrict__ widx,
    const unsigned short* __restrict__ wob, const float* __restrict__ out_b,
    float* __restrict__ doc){
  __shared__ __align__(16) unsigned short As[64*APAD];
  __shared__ int wm[64];
  const int tid = threadIdx.x;
  const int p0 = blockIdx.x * 64;
  if (tid < 64) wm[tid] = widx[p0 + tid];
  for (int i = tid; i < 64*32; i += 256){
    int row = i >> 5, j = i & 31;
    float4 v = ((const float4*)(o_attn + (size_t)(p0+row)*DD))[j];
    unsigned short* d = As + row*APAD + j*4;
    d[0]=f2bf(v.x); d[1]=f2bf(v.y); d[2]=f2bf(v.z); d[3]=f2bf(v.w);
  }
  __syncthreads();
  const int wave = tid >> 6;
  const int lane = tid & 63;
  const int l15  = lane & 15;
  const int quad = lane >> 4;
  bf16x8 afr[4][4];
  #pragma unroll
  for (int mt=0; mt<4; mt++)
    #pragma unroll
    for (int ks=0; ks<4; ks++)
      afr[mt][ks] = *(const bf16x8*)(As + (mt*16 + l15)*APAD + ks*32 + quad*8);
  #pragma unroll
  for (int nt=0; nt<2; nt++){
    const int n0 = wave*32 + nt*16;
    bf16x8 bfr[4];
    #pragma unroll
    for (int ks=0; ks<4; ks++)
      bfr[ks] = *(const bf16x8*)(wob + (size_t)(n0+l15)*DD + ks*32 + quad*8);
    const float bias = out_b[n0 + l15];
    #pragma unroll
    for (int mt=0; mt<4; mt++){
      f32x4 acc = {0.f,0.f,0.f,0.f};
      #pragma unroll
      for (int ks=0; ks<4; ks++)
        acc = __builtin_amdgcn_mfma_f32_16x16x32_bf16(afr[mt][ks], bfr[ks], acc, 0,0,0);
      #pragma unroll
      for (int r=0;r<4;r++){
        int m = mt*16 + quad*4 + r;
        doc[(size_t)(p0+m)*DD + n0 + l15] = (wm[m] == 0) ? 0.0f : (acc[r] + bias);
      }
    }
  }
}

// ---------------------------------------------------------------------------
// 6) conv as MFMA GEMM + fused max-over-t.
#define CROWS 68
#define CPAD 136
__global__ __launch_bounds__(256) void k_conv(
    const float* __restrict__ doc, const unsigned short* __restrict__ wb3,
    const unsigned short* __restrict__ wb4, const unsigned short* __restrict__ wb5,
    float* __restrict__ convp){
  __shared__ __align__(16) char smem[CROWS*CPAD*2];
  unsigned short* ds = (unsigned short*)smem;
  float* smf = (float*)smem;
  const int blk = blockIdx.x;
  const int chunk = blk & 3;
  const int j = (blk >> 2) % 3;
  const int b = blk / 12;
  const int kk = 3 + j;
  const int T = LL - kk + 1;
  const int t0 = chunk * 64;
  const int nrows = 64 + kk - 1;
  const unsigned short* wb = (j==0) ? wb3 : (j==1) ? wb4 : wb5;
  const int tid = threadIdx.x;
  for (int i = tid; i < nrows*32; i += 256){
    int row = i >> 5, q4 = i & 31;
    int gt = t0 + row;
    float4 v = (gt < LL) ? ((const float4*)(doc + ((size_t)b*LL + gt)*DD))[q4]
                         : make_float4(0.f,0.f,0.f,0.f);
    unsigned short* dp = ds + row*CPAD + q4*4;
    dp[0]=f2bf(v.x); dp[1]=f2bf(v.y); dp[2]=f2bf(v.z); dp[3]=f2bf(v.w);
  }
  __syncthreads();
  const int wave = tid >> 6;
  const int lane = tid & 63;
  const int l15  = lane & 15;
  const int quad = lane >> 4;
  f32x4 acc[8];
  #pragma unroll
  for (int nt=0;nt<8;nt++) acc[nt] = (f32x4){0.f,0.f,0.f,0.f};
  for (int jj=0; jj<kk; jj++){
    #pragma unroll
    for (int ks=0; ks<4; ks++){
      bf16x8 af = *(const bf16x8*)(ds + (wave*16 + l15 + jj)*CPAD + ks*32 + quad*8);
      #pragma unroll
      for (int nt=0; nt<8; nt++){
        bf16x8 bf = *(const bf16x8*)(wb + ((size_t)jj*CC + nt*16 + l15)*DD + ks*32 + quad*8);
        acc[nt] = __builtin_amdgcn_mfma_f32_16x16x32_bf16(af, bf, acc[nt], 0,0,0);
      }
    }
  }
  __syncthreads();
  #pragma unroll
  for (int nt=0; nt<8; nt++){
    float mx = -1e30f;
    #pragma unroll
    for (int r=0;r<4;r++){
      int t = t0 + wave*16 + quad*4 + r;
      mx = fmaxf(mx, (t < T) ? acc[nt][r] : -1e30f);
    }
    mx = fmaxf(mx, __shfl_xor(mx, 16, 64));
    mx = fmaxf(mx, __shfl_xor(mx, 32, 64));
    if (quad == 0) smf[wave*128 + nt*16 + l15] = mx;
  }
  __syncthreads();
  if (tid < 128){
    float m4 = fmaxf(fmaxf(smf[tid], smf[128+tid]), fmaxf(smf[256+tid], smf[384+tid]));
    convp[(((size_t)b*3 + j)*4 + chunk)*CC + tid] = m4;
  }
}

// ---------------------------------------------------------------------------
// 7) GRU via MFMA; block per (module, b, 8-seq half); 256 thr = 4 waves.
#define GSTR 392
__global__ __launch_bounds__(256) void k_gru(
    const float* __restrict__ news_table, const float* __restrict__ user_table,
    const float* __restrict__ source_table,
    const int* __restrict__ news_ids, const int* __restrict__ nsn_src,
    const int* __restrict__ nsn_end, const int* __restrict__ nun_usr,
    const int* __restrict__ nun_end,
    const unsigned short* __restrict__ wgb,
    const float* __restrict__ bih0, const float* __restrict__ bhh0,
    const float* __restrict__ bih1, const float* __restrict__ bhh1,
    float* __restrict__ enc){
  __shared__ __align__(16) unsigned short xs[16][CPAD];
  __shared__ __align__(16) unsigned short hs[16][CPAD];
  __shared__ float hf[8][128];
  __shared__ float gi[8][GSTR];
  __shared__ float gh[8][GSTR];
  const int blk = blockIdx.x;
  const int m  = blk >> 6;
  const int b  = (blk >> 1) & 31;
  const int s0 = (blk & 1) * 8;
  const int tid = threadIdx.x;
  const int wave = tid >> 6, lane = tid & 63, l15 = lane & 15, quad = lane >> 4;
  const unsigned short* Wih = wgb + (size_t)m*2*384*DD;
  const unsigned short* Whh = Wih + 384*DD;
  const float* bih = m ? bih1 : bih0;
  const float* bhh = m ? bhh1 : bhh0;
  for (int i=tid;i<16*CPAD;i+=256){ (&xs[0][0])[i]=0; (&hs[0][0])[i]=0; }
  for (int i=tid;i<8*128;i+=256) (&hf[0][0])[i]=0.f;
  __syncthreads();
  for (int t=0;t<3;t++){
    {
      int s = tid >> 5, j = tid & 31;
      int row; const float* tab;
      if (t==0){ row = news_ids[b]; tab = news_table; }
      else if (t==1){ row = m ? nun_usr[b*SS+s0+s] : nsn_src[b*SS+s0+s];
                      tab = m ? user_table : source_table; }
      else { row = m ? nun_end[b*SS+s0+s] : nsn_end[b*SS+s0+s]; tab = news_table; }
      float4 v = ((const float4*)(tab + (size_t)row*DD))[j];
      unsigned short* dp = &xs[s][j*4];
      dp[0]=f2bf(v.x); dp[1]=f2bf(v.y); dp[2]=f2bf(v.z); dp[3]=f2bf(v.w);
    }
    __syncthreads();
    bf16x8 ax[4], ah[4];
    #pragma unroll
    for (int ks=0;ks<4;ks++){
      ax[ks] = *(const bf16x8*)&xs[l15][ks*32+quad*8];
      ah[ks] = *(const bf16x8*)&hs[l15][ks*32+quad*8];
    }
    #pragma unroll
    for (int nt=0;nt<6;nt++){
      const int n0 = wave*96 + nt*16;
      f32x4 ga = {0.f,0.f,0.f,0.f}, ha = {0.f,0.f,0.f,0.f};
      #pragma unroll
      for (int ks=0;ks<4;ks++){
        bf16x8 bi = *(const bf16x8*)(Wih + (size_t)(n0+l15)*DD + ks*32+quad*8);
        ga = __builtin_amdgcn_mfma_f32_16x16x32_bf16(ax[ks], bi, ga, 0,0,0);
        bf16x8 bh = *(const bf16x8*)(Whh + (size_t)(n0+l15)*DD + ks*32+quad*8);
        ha = __builtin_amdgcn_mfma_f32_16x16x32_bf16(ah[ks], bh, ha, 0,0,0);
      }
      if (quad < 2){
        #pragma unroll
        for (int r=0;r<4;r++){
          gi[quad*4+r][n0+l15] = ga[r];
          gh[quad*4+r][n0+l15] = ha[r];
        }
      }
    }
    __syncthreads();
    #pragma unroll
    for (int k=0;k<4;k++){
      int it = tid + k*256;
      int s = it >> 7, g = it & 127;
      float rr = 1.f/(1.f+__expf(-(gi[s][g] + gh[s][g] + bih[g] + bhh[g])));
      float zz = 1.f/(1.f+__expf(-(gi[s][128+g] + gh[s][128+g] + bih[128+g] + bhh[128+g])));
      float nn = tanhf(gi[s][256+g] + bih[256+g] + rr*(gh[s][256+g] + bhh[256+g]));
      float hnew = (1.f-zz)*nn + zz*hf[s][g];
      hf[s][g] = hnew;
      hs[s][g] = f2bf(hnew);
    }
    __syncthreads();
  }
  {
    int s = tid >> 5, j = tid & 31;
    float4 v = ((const float4*)hf[s])[j];
    ((float4*)(enc + (((size_t)m*BB + b)*SS + (s0+s))*DD))[j] = v;
  }
}

// ---------------------------------------------------------------------------
// 8) meta-path MHA + residual + LN + mean over s; block per (module, b)
__global__ __launch_bounds__(128, 2) void k_metamha(
    const float* __restrict__ enc,
    const float* __restrict__ inw0, const float* __restrict__ inb0,
    const float* __restrict__ outw0, const float* __restrict__ outb0,
    const float* __restrict__ lng0, const float* __restrict__ lnb0,
    const float* __restrict__ inw1, const float* __restrict__ inb1,
    const float* __restrict__ outw1, const float* __restrict__ outb1,
    const float* __restrict__ lng1, const float* __restrict__ lnb1,
    float* __restrict__ meta_e){
  const int m = blockIdx.x >> 5;
  const int b = blockIdx.x & 31;
  const int c = threadIdx.x;
  const float* in_w  = m?inw1:inw0;  const float* in_b  = m?inb1:inb0;
  const float* out_w = m?outw1:outw0; const float* out_b = m?outb1:outb0;
  const float* lng   = m?lng1:lng0;  const float* lnb   = m?lnb1:lnb0;
  __shared__ float e[16][128], q[16][128], k[16][128], v[16][128];
  __shared__ float at[4][16][16];
  __shared__ float mu[16], rs[16];
  const float* esrc = enc + ((size_t)m*BB + b)*SS*DD;
  for (int i=c;i<16*128;i+=128) ((float*)e)[i] = esrc[i];
  __syncthreads();
  {
    float aq[16], ak[16], av[16];
    float bq = in_b[c], bk = in_b[128+c], bv = in_b[256+c];
    #pragma unroll
    for (int s=0;s<16;s++){ aq[s]=bq; ak[s]=bk; av[s]=bv; }
    const float4* wq4 = (const float4*)(in_w + c*DD);
    const float4* wk4 = (const float4*)(in_w + (128+c)*DD);
    const float4* wv4 = (const float4*)(in_w + (256+c)*DD);
    for (int j=0;j<32;j++){
      float4 a0=wq4[j], a1=wk4[j], a2=wv4[j];
      #pragma unroll
      for (int s=0;s<16;s++){
        float4 ev = ((const float4*)e[s])[j];
        aq[s]+=dot4(a0,ev); ak[s]+=dot4(a1,ev); av[s]+=dot4(a2,ev);
      }
    }
    #pragma unroll
    for (int s=0;s<16;s++){ q[s][c]=aq[s]; k[s][c]=ak[s]; v[s][c]=av[s]; }
  }
  __syncthreads();
  for (int r=0;r<8;r++){
    int lin = r*128 + c;
    int h = lin >> 8, qi = (lin>>4)&15, ki = lin&15;
    float sum=0.f;
    const float* qp = &q[qi][h*32];
    const float* kp = &k[ki][h*32];
    for (int x=0;x<32;x++) sum += qp[x]*kp[x];
    at[h][qi][ki] = sum * 0.17677669529663687f;
  }
  __syncthreads();
  if (c < 64){
    int h = c>>4, qi = c&15;
    float mx=-1e30f;
    for (int ki=0;ki<16;ki++) mx = fmaxf(mx, at[h][qi][ki]);
    float sm=0.f;
    for (int ki=0;ki<16;ki++){ float ee=__expf(at[h][qi][ki]-mx); at[h][qi][ki]=ee; sm+=ee; }
    float inv=1.f/sm;
    for (int ki=0;ki<16;ki++) at[h][qi][ki]*=inv;
  }
  __syncthreads();
  {
    int h = c>>5;
    float o[16];
    #pragma unroll
    for (int s=0;s<16;s++){
      float acc=0.f;
      for (int ki=0;ki<16;ki++) acc += at[h][s][ki]*v[ki][c];
      o[s]=acc;
    }
    __syncthreads();
    #pragma unroll
    for (int s=0;s<16;s++) q[s][c]=o[s];
  }
  __syncthreads();
  {
    float ay[16];
    float bo = out_b[c];
    #pragma unroll
    for (int s=0;s<16;s++) ay[s] = bo + e[s][c];
    const float4* wo4 = (const float4*)(out_w + c*DD);
    for (int j=0;j<32;j++){
      float4 wv_ = wo4[j];
      #pragma unroll
      for (int s=0;s<16;s++) ay[s] += dot4(wv_, ((const float4*)q[s])[j]);
    }
    __syncthreads();
    #pragma unroll
    for (int s=0;s<16;s++) e[s][c] = ay[s];
  }
  __syncthreads();
  if (c < 16){
    float sm=0.f;
    for (int d=0;d<128;d++) sm += e[c][d];
    float mean = sm*(1.f/128.f);
    float vs=0.f;
    for (int d=0;d<128;d++){ float df = e[c][d]-mean; vs += df*df; }
    mu[c]=mean; rs[c]=rsqrtf(vs*(1.f/128.f) + 1e-5f);
  }
  __syncthreads();
  {
    float g = lng[c], bb2 = lnb[c];
    float acc=0.f;
    #pragma unroll
    for (int s=0;s<16;s++) acc += (e[s][c]-mu[s])*rs[s]*g + bb2;
    meta_e[((size_t)m*BB+b)*DD + c] = acc * (1.f/16.f);
  }
}

// ---------------------------------------------------------------------------
// 9) pool-reduce + fc + meta gate + classifier; block per b
__global__ __launch_bounds__(128) void k_final(
    const float* __restrict__ convp,
    const float* __restrict__ cb3, const float* __restrict__ cb4,
    const float* __restrict__ cb5,
    const float* __restrict__ fc_w, const float* __restrict__ fc_b,
    const float* __restrict__ meta_e,
    const float* __restrict__ mp_w1, const float* __restrict__ mp_b1,
    const float* __restrict__ mp_w2, const float* __restrict__ mp_b2,
    const float* __restrict__ cls_w1, const float* __restrict__ cls_b1,
    const float* __restrict__ cls_w2, const float* __restrict__ cls_b2,
    float* __restrict__ out){
  const int b = blockIdx.x;
  const int c = threadIdx.x;
  __shared__ float pooled[384];
  __shared__ float comb[256];
  __shared__ float hcls[128];
  __shared__ float tt[2][64];
  __shared__ float wsc[2];
  for (int idx=c; idx<384; idx+=128){
    int j = idx >> 7, cc2 = idx & 127;
    const float* base = convp + (((size_t)b*3 + j)*4)*CC + cc2;
    float mx = -1e30f;
    for (int ci=0;ci<4;ci++) mx = fmaxf(mx, base[ci*CC]);
    const float* cb = (j==0)?cb3:(j==1)?cb4:cb5;
    pooled[idx] = fmaxf(mx + cb[cc2], 0.f);
  }
  __syncthreads();
  {
    float acc = fc_b[c];
    const float* wr = fc_w + (size_t)c*384;
    for (int i=0;i<384;i++) acc += pooled[i]*wr[i];
    comb[c] = acc;
  }
  if (c < 64){
    for (int m=0;m<2;m++){
      const float* ev = meta_e + ((size_t)m*BB+b)*DD;
      float acc = mp_b1[c];
      const float* wr = mp_w1 + (size_t)c*DD;
      for (int i=0;i<DD;i++) acc += ev[i]*wr[i];
      tt[m][c] = tanhf(acc);
    }
  }
  __syncthreads();
  if (c == 0){
    float s0 = mp_b2[0], s1 = mp_b2[0];
    for (int j=0;j<64;j++){ s0 += tt[0][j]*mp_w2[j]; s1 += tt[1][j]*mp_w2[j]; }
    float mx = fmaxf(s0,s1);
    float e0 = __expf(s0-mx), e1 = __expf(s1-mx);
    wsc[0] = e0/(e0+e1); wsc[1] = e1/(e0+e1);
  }
  __syncthreads();
  comb[128+c] = wsc[0]*meta_e[((size_t)b)*DD + c]
              + wsc[1]*meta_e[((size_t)(BB+b))*DD + c];
  __syncthreads();
  {
    float acc = cls_b1[c];
    const float* wr = cls_w1 + (size_t)c*256;
    for (int i=0;i<256;i++) acc += comb[i]*wr[i];
    hcls[c] = fmaxf(acc, 0.f);
  }
  __syncthreads();
  if (c < 2){
    float acc = cls_b2[c];
    const float* wr = cls_w2 + (size_t)c*DD;
    for (int i=0;i<DD;i++) acc += hcls[i]*wr[i];
    out[b*2 + c] = acc;
  }
}

// ---------------------------------------------------------------------------
extern "C" void kernel_launch(void* const* d_in, const int* in_sizes, int n_in,
                              void* d_out, int out_size, void* d_ws, size_t ws_size,
                              hipStream_t stream){
  const int* news_ids = (const int*)d_in[0];
  const int* nwi      = (const int*)d_in[1];
  const int* ctx_ids  = (const int*)d_in[2];
  const int* nsn_src  = (const int*)d_in[3];
  const int* nsn_end  = (const int*)d_in[4];
  const int* nun_usr  = (const int*)d_in[5];
  const int* nun_end  = (const int*)d_in[6];
  const float* word_table   = (const float*)d_in[7];
  const float* news_table   = (const float*)d_in[8];
  const float* user_table   = (const float*)d_in[9];
  const float* source_table = (const float*)d_in[10];
  const float* wa_in_w  = (const float*)d_in[11];
  const float* wa_in_b  = (const float*)d_in[12];
  const float* wa_out_w = (const float*)d_in[13];
  const float* wa_out_b = (const float*)d_in[14];
  const float* conv_w3 = (const float*)d_in[15];
  const float* conv_b3 = (const float*)d_in[16];
  const float* conv_w4 = (const float*)d_in[17];
  const float* conv_b4 = (const float*)d_in[18];
  const float* conv_w5 = (const float*)d_in[19];
  const float* conv_b5 = (const float*)d_in[20];
  const float* fc_w = (const float*)d_in[21];
  const float* fc_b = (const float*)d_in[22];
  const float* wih0 = (const float*)d_in[23];
  const float* whh0 = (const float*)d_in[24];
  const float* bih0 = (const float*)d_in[25];
  const float* bhh0 = (const float*)d_in[26];
  const float* inw0 = (const float*)d_in[27];
  const float* inb0 = (const float*)d_in[28];
  const float* outw0 = (const float*)d_in[29];
  const float* outb0 = (const float*)d_in[30];
  const float* lng0 = (const float*)d_in[31];
  const float* lnb0 = (const float*)d_in[32];
  const float* wih1 = (const float*)d_in[33];
  const float* whh1 = (const float*)d_in[34];
  const float* bih1 = (const float*)d_in[35];
  const float* bhh1 = (const float*)d_in[36];
  const float* inw1 = (const float*)d_in[37];
  const float* inb1 = (const float*)d_in[38];
  const float* outw1 = (const float*)d_in[39];
  const float* outb1 = (const float*)d_in[40];
  const float* lng1 = (const float*)d_in[41];
  const float* lnb1 = (const float*)d_in[42];
  const float* mp_w1 = (const float*)d_in[43];
  const float* mp_b1 = (const float*)d_in[44];
  const float* mp_w2 = (const float*)d_in[45];
  const float* mp_b2 = (const float*)d_in[46];
  const float* cls_w1 = (const float*)d_in[47];
  const float* cls_b1 = (const float*)d_in[48];
  const float* cls_w2 = (const float*)d_in[49];
  const float* cls_b2 = (const float*)d_in[50];

  // workspace layout
  char* wsb = (char*)d_ws;
  unsigned short* nK = (unsigned short*)wsb;                 // NNN*DD bf16
  unsigned short* nV = nK + (size_t)NNN*DD;                  // NNN*DD bf16
  unsigned short* wb3 = nV + (size_t)NNN*DD;                 // CC*DD*3 bf16
  unsigned short* wb4 = wb3 + (size_t)CC*DD*3;
  unsigned short* wb5 = wb4 + (size_t)CC*DD*4;
  unsigned short* wgb = wb5 + (size_t)CC*DD*5;               // 4*384*128 bf16
  unsigned short* wab = wgb + (size_t)4*384*DD;              // 512*128 bf16
  float* qh     = (float*)(wab + (size_t)512*DD);
  float* o_at   = qh + (size_t)BB*LL*DD;
  float* doc    = o_at + (size_t)BB*LL*DD;
  float* convp  = doc + (size_t)BB*LL*DD;
  float* enc    = convp + BB*3*4*CC;
  float* meta_e = enc + (size_t)2*BB*SS*DD;
  const size_t need_bytes = (size_t)((char*)(meta_e + 2*BB*DD) - wsb);
  if (ws_size < need_bytes) return;

  const unsigned short* wqb  = wab;                   // rows 0..127 (wq)
  const unsigned short* wkvb = wab + (size_t)128*DD;  // rows 128..383 (wk;wv)
  const unsigned short* wob  = wab + (size_t)384*DD;  // out_w

  k_prep<<<dim3(320), dim3(256), 0, stream>>>(conv_w3, conv_w4, conv_w5,
      wih0, whh0, wih1, whh1, wa_in_w, wa_out_w, wb3, wb4, wb5, wgb, wab);
  k_projkv<<<dim3((NNN+63)/64), dim3(256), 0, stream>>>(news_table, wkvb, wa_in_b, nK, nV);
  k_qh<<<dim3(BB*LL/64), dim3(256), 0, stream>>>(word_table, nwi, wqb, wa_in_b, qh);
  k_attn<<<dim3(BB*LL), dim3(64), 0, stream>>>(qh, nK, nV, ctx_ids, o_at);
  k_wo<<<dim3(BB*LL/64), dim3(256), 0, stream>>>(o_at, nwi, wob, wa_out_b, doc);
  k_conv<<<dim3(BB*3*4), dim3(256), 0, stream>>>(doc, wb3, wb4, wb5, convp);
  k_gru<<<dim3(128), dim3(256), 0, stream>>>(news_table, user_table, source_table,
      news_ids, nsn_src, nsn_end, nun_usr, nun_end,
      wgb, bih0, bhh0, bih1, bhh1, enc);
  k_metamha<<<dim3(64), dim3(128), 0, stream>>>(enc,
      inw0, inb0, outw0, outb0, lng0, lnb0,
      inw1, inb1, outw1, outb1, lng1, lnb1, meta_e);
  k_final<<<dim3(BB), dim3(128), 0, stream>>>(convp, conv_b3, conv_b4, conv_b5,
      fc_w, fc_b, meta_e, mp_w1, mp_b1, mp_w2, mp_b2,
      cls_w1, cls_b1, cls_w2, cls_b2, (float*)d_out);
}

// Round 8
// 385.719 us; speedup vs baseline: 2.4901x; 1.0285x over previous
//
#include <hip/hip_runtime.h>
#include <hip/hip_bf16.h>

// Problem dims
#define BB 32
#define LL 256
#define KC 50
#define SS 16
#define DD 128
#define NH 4
#define CC 128
#define VV 50000
#define NNN 100000
#define NUU 50000
#define NSS 5000

typedef __attribute__((ext_vector_type(8))) short bf16x8;
typedef __attribute__((ext_vector_type(8))) unsigned short u16x8;
typedef __attribute__((ext_vector_type(4))) float f32x4;

#define APAD 132   // LDS row stride (shorts): 66 words -> uniform bank spread

__device__ __forceinline__ float dot4(float4 a, float4 b){
  return a.x*b.x + a.y*b.y + a.z*b.z + a.w*b.w;
}

__device__ __forceinline__ unsigned short f2bf(float f){
  union { float f; unsigned int u; } v; v.f = f;
  unsigned int r = (v.u + 0x7FFFu + ((v.u >> 16) & 1u)) >> 16;
  return (unsigned short)r;
}
__device__ __forceinline__ float bf2f(unsigned short s){
  union { unsigned int u; float f; } v; v.u = ((unsigned int)s) << 16;
  return v.f;
}

// ---------------------------------------------------------------------------
// 0) unified weight prep: conv wb3/4/5, GRU wgb, word-attn wab  (one launch)
__global__ __launch_bounds__(256) void k_prep(
    const float* __restrict__ w3, const float* __restrict__ w4,
    const float* __restrict__ w5,
    const float* __restrict__ wih0, const float* __restrict__ whh0,
    const float* __restrict__ wih1, const float* __restrict__ whh1,
    const float* __restrict__ in_w, const float* __restrict__ out_w,
    unsigned short* __restrict__ wb3, unsigned short* __restrict__ wb4,
    unsigned short* __restrict__ wb5, unsigned short* __restrict__ wgb,
    unsigned short* __restrict__ wab){
  int e = blockIdx.x*256 + threadIdx.x;
  if (e < CC*DD*3){ int c=e/(DD*3), rm=e%(DD*3), d=rm/3, jj=rm%3;
    wb3[((size_t)jj*CC + c)*DD + d] = f2bf(w3[e]); }
  if (e < CC*DD*4){ int c=e/(DD*4), rm=e%(DD*4), d=rm/4, jj=rm%4;
    wb4[((size_t)jj*CC + c)*DD + d] = f2bf(w4[e]); }
  if (e < CC*DD*5){ int c=e/(DD*5), rm=e%(DD*5), d=rm/5, jj=rm%5;
    wb5[((size_t)jj*CC + c)*DD + d] = f2bf(w5[e]); }
  if (e < 384*DD){
    wgb[e]          = f2bf(wih0[e]);
    wgb[49152 + e]  = f2bf(whh0[e]);
    wgb[98304 + e]  = f2bf(wih1[e]);
    wgb[147456 + e] = f2bf(whh1[e]);
    wab[e]          = f2bf(in_w[e]);
  }
  if (e >= 384*DD && e < 512*DD) wab[e] = f2bf(out_w[e - 384*DD]);
}

// ---------------------------------------------------------------------------
// 1) nK/nV = bf16( news_table @ [wk;wv]^T + [bk;bv] ); 16.9 KB LDS, 2 passes
__global__ __launch_bounds__(256) void k_projkv(
    const float* __restrict__ news, const unsigned short* __restrict__ wkvb,
    const float* __restrict__ in_b, unsigned short* __restrict__ nK,
    unsigned short* __restrict__ nV){
  __shared__ __align__(16) unsigned short Ts[64*APAD];
  const int tid = threadIdx.x;
  const int r0 = blockIdx.x * 64;
  for (int i = tid; i < 64*32; i += 256){
    int row = i >> 5, j = i & 31;
    int gr = r0 + row;
    float4 v = (gr < NNN) ? ((const float4*)(news + (size_t)gr*DD))[j]
                          : make_float4(0.f,0.f,0.f,0.f);
    unsigned short* d = Ts + row*APAD + j*4;
    d[0]=f2bf(v.x); d[1]=f2bf(v.y); d[2]=f2bf(v.z); d[3]=f2bf(v.w);
  }
  __syncthreads();
  const int wave = tid >> 6;
  const int lane = tid & 63;
  const int l15  = lane & 15;
  const int quad = lane >> 4;
  bf16x8 afr[4][4];
  #pragma unroll
  for (int mt=0; mt<4; mt++)
    #pragma unroll
    for (int ks=0; ks<4; ks++)
      afr[mt][ks] = *(const bf16x8*)(Ts + (mt*16 + l15)*APAD + ks*32 + quad*8);
  __syncthreads();
  for (int pass=0; pass<2; pass++){
    unsigned short* outp = pass ? nV : nK;
    #pragma unroll
    for (int t=0; t<2; t++){
      const int n0 = wave*32 + t*16;
      bf16x8 bfr[4];
      #pragma unroll
      for (int ks=0; ks<4; ks++)
        bfr[ks] = *(const bf16x8*)(wkvb + (size_t)(pass*128 + n0 + l15)*DD + ks*32 + quad*8);
      const float bias = in_b[128 + pass*128 + n0 + l15];
      #pragma unroll
      for (int mt=0; mt<4; mt++){
        f32x4 acc = {0.f,0.f,0.f,0.f};
        #pragma unroll
        for (int ks=0; ks<4; ks++)
          acc = __builtin_amdgcn_mfma_f32_16x16x32_bf16(afr[mt][ks], bfr[ks], acc, 0,0,0);
        const int col = n0 + l15;
        const int rb  = mt*16 + quad*4;
        #pragma unroll
        for (int r=0;r<4;r++)
          Ts[(rb + r)*APAD + col] = f2bf(acc[r] + bias);
      }
    }
    __syncthreads();
    for (int c = tid; c < 64*32; c += 256){
      int row = c >> 5, col4 = (c & 31) * 4;
      int gr = r0 + row;
      if (gr < NNN)
        *(unsigned long long*)(outp + (size_t)gr*128 + col4) =
            *(const unsigned long long*)(Ts + row*APAD + col4);
    }
    __syncthreads();
  }
}

// ---------------------------------------------------------------------------
// 2) qh = gather(word_table, widx) @ wq^T + bq
//    One wave per 16-row M-tile; LDS-free: A-frag loaded directly from global.
__global__ __launch_bounds__(64) void k_qh(
    const float* __restrict__ word_table, const int* __restrict__ widx,
    const unsigned short* __restrict__ wqb, const float* __restrict__ in_b,
    float* __restrict__ qh){
  const int lane = threadIdx.x;
  const int l15 = lane & 15, quad = lane >> 4;
  const int p0 = blockIdx.x * 16;
  const int row = widx[p0 + l15];
  const float* src = word_table + (size_t)row*DD + quad*8;
  bf16x8 afr[4];
  #pragma unroll
  for (int ks=0; ks<4; ks++){
    float4 v0 = *(const float4*)(src + ks*32);
    float4 v1 = *(const float4*)(src + ks*32 + 4);
    bf16x8 a;
    a[0]=(short)f2bf(v0.x); a[1]=(short)f2bf(v0.y); a[2]=(short)f2bf(v0.z); a[3]=(short)f2bf(v0.w);
    a[4]=(short)f2bf(v1.x); a[5]=(short)f2bf(v1.y); a[6]=(short)f2bf(v1.z); a[7]=(short)f2bf(v1.w);
    afr[ks] = a;
  }
  #pragma unroll
  for (int nt=0; nt<8; nt++){
    const int n0 = nt*16;
    bf16x8 bfr[4];
    #pragma unroll
    for (int ks=0; ks<4; ks++)
      bfr[ks] = *(const bf16x8*)(wqb + (size_t)(n0+l15)*DD + ks*32 + quad*8);
    const float bias = in_b[n0 + l15];
    f32x4 acc = {0.f,0.f,0.f,0.f};
    #pragma unroll
    for (int ks=0; ks<4; ks++)
      acc = __builtin_amdgcn_mfma_f32_16x16x32_bf16(afr[ks], bfr[ks], acc, 0,0,0);
    #pragma unroll
    for (int r=0;r<4;r++){
      int m = quad*4 + r;
      qh[(size_t)(p0+m)*DD + n0 + l15] = acc[r] + bias;
    }
  }
}

// ---------------------------------------------------------------------------
// 3) per-(b,l) attention, one wave per token; writes o as bf16.
__global__ __launch_bounds__(64) void k_attn(
    const float* __restrict__ qh, const unsigned short* __restrict__ nK,
    const unsigned short* __restrict__ nV, const int* __restrict__ ctx_ids,
    unsigned short* __restrict__ o_out){
  const int p = blockIdx.x;
  const int lane = threadIdx.x;
  const int r = lane >> 4;
  const int g = lane & 15;
  const int h = g >> 2;
  __shared__ int ids[52];
  __shared__ float sc[NH][52];
  if (lane < KC) ids[lane] = ctx_ids[(size_t)p*KC + lane];
  float qv[8];
  {
    const float4* qp = (const float4*)(qh + (size_t)p*DD + g*8);
    float4 q0 = qp[0], q1 = qp[1];
    qv[0]=q0.x; qv[1]=q0.y; qv[2]=q0.z; qv[3]=q0.w;
    qv[4]=q1.x; qv[5]=q1.y; qv[6]=q1.z; qv[7]=q1.w;
  }
  __syncthreads();
  for (int kb=0; kb<13; kb++){
    int k2 = kb*4 + r;
    int row = ids[(k2 < KC) ? k2 : 0];
    u16x8 kv = *(const u16x8*)(nK + (size_t)row*DD + g*8);
    float pr = 0.f;
    #pragma unroll
    for (int j=0;j<8;j++) pr += qv[j]*bf2f(kv[j]);
    pr += __shfl_xor(pr, 1, 64);
    pr += __shfl_xor(pr, 2, 64);
    if ((g & 3) == 0 && k2 < KC) sc[h][k2] = pr;
  }
  __syncthreads();
  {
    const int hh = lane >> 4, kc = lane & 15;
    const float scale = 0.17677669529663687f;
    float mx = -1e30f;
    #pragma unroll
    for (int q4=0;q4<4;q4++){ int k2=kc+q4*16; if (k2<KC) mx = fmaxf(mx, sc[hh][k2]); }
    mx = fmaxf(mx, __shfl_xor(mx, 1, 64));
    mx = fmaxf(mx, __shfl_xor(mx, 2, 64));
    mx = fmaxf(mx, __shfl_xor(mx, 4, 64));
    mx = fmaxf(mx, __shfl_xor(mx, 8, 64));
    float sm = 0.f;
    float ev[4];
    #pragma unroll
    for (int q4=0;q4<4;q4++){
      int k2=kc+q4*16;
      ev[q4] = (k2<KC) ? __expf((sc[hh][k2]-mx)*scale) : 0.f;
      sm += ev[q4];
    }
    sm += __shfl_xor(sm, 1, 64);
    sm += __shfl_xor(sm, 2, 64);
    sm += __shfl_xor(sm, 4, 64);
    sm += __shfl_xor(sm, 8, 64);
    float inv = 1.f/sm;
    #pragma unroll
    for (int q4=0;q4<4;q4++){ int k2=kc+q4*16; if (k2<KC) sc[hh][k2] = ev[q4]*inv; }
  }
  __syncthreads();
  float acc[8];
  #pragma unroll
  for (int j=0;j<8;j++) acc[j]=0.f;
  for (int kb=0; kb<13; kb++){
    int k2 = kb*4 + r;
    int row = ids[(k2 < KC) ? k2 : 0];
    float w = (k2 < KC) ? sc[h][k2] : 0.f;
    u16x8 vv = *(const u16x8*)(nV + (size_t)row*DD + g*8);
    #pragma unroll
    for (int j=0;j<8;j++) acc[j] += w*bf2f(vv[j]);
  }
  #pragma unroll
  for (int j=0;j<8;j++){
    acc[j] += __shfl_xor(acc[j], 16, 64);
    acc[j] += __shfl_xor(acc[j], 32, 64);
  }
  if (r == 0){
    u16x8 o;
    #pragma unroll
    for (int j=0;j<8;j++) o[j] = f2bf(acc[j]);
    *(u16x8*)(o_out + (size_t)p*DD + g*8) = o;
  }
}

// ---------------------------------------------------------------------------
// 4) doc(bf16) = mask(widx==0) ? 0 : o @ wo^T + bo
//    One wave per 16-row tile; LDS-free (o already bf16).
__global__ __launch_bounds__(64) void k_wo(
    const unsigned short* __restrict__ o_attn, const int* __restrict__ widx,
    const unsigned short* __restrict__ wob, const float* __restrict__ out_b,
    unsigned short* __restrict__ doc){
  const int lane = threadIdx.x;
  const int l15 = lane & 15, quad = lane >> 4;
  const int p0 = blockIdx.x * 16;
  bf16x8 afr[4];
  #pragma unroll
  for (int ks=0; ks<4; ks++)
    afr[ks] = *(const bf16x8*)(o_attn + (size_t)(p0+l15)*DD + ks*32 + quad*8);
  int msk[4];
  #pragma unroll
  for (int r=0;r<4;r++) msk[r] = widx[p0 + quad*4 + r];
  #pragma unroll
  for (int nt=0; nt<8; nt++){
    const int n0 = nt*16;
    bf16x8 bfr[4];
    #pragma unroll
    for (int ks=0; ks<4; ks++)
      bfr[ks] = *(const bf16x8*)(wob + (size_t)(n0+l15)*DD + ks*32 + quad*8);
    const float bias = out_b[n0 + l15];
    f32x4 acc = {0.f,0.f,0.f,0.f};
    #pragma unroll
    for (int ks=0; ks<4; ks++)
      acc = __builtin_amdgcn_mfma_f32_16x16x32_bf16(afr[ks], bfr[ks], acc, 0,0,0);
    #pragma unroll
    for (int r=0;r<4;r++){
      int m = quad*4 + r;
      doc[(size_t)(p0+m)*DD + n0 + l15] = (msk[r] == 0) ? (unsigned short)0
                                                        : f2bf(acc[r] + bias);
    }
  }
}

// ---------------------------------------------------------------------------
// 6) conv as MFMA GEMM + fused max-over-t (doc already bf16: staging = copy)
#define CROWS 68
#define CPAD 136
__global__ __launch_bounds__(256) void k_conv(
    const unsigned short* __restrict__ doc, const unsigned short* __restrict__ wb3,
    const unsigned short* __restrict__ wb4, const unsigned short* __restrict__ wb5,
    float* __restrict__ convp){
  __shared__ __align__(16) char smem[CROWS*CPAD*2];
  unsigned short* ds = (unsigned short*)smem;
  float* smf = (float*)smem;
  const int blk = blockIdx.x;
  const int chunk = blk & 3;
  const int j = (blk >> 2) % 3;
  const int b = blk / 12;
  const int kk = 3 + j;
  const int T = LL - kk + 1;
  const int t0 = chunk * 64;
  const int nrows = 64 + kk - 1;
  const unsigned short* wb = (j==0) ? wb3 : (j==1) ? wb4 : wb5;
  const int tid = threadIdx.x;
  for (int i = tid; i < nrows*16; i += 256){
    int row = i >> 4, q8 = i & 15;
    int gt = t0 + row;
    u16x8 v = (u16x8){0,0,0,0,0,0,0,0};
    if (gt < LL) v = *(const u16x8*)(doc + ((size_t)b*LL + gt)*DD + q8*8);
    *(u16x8*)(ds + row*CPAD + q8*8) = v;
  }
  __syncthreads();
  const int wave = tid >> 6;
  const int lane = tid & 63;
  const int l15  = lane & 15;
  const int quad = lane >> 4;
  f32x4 acc[8];
  #pragma unroll
  for (int nt=0;nt<8;nt++) acc[nt] = (f32x4){0.f,0.f,0.f,0.f};
  for (int jj=0; jj<kk; jj++){
    #pragma unroll
    for (int ks=0; ks<4; ks++){
      bf16x8 af = *(const bf16x8*)(ds + (wave*16 + l15 + jj)*CPAD + ks*32 + quad*8);
      #pragma unroll
      for (int nt=0; nt<8; nt++){
        bf16x8 bf = *(const bf16x8*)(wb + ((size_t)jj*CC + nt*16 + l15)*DD + ks*32 + quad*8);
        acc[nt] = __builtin_amdgcn_mfma_f32_16x16x32_bf16(af, bf, acc[nt], 0,0,0);
      }
    }
  }
  __syncthreads();
  #pragma unroll
  for (int nt=0; nt<8; nt++){
    float mx = -1e30f;
    #pragma unroll
    for (int r=0;r<4;r++){
      int t = t0 + wave*16 + quad*4 + r;
      mx = fmaxf(mx, (t < T) ? acc[nt][r] : -1e30f);
    }
    mx = fmaxf(mx, __shfl_xor(mx, 16, 64));
    mx = fmaxf(mx, __shfl_xor(mx, 32, 64));
    if (quad == 0) smf[wave*128 + nt*16 + l15] = mx;
  }
  __syncthreads();
  if (tid < 128){
    float m4 = fmaxf(fmaxf(smf[tid], smf[128+tid]), fmaxf(smf[256+tid], smf[384+tid]));
    convp[(((size_t)b*3 + j)*4 + chunk)*CC + tid] = m4;
  }
}

// ---------------------------------------------------------------------------
// 7) GRU via MFMA; block per (module, b, 8-seq half); 256 thr = 4 waves.
#define GSTR 392
__global__ __launch_bounds__(256) void k_gru(
    const float* __restrict__ news_table, const float* __restrict__ user_table,
    const float* __restrict__ source_table,
    const int* __restrict__ news_ids, const int* __restrict__ nsn_src,
    const int* __restrict__ nsn_end, const int* __restrict__ nun_usr,
    const int* __restrict__ nun_end,
    const unsigned short* __restrict__ wgb,
    const float* __restrict__ bih0, const float* __restrict__ bhh0,
    const float* __restrict__ bih1, const float* __restrict__ bhh1,
    float* __restrict__ enc){
  __shared__ __align__(16) unsigned short xs[16][CPAD];
  __shared__ __align__(16) unsigned short hs[16][CPAD];
  __shared__ float hf[8][128];
  __shared__ float gi[8][GSTR];
  __shared__ float gh[8][GSTR];
  const int blk = blockIdx.x;
  const int m  = blk >> 6;
  const int b  = (blk >> 1) & 31;
  const int s0 = (blk & 1) * 8;
  const int tid = threadIdx.x;
  const int wave = tid >> 6, lane = tid & 63, l15 = lane & 15, quad = lane >> 4;
  const unsigned short* Wih = wgb + (size_t)m*2*384*DD;
  const unsigned short* Whh = Wih + 384*DD;
  const float* bih = m ? bih1 : bih0;
  const float* bhh = m ? bhh1 : bhh0;
  for (int i=tid;i<16*CPAD;i+=256){ (&xs[0][0])[i]=0; (&hs[0][0])[i]=0; }
  for (int i=tid;i<8*128;i+=256) (&hf[0][0])[i]=0.f;
  __syncthreads();
  for (int t=0;t<3;t++){
    {
      int s = tid >> 5, j = tid & 31;
      int row; const float* tab;
      if (t==0){ row = news_ids[b]; tab = news_table; }
      else if (t==1){ row = m ? nun_usr[b*SS+s0+s] : nsn_src[b*SS+s0+s];
                      tab = m ? user_table : source_table; }
      else { row = m ? nun_end[b*SS+s0+s] : nsn_end[b*SS+s0+s]; tab = news_table; }
      float4 v = ((const float4*)(tab + (size_t)row*DD))[j];
      unsigned short* dp = &xs[s][j*4];
      dp[0]=f2bf(v.x); dp[1]=f2bf(v.y); dp[2]=f2bf(v.z); dp[3]=f2bf(v.w);
    }
    __syncthreads();
    bf16x8 ax[4], ah[4];
    #pragma unroll
    for (int ks=0;ks<4;ks++){
      ax[ks] = *(const bf16x8*)&xs[l15][ks*32+quad*8];
      ah[ks] = *(const bf16x8*)&hs[l15][ks*32+quad*8];
    }
    #pragma unroll
    for (int nt=0;nt<6;nt++){
      const int n0 = wave*96 + nt*16;
      f32x4 ga = {0.f,0.f,0.f,0.f}, ha = {0.f,0.f,0.f,0.f};
      #pragma unroll
      for (int ks=0;ks<4;ks++){
        bf16x8 bi = *(const bf16x8*)(Wih + (size_t)(n0+l15)*DD + ks*32+quad*8);
        ga = __builtin_amdgcn_mfma_f32_16x16x32_bf16(ax[ks], bi, ga, 0,0,0);
        bf16x8 bh = *(const bf16x8*)(Whh + (size_t)(n0+l15)*DD + ks*32+quad*8);
        ha = __builtin_amdgcn_mfma_f32_16x16x32_bf16(ah[ks], bh, ha, 0,0,0);
      }
      if (quad < 2){
        #pragma unroll
        for (int r=0;r<4;r++){
          gi[quad*4+r][n0+l15] = ga[r];
          gh[quad*4+r][n0+l15] = ha[r];
        }
      }
    }
    __syncthreads();
    #pragma unroll
    for (int k=0;k<4;k++){
      int it = tid + k*256;
      int s = it >> 7, g = it & 127;
      float rr = 1.f/(1.f+__expf(-(gi[s][g] + gh[s][g] + bih[g] + bhh[g])));
      float zz = 1.f/(1.f+__expf(-(gi[s][128+g] + gh[s][128+g] + bih[128+g] + bhh[128+g])));
      float nn = tanhf(gi[s][256+g] + bih[256+g] + rr*(gh[s][256+g] + bhh[256+g]));
      float hnew = (1.f-zz)*nn + zz*hf[s][g];
      hf[s][g] = hnew;
      hs[s][g] = f2bf(hnew);
    }
    __syncthreads();
  }
  {
    int s = tid >> 5, j = tid & 31;
    float4 v = ((const float4*)hf[s])[j];
    ((float4*)(enc + (((size_t)m*BB + b)*SS + (s0+s))*DD))[j] = v;
  }
}

// ---------------------------------------------------------------------------
// 8) meta-path MHA + residual + LN + mean over s; block per (module, b)
__global__ __launch_bounds__(128, 2) void k_metamha(
    const float* __restrict__ enc,
    const float* __restrict__ inw0, const float* __restrict__ inb0,
    const float* __restrict__ outw0, const float* __restrict__ outb0,
    const float* __restrict__ lng0, const float* __restrict__ lnb0,
    const float* __restrict__ inw1, const float* __restrict__ inb1,
    const float* __restrict__ outw1, const float* __restrict__ outb1,
    const float* __restrict__ lng1, const float* __restrict__ lnb1,
    float* __restrict__ meta_e){
  const int m = blockIdx.x >> 5;
  const int b = blockIdx.x & 31;
  const int c = threadIdx.x;
  const float* in_w  = m?inw1:inw0;  const float* in_b  = m?inb1:inb0;
  const float* out_w = m?outw1:outw0; const float* out_b = m?outb1:outb0;
  const float* lng   = m?lng1:lng0;  const float* lnb   = m?lnb1:lnb0;
  __shared__ float e[16][128], q[16][128], k[16][128], v[16][128];
  __shared__ float at[4][16][16];
  __shared__ float mu[16], rs[16];
  const float* esrc = enc + ((size_t)m*BB + b)*SS*DD;
  for (int i=c;i<16*128;i+=128) ((float*)e)[i] = esrc[i];
  __syncthreads();
  {
    float aq[16], ak[16], av[16];
    float bq = in_b[c], bk = in_b[128+c], bv = in_b[256+c];
    #pragma unroll
    for (int s=0;s<16;s++){ aq[s]=bq; ak[s]=bk; av[s]=bv; }
    const float4* wq4 = (const float4*)(in_w + c*DD);
    const float4* wk4 = (const float4*)(in_w + (128+c)*DD);
    const float4* wv4 = (const float4*)(in_w + (256+c)*DD);
    for (int j=0;j<32;j++){
      float4 a0=wq4[j], a1=wk4[j], a2=wv4[j];
      #pragma unroll
      for (int s=0;s<16;s++){
        float4 ev = ((const float4*)e[s])[j];
        aq[s]+=dot4(a0,ev); ak[s]+=dot4(a1,ev); av[s]+=dot4(a2,ev);
      }
    }
    #pragma unroll
    for (int s=0;s<16;s++){ q[s][c]=aq[s]; k[s][c]=ak[s]; v[s][c]=av[s]; }
  }
  __syncthreads();
  for (int r=0;r<8;r++){
    int lin = r*128 + c;
    int h = lin >> 8, qi = (lin>>4)&15, ki = lin&15;
    float sum=0.f;
    const float* qp = &q[qi][h*32];
    const float* kp = &k[ki][h*32];
    for (int x=0;x<32;x++) sum += qp[x]*kp[x];
    at[h][qi][ki] = sum * 0.17677669529663687f;
  }
  __syncthreads();
  if (c < 64){
    int h = c>>4, qi = c&15;
    float mx=-1e30f;
    for (int ki=0;ki<16;ki++) mx = fmaxf(mx, at[h][qi][ki]);
    float sm=0.f;
    for (int ki=0;ki<16;ki++){ float ee=__expf(at[h][qi][ki]-mx); at[h][qi][ki]=ee; sm+=ee; }
    float inv=1.f/sm;
    for (int ki=0;ki<16;ki++) at[h][qi][ki]*=inv;
  }
  __syncthreads();
  {
    int h = c>>5;
    float o[16];
    #pragma unroll
    for (int s=0;s<16;s++){
      float acc=0.f;
      for (int ki=0;ki<16;ki++) acc += at[h][s][ki]*v[ki][c];
      o[s]=acc;
    }
    __syncthreads();
    #pragma unroll
    for (int s=0;s<16;s++) q[s][c]=o[s];
  }
  __syncthreads();
  {
    float ay[16];
    float bo = out_b[c];
    #pragma unroll
    for (int s=0;s<16;s++) ay[s] = bo + e[s][c];
    const float4* wo4 = (const float4*)(out_w + c*DD);
    for (int j=0;j<32;j++){
      float4 wv_ = wo4[j];
      #pragma unroll
      for (int s=0;s<16;s++) ay[s] += dot4(wv_, ((const float4*)q[s])[j]);
    }
    __syncthreads();
    #pragma unroll
    for (int s=0;s<16;s++) e[s][c] = ay[s];
  }
  __syncthreads();
  if (c < 16){
    float sm=0.f;
    for (int d=0;d<128;d++) sm += e[c][d];
    float mean = sm*(1.f/128.f);
    float vs=0.f;
    for (int d=0;d<128;d++){ float df = e[c][d]-mean; vs += df*df; }
    mu[c]=mean; rs[c]=rsqrtf(vs*(1.f/128.f) + 1e-5f);
  }
  __syncthreads();
  {
    float g = lng[c], bb2 = lnb[c];
    float acc=0.f;
    #pragma unroll
    for (int s=0;s<16;s++) acc += (e[s][c]-mu[s])*rs[s]*g + bb2;
    meta_e[((size_t)m*BB+b)*DD + c] = acc * (1.f/16.f);
  }
}

// ---------------------------------------------------------------------------
// 9) pool-reduce + fc + meta gate + classifier; block per b
__global__ __launch_bounds__(128) void k_final(
    const float* __restrict__ convp,
    const float* __restrict__ cb3, const float* __restrict__ cb4,
    const float* __restrict__ cb5,
    const float* __restrict__ fc_w, const float* __restrict__ fc_b,
    const float* __restrict__ meta_e,
    const float* __restrict__ mp_w1, const float* __restrict__ mp_b1,
    const float* __restrict__ mp_w2, const float* __restrict__ mp_b2,
    const float* __restrict__ cls_w1, const float* __restrict__ cls_b1,
    const float* __restrict__ cls_w2, const float* __restrict__ cls_b2,
    float* __restrict__ out){
  const int b = blockIdx.x;
  const int c = threadIdx.x;
  __shared__ float pooled[384];
  __shared__ float comb[256];
  __shared__ float hcls[128];
  __shared__ float tt[2][64];
  __shared__ float wsc[2];
  for (int idx=c; idx<384; idx+=128){
    int j = idx >> 7, cc2 = idx & 127;
    const float* base = convp + (((size_t)b*3 + j)*4)*CC + cc2;
    float mx = -1e30f;
    for (int ci=0;ci<4;ci++) mx = fmaxf(mx, base[ci*CC]);
    const float* cb = (j==0)?cb3:(j==1)?cb4:cb5;
    pooled[idx] = fmaxf(mx + cb[cc2], 0.f);
  }
  __syncthreads();
  {
    float acc = fc_b[c];
    const float* wr = fc_w + (size_t)c*384;
    for (int i=0;i<384;i++) acc += pooled[i]*wr[i];
    comb[c] = acc;
  }
  if (c < 64){
    for (int m=0;m<2;m++){
      const float* ev = meta_e + ((size_t)m*BB+b)*DD;
      float acc = mp_b1[c];
      const float* wr = mp_w1 + (size_t)c*DD;
      for (int i=0;i<DD;i++) acc += ev[i]*wr[i];
      tt[m][c] = tanhf(acc);
    }
  }
  __syncthreads();
  if (c == 0){
    float s0 = mp_b2[0], s1 = mp_b2[0];
    for (int j=0;j<64;j++){ s0 += tt[0][j]*mp_w2[j]; s1 += tt[1][j]*mp_w2[j]; }
    float mx = fmaxf(s0,s1);
    float e0 = __expf(s0-mx), e1 = __expf(s1-mx);
    wsc[0] = e0/(e0+e1); wsc[1] = e1/(e0+e1);
  }
  __syncthreads();
  comb[128+c] = wsc[0]*meta_e[((size_t)b)*DD + c]
              + wsc[1]*meta_e[((size_t)(BB+b))*DD + c];
  __syncthreads();
  {
    float acc = cls_b1[c];
    const float* wr = cls_w1 + (size_t)c*256;
    for (int i=0;i<256;i++) acc += comb[i]*wr[i];
    hcls[c] = fmaxf(acc, 0.f);
  }
  __syncthreads();
  if (c < 2){
    float acc = cls_b2[c];
    const float* wr = cls_w2 + (size_t)c*DD;
    for (int i=0;i<DD;i++) acc += hcls[i]*wr[i];
    out[b*2 + c] = acc;
  }
}

// ---------------------------------------------------------------------------
extern "C" void kernel_launch(void* const* d_in, const int* in_sizes, int n_in,
                              void* d_out, int out_size, void* d_ws, size_t ws_size,
                              hipStream_t stream){
  const int* news_ids = (const int*)d_in[0];
  const int* nwi      = (const int*)d_in[1];
  const int* ctx_ids  = (const int*)d_in[2];
  const int* nsn_src  = (const int*)d_in[3];
  const int* nsn_end  = (const int*)d_in[4];
  const int* nun_usr  = (const int*)d_in[5];
  const int* nun_end  = (const int*)d_in[6];
  const float* word_table   = (const float*)d_in[7];
  const float* news_table   = (const float*)d_in[8];
  const float* user_table   = (const float*)d_in[9];
  const float* source_table = (const float*)d_in[10];
  const float* wa_in_w  = (const float*)d_in[11];
  const float* wa_in_b  = (const float*)d_in[12];
  const float* wa_out_w = (const float*)d_in[13];
  const float* wa_out_b = (const float*)d_in[14];
  const float* conv_w3 = (const float*)d_in[15];
  const float* conv_b3 = (const float*)d_in[16];
  const float* conv_w4 = (const float*)d_in[17];
  const float* conv_b4 = (const float*)d_in[18];
  const float* conv_w5 = (const float*)d_in[19];
  const float* conv_b5 = (const float*)d_in[20];
  const float* fc_w = (const float*)d_in[21];
  const float* fc_b = (const float*)d_in[22];
  const float* wih0 = (const float*)d_in[23];
  const float* whh0 = (const float*)d_in[24];
  const float* bih0 = (const float*)d_in[25];
  const float* bhh0 = (const float*)d_in[26];
  const float* inw0 = (const float*)d_in[27];
  const float* inb0 = (const float*)d_in[28];
  const float* outw0 = (const float*)d_in[29];
  const float* outb0 = (const float*)d_in[30];
  const float* lng0 = (const float*)d_in[31];
  const float* lnb0 = (const float*)d_in[32];
  const float* wih1 = (const float*)d_in[33];
  const float* whh1 = (const float*)d_in[34];
  const float* bih1 = (const float*)d_in[35];
  const float* bhh1 = (const float*)d_in[36];
  const float* inw1 = (const float*)d_in[37];
  const float* inb1 = (const float*)d_in[38];
  const float* outw1 = (const float*)d_in[39];
  const float* outb1 = (const float*)d_in[40];
  const float* lng1 = (const float*)d_in[41];
  const float* lnb1 = (const float*)d_in[42];
  const float* mp_w1 = (const float*)d_in[43];
  const float* mp_b1 = (const float*)d_in[44];
  const float* mp_w2 = (const float*)d_in[45];
  const float* mp_b2 = (const float*)d_in[46];
  const float* cls_w1 = (const float*)d_in[47];
  const float* cls_b1 = (const float*)d_in[48];
  const float* cls_w2 = (const float*)d_in[49];
  const float* cls_b2 = (const float*)d_in[50];

  // workspace layout (o_at/doc now bf16 but keep float-sized slots)
  char* wsb = (char*)d_ws;
  unsigned short* nK = (unsigned short*)wsb;                 // NNN*DD bf16
  unsigned short* nV = nK + (size_t)NNN*DD;                  // NNN*DD bf16
  unsigned short* wb3 = nV + (size_t)NNN*DD;
  unsigned short* wb4 = wb3 + (size_t)CC*DD*3;
  unsigned short* wb5 = wb4 + (size_t)CC*DD*4;
  unsigned short* wgb = wb5 + (size_t)CC*DD*5;               // 4*384*128 bf16
  unsigned short* wab = wgb + (size_t)4*384*DD;              // 512*128 bf16
  float* qh     = (float*)(wab + (size_t)512*DD);
  unsigned short* o_at = (unsigned short*)(qh + (size_t)BB*LL*DD);   // bf16 (slot sized fp32)
  unsigned short* doc  = (unsigned short*)((float*)o_at + (size_t)BB*LL*DD); // bf16
  float* convp  = (float*)doc + (size_t)BB*LL*DD;
  float* enc    = convp + BB*3*4*CC;
  float* meta_e = enc + (size_t)2*BB*SS*DD;
  const size_t need_bytes = (size_t)((char*)(meta_e + 2*BB*DD) - wsb);
  if (ws_size < need_bytes) return;

  const unsigned short* wqb  = wab;                   // rows 0..127 (wq)
  const unsigned short* wkvb = wab + (size_t)128*DD;  // rows 128..383 (wk;wv)
  const unsigned short* wob  = wab + (size_t)384*DD;  // out_w

  k_prep<<<dim3(320), dim3(256), 0, stream>>>(conv_w3, conv_w4, conv_w5,
      wih0, whh0, wih1, whh1, wa_in_w, wa_out_w, wb3, wb4, wb5, wgb, wab);
  k_projkv<<<dim3((NNN+63)/64), dim3(256), 0, stream>>>(news_table, wkvb, wa_in_b, nK, nV);
  k_qh<<<dim3(BB*LL/16), dim3(64), 0, stream>>>(word_table, nwi, wqb, wa_in_b, qh);
  k_attn<<<dim3(BB*LL), dim3(64), 0, stream>>>(qh, nK, nV, ctx_ids, o_at);
  k_wo<<<dim3(BB*LL/16), dim3(64), 0, stream>>>(o_at, nwi, wob, wa_out_b, doc);
  k_conv<<<dim3(BB*3*4), dim3(256), 0, stream>>>(doc, wb3, wb4, wb5, convp);
  k_gru<<<dim3(128), dim3(256), 0, stream>>>(news_table, user_table, source_table,
      news_ids, nsn_src, nsn_end, nun_usr, nun_end,
      wgb, bih0, bhh0, bih1, bhh1, enc);
  k_metamha<<<dim3(64), dim3(128), 0, stream>>>(enc,
      inw0, inb0, outw0, outb0, lng0, lnb0,
      inw1, inb1, outw1, outb1, lng1, lnb1, meta_e);
  k_final<<<dim3(BB), dim3(128), 0, stream>>>(convp, conv_b3, conv_b4, conv_b5,
      fc_w, fc_b, meta_e, mp_w1, mp_b1, mp_w2, mp_b2,
      cls_w1, cls_b1, cls_w2, cls_b2, (float*)d_out);
}